// Round 3
// baseline (1533.594 us; speedup 1.0000x reference)
//
#include <hip/hip_runtime.h>
#include <stdint.h>

// ---------------------------------------------------------------------------
// Enc_block: KNN graph + gumbel-softmax soft edges + PointTransformerConv +
// down + neighbor max-pool + GridSampling.  N=8192, Cin=64, Cout=128, K=16.
// ---------------------------------------------------------------------------

#define PARTITIONABLE 1   // JAX >= 0.5: threefry_partitionable default True

typedef unsigned int u32;

#define NN 8192
#define EPS20 1e-20f

// ---------------- threefry2x32 (JAX key schedule) ----------------
__host__ __device__ static inline u32 rotl32(u32 v, int r){ return (v<<r)|(v>>(32-r)); }

__host__ __device__ static inline void tf2x32(u32 k0, u32 k1, u32 c0, u32 c1, u32& o0, u32& o1){
  u32 ks2 = k0 ^ k1 ^ 0x1BD11BDAu;
  u32 x0 = c0 + k0;
  u32 x1 = c1 + k1;
#define TFR(r) x0 += x1; x1 = rotl32(x1,(r)); x1 ^= x0;
  TFR(13) TFR(15) TFR(26) TFR(6)
  x0 += k1;  x1 += ks2 + 1u;
  TFR(17) TFR(29) TFR(16) TFR(24)
  x0 += ks2; x1 += k0 + 2u;
  TFR(13) TFR(15) TFR(26) TFR(6)
  x0 += k0;  x1 += k1 + 3u;
  TFR(17) TFR(29) TFR(16) TFR(24)
  x0 += k1;  x1 += ks2 + 4u;
  TFR(13) TFR(15) TFR(26) TFR(6)
  x0 += ks2; x1 += k0 + 5u;
#undef TFR
  o0 = x0; o1 = x1;
}

__device__ static inline u32 rbits(u32 k0, u32 k1, u32 idx){
#if PARTITIONABLE
  u32 o0,o1; tf2x32(k0,k1, 0u, idx, o0,o1);   // 64-bit counter (0, idx)
  return o0 ^ o1;                              // 32-bit fold
#else
  u32 o0,o1; tf2x32(k0,k1, 0u, idx, o0,o1);
  return o0;
#endif
}

__device__ static inline float u01(u32 b){
  return __uint_as_float((b>>9) | 0x3f800000u) - 1.0f;   // [0,1), JAX formula
}

// ---------------- workspace layout ----------------
static constexpr size_t OFF_EMBF = 0;                              // [8192][12] f32: e[10], se, K
static constexpr size_t OFF_SP   = OFF_EMBF + (size_t)8192*12*4;
static constexpr size_t OFF_PSUM = OFF_SP   + (size_t)8192*4;      // [32][8192]
static constexpr size_t OFF_SSRC = OFF_PSUM + (size_t)32*8192*4;   // int [8192][16]
static constexpr size_t OFF_TOPV = OFF_SSRC + (size_t)8192*16*4;
static constexpr size_t OFF_KSRC = OFF_TOPV + (size_t)8192*16*4;   // int [8192][16]
static constexpr size_t OFF_A    = OFF_KSRC + (size_t)8192*16*4;   // x@Wsrc
static constexpr size_t OFF_B    = OFF_A    + (size_t)8192*128*4;  // x@Wdst
static constexpr size_t OFF_V    = OFF_B    + (size_t)8192*128*4;  // x@Wlin
static constexpr size_t OFF_H    = OFF_V    + (size_t)8192*128*4;  // conv out
static constexpr size_t OFF_HD   = OFF_H    + (size_t)8192*128*4;  // after down
static constexpr size_t OFF_Y    = OFF_HD   + (size_t)8192*128*4;  // after pool
static constexpr size_t OFF_ACCX = OFF_Y    + (size_t)8192*128*4;  // voxel sums
static constexpr size_t OFF_ACCP = OFF_ACCX + (size_t)8192*128*4;  // voxel pos sums
static constexpr size_t OFF_HIST = OFF_ACCP + (size_t)8192*3*4;    // int [8192]
static constexpr size_t OFF_RANK = OFF_HIST + (size_t)8192*4;      // int [8192]
static constexpr size_t OFF_UCNT = OFF_RANK + (size_t)8192*4;      // int [8192]
static constexpr size_t OFF_VID  = OFF_UCNT + (size_t)8192*4;      // int [8192]
static constexpr size_t OFF_META = OFF_VID  + (size_t)8192*4;      // posmin f[3] @0, nv i[3] @16B, U i @32B

// ---------------- kernels ----------------

// pos column-min and voxel-grid extents (single block)
__global__ __launch_bounds__(1024) void k_prep(const float* __restrict__ pos,
                                               float* __restrict__ meta_f, int* __restrict__ meta_i){
  __shared__ float red[1024][3];
  __shared__ int   redi[1024][3];
  __shared__ float pmn[3];
  int t = threadIdx.x;
  float mn[3] = {1e30f,1e30f,1e30f};
  for (int n=t; n<NN; n+=1024){
    #pragma unroll
    for (int d=0; d<3; d++) mn[d] = fminf(mn[d], pos[n*3+d]);
  }
  #pragma unroll
  for (int d=0; d<3; d++) red[t][d] = mn[d];
  __syncthreads();
  for (int s=512; s>0; s>>=1){
    if (t < s){ for (int d=0; d<3; d++) red[t][d] = fminf(red[t][d], red[t+s][d]); }
    __syncthreads();
  }
  if (t < 3) pmn[t] = red[0][t];
  __syncthreads();
  int mx[3] = {0,0,0};
  for (int n=t; n<NN; n+=1024){
    #pragma unroll
    for (int d=0; d<3; d++){
      int v = (int)floorf((pos[n*3+d] - pmn[d]) * 2.0f);   // /0.5 == *2 exactly
      mx[d] = max(mx[d], v);
    }
  }
  #pragma unroll
  for (int d=0; d<3; d++) redi[t][d] = mx[d];
  __syncthreads();
  for (int s=512; s>0; s>>=1){
    if (t < s){ for (int d=0; d<3; d++) redi[t][d] = max(redi[t][d], redi[t+s][d]); }
    __syncthreads();
  }
  if (t == 0){
    meta_f[0]=pmn[0]; meta_f[1]=pmn[1]; meta_f[2]=pmn[2];
    meta_i[0]=redi[0][0]+1; meta_i[1]=redi[0][1]+1; meta_i[2]=redi[0][2]+1;
  }
}

// voxel id + histogram + pos squared norms
__global__ __launch_bounds__(256) void k_vid(const float* __restrict__ pos,
                                             const float* __restrict__ meta_f, const int* __restrict__ meta_i,
                                             int* __restrict__ vid, int* __restrict__ hist,
                                             float* __restrict__ sp){
  int n = blockIdx.x*256 + threadIdx.x;
  float p0=pos[n*3], p1=pos[n*3+1], p2=pos[n*3+2];
  sp[n] = p0*p0 + p1*p1 + p2*p2;
  int v0 = (int)floorf((p0-meta_f[0])*2.0f);
  int v1 = (int)floorf((p1-meta_f[1])*2.0f);
  int v2 = (int)floorf((p2-meta_f[2])*2.0f);
  int id = (v0*meta_i[1] + v1)*meta_i[2] + v2;
  vid[n] = id;
  atomicAdd(&hist[id], 1);
}

// embF[i] = { relu(x@Wg1+bg1)@Wg2+bg2 + u*0.001  (10), |emb|^2, 0 }
__global__ __launch_bounds__(64) void k_emb(const float* __restrict__ x,
    const float* __restrict__ Wg1, const float* __restrict__ bg1,
    const float* __restrict__ Wg2, const float* __restrict__ bg2,
    u32 ka, u32 kb, float* __restrict__ embF){
  int i = blockIdx.x; int t = threadIdx.x;
  __shared__ float xs[64], hs[64], esq[10];
  xs[t] = x[i*64+t];
  __syncthreads();
  float a = bg1[t];
  for (int k=0; k<64; k++) a += xs[k]*Wg1[k*64+t];
  hs[t] = fmaxf(a, 0.0f);
  __syncthreads();
  if (t < 10){
    float e = bg2[t];
    for (int k=0; k<64; k++) e += hs[k]*Wg2[k*10+t];
    e += u01(rbits(ka, kb, (u32)(i*10+t))) * 0.001f;
    embF[i*12+t] = e;
    esq[t] = e*e;
  }
  __syncthreads();
  if (t == 0){
    float ssum = 0.0f;
    #pragma unroll
    for (int d=0; d<10; d++) ssum += esq[d];
    embF[i*12+10] = ssum;
    embF[i*12+11] = 0.0f;
  }
}

// KNN: top-16 smallest d2 per row (diag excluded), ties -> lower index
__global__ __launch_bounds__(64) void k_knn(const float* __restrict__ pos, const float* __restrict__ sp,
                                            int* __restrict__ knn_src){
  int i = blockIdx.x; int l = threadIdx.x;
  float pi0=pos[i*3], pi1=pos[i*3+1], pi2=pos[i*3+2];
  float spi = sp[i];
  float lv[16]; int lj[16];
  #pragma unroll
  for (int s=0; s<16; s++){ lv[s]=1e30f; lj[s]=0x7fffffff; }
  for (int tt=0; tt<128; tt++){
    int j = l + 64*tt;
    if (j == i) continue;
    float d = spi + sp[j] - 2.0f*(pi0*pos[j*3] + pi1*pos[j*3+1] + pi2*pos[j*3+2]);
    d = fmaxf(d, 0.0f);
    if (d < lv[15]){
      lv[15]=d; lj[15]=j;
      #pragma unroll
      for (int s=15; s>0; s--){
        if (lv[s] < lv[s-1]){ float tv=lv[s]; lv[s]=lv[s-1]; lv[s-1]=tv; int tj=lj[s]; lj[s]=lj[s-1]; lj[s-1]=tj; }
      }
    }
  }
  for (int r=0; r<16; r++){
    float bv = lv[0]; int bj = lj[0];
    #pragma unroll
    for (int off=32; off>=1; off>>=1){
      float ov = __shfl_xor(bv, off);
      int   oj = __shfl_xor(bj, off);
      if (ov < bv || (ov == bv && oj < bj)){ bv = ov; bj = oj; }
    }
    if (l == 0) knn_src[i*16+r] = bj;
    if (lj[0] == bj){
      #pragma unroll
      for (int s=0; s<15; s++){ lv[s]=lv[s+1]; lj[s]=lj[s+1]; }
      lv[15]=1e30f; lj[15]=0x7fffffff;
    }
  }
}

// z = 2*(log(exp(-d2)+eps) + gumbel).  Hard bound: z <= 2*g_max <= 33.3,
// so sum(exp(z-40)) never overflows -> no max pass needed at all.
// column partial sums of exp(z-40) over a 256-row chunk
__global__ __launch_bounds__(256) void k_colstats(const float* __restrict__ embF,
                                                  u32 ka, u32 kb, float* __restrict__ psum){
  __shared__ float4 sE4[768];                 // 256 rows x 12 floats
  int t = threadIdx.x;
  int j = blockIdx.x*256 + t;
  int i0 = blockIdx.y*256;
  const float4* gF = (const float4*)embF;
  #pragma unroll
  for (int q=0; q<3; q++) sE4[t + 256*q] = gF[(size_t)i0*3 + t + 256*q];
  __syncthreads();
  float4 b0 = gF[j*3+0], b1 = gF[j*3+1], b2 = gF[j*3+2];
  float sej = b2.z;
  float s = 0.0f;
  for (int r=0; r<256; r++){
    float4 a0 = sE4[r*3+0], a1 = sE4[r*3+1], a2 = sE4[r*3+2];
    float dot = a0.x*b0.x + a0.y*b0.y + a0.z*b0.z + a0.w*b0.w
              + a1.x*b1.x + a1.y*b1.y + a1.z*b1.z + a1.w*b1.w
              + a2.x*b2.x + a2.y*b2.y;
    float d2 = fmaxf(a2.z + sej - 2.0f*dot, 0.0f);
    float u = u01(rbits(ka, kb, (u32)(i0+r)*8192u + (u32)j));
    float g = -__logf(-__logf(u + EPS20) + EPS20);
    float z = 2.0f*(__logf(__expf(-d2) + EPS20) + g);
    s += __expf(z - 40.0f);
  }
  psum[blockIdx.y*NN + j] = s;
}

// K_j = 40 + log(sum_chunks psum) ; probs = exp(z - K_j).  Written into embF[j][11].
__global__ __launch_bounds__(256) void k_colfin(const float* __restrict__ psum, float* __restrict__ embF){
  int j = blockIdx.x*256 + threadIdx.x;
  float S = 0.0f;
  for (int c=0; c<32; c++) S += psum[c*NN + j];
  embF[j*12+11] = 40.0f + __logf(S);
}

// per-row top-16 of y = z - K_j  (== top-16 of probs, exp monotone); exp deferred
__global__ __launch_bounds__(64) void k_rowtopk(const float* __restrict__ embF,
    u32 ka, u32 kb, int* __restrict__ soft_src, float* __restrict__ top_v){
  int i = blockIdx.x; int l = threadIdx.x;
  const float4* gF = (const float4*)embF;
  float4 b0 = gF[i*3+0], b1 = gF[i*3+1], b2 = gF[i*3+2];
  float sei = b2.z;
  float lv[16]; int lj[16];
  #pragma unroll
  for (int s=0; s<16; s++){ lv[s]=-1e30f; lj[s]=0x7fffffff; }
  for (int tt=0; tt<128; tt++){
    int j = l + 64*tt;
    float4 a0 = gF[j*3+0], a1 = gF[j*3+1], a2 = gF[j*3+2];
    float dot = a0.x*b0.x + a0.y*b0.y + a0.z*b0.z + a0.w*b0.w
              + a1.x*b1.x + a1.y*b1.y + a1.z*b1.z + a1.w*b1.w
              + a2.x*b2.x + a2.y*b2.y;
    float d2 = fmaxf(a2.z + sei - 2.0f*dot, 0.0f);
    float u = u01(rbits(ka, kb, (u32)i*8192u + (u32)j));
    float g = -__logf(-__logf(u + EPS20) + EPS20);
    float z = 2.0f*(__logf(__expf(-d2) + EPS20) + g);
    float y = z - a2.w;
    if (y > lv[15]){
      lv[15]=y; lj[15]=j;
      #pragma unroll
      for (int s=15; s>0; s--){
        if (lv[s] > lv[s-1]){ float tv=lv[s]; lv[s]=lv[s-1]; lv[s-1]=tv; int tj=lj[s]; lj[s]=lj[s-1]; lj[s-1]=tj; }
      }
    }
  }
  for (int r=0; r<16; r++){
    float bv = lv[0]; int bj = lj[0];
    #pragma unroll
    for (int off=32; off>=1; off>>=1){
      float ov = __shfl_xor(bv, off);
      int   oj = __shfl_xor(bj, off);
      if (ov > bv || (ov == bv && oj < bj)){ bv = ov; bj = oj; }
    }
    if (l == 0){ soft_src[i*16+r] = bj; top_v[i*16+r] = __expf(bv); }
    if (lj[0] == bj){
      #pragma unroll
      for (int s=0; s<15; s++){ lv[s]=lv[s+1]; lj[s]=lj[s+1]; }
      lv[15]=-1e30f; lj[15]=0x7fffffff;
    }
  }
}

// A = x@Wsrc, B = x@Wdst, V = x@Wlin  (8 rows per block)
__global__ __launch_bounds__(128) void k_xw(const float* __restrict__ x,
    const float* __restrict__ Wsrc, const float* __restrict__ Wdst, const float* __restrict__ Wlin,
    float* __restrict__ A, float* __restrict__ B, float* __restrict__ V){
  int g0 = blockIdx.x*8; int c = threadIdx.x;
  __shared__ float xs[8][64];
  for (int idx=c; idx<512; idx+=128) xs[idx>>6][idx&63] = x[(g0 + (idx>>6))*64 + (idx&63)];
  __syncthreads();
  float aA[8], aB[8], aV[8];
  #pragma unroll
  for (int g=0; g<8; g++){ aA[g]=0.0f; aB[g]=0.0f; aV[g]=0.0f; }
  for (int k=0; k<64; k++){
    float ws=Wsrc[k*128+c], wd=Wdst[k*128+c], wl=Wlin[k*128+c];
    #pragma unroll
    for (int g=0; g<8; g++){
      float xv = xs[g][k];
      aA[g] += xv*ws; aB[g] += xv*wd; aV[g] += xv*wl;
    }
  }
  #pragma unroll
  for (int g=0; g<8; g++){
    A[(g0+g)*128+c]=aA[g]; B[(g0+g)*128+c]=aB[g]; V[(g0+g)*128+c]=aV[g];
  }
}

// wave-private 8-edge x (2-col float2) GEMM over k=128: acc[e] = bias + ein[e]@W
#define GEMMW(WPTR, BPTR)                                                  \
  {                                                                        \
    const float2* Wv = (const float2*)(WPTR);                              \
    float2 bb = ((const float2*)(BPTR))[l];                                \
    _Pragma("unroll")                                                      \
    for (int e=0; e<8; e++) acc[e] = bb;                                   \
    for (int kg=0; kg<32; kg++){                                           \
      float2 w0 = Wv[(4*kg+0)*64 + l];                                     \
      float2 w1 = Wv[(4*kg+1)*64 + l];                                     \
      float2 w2 = Wv[(4*kg+2)*64 + l];                                     \
      float2 w3 = Wv[(4*kg+3)*64 + l];                                     \
      _Pragma("unroll")                                                    \
      for (int e=0; e<8; e++){                                             \
        const float4 ev = *(const float4*)(&ein[e0+e][4*kg]);              \
        acc[e].x += ev.x*w0.x + ev.y*w1.x + ev.z*w2.x + ev.w*w3.x;         \
        acc[e].y += ev.x*w0.y + ev.y*w1.y + ev.z*w2.y + ev.w*w3.y;         \
      }                                                                    \
    }                                                                      \
  }

// PointTransformerConv, per-target fused. 256 threads = 4 waves x 8 edges,
// 2 adjacent cols per thread (float2 -> v_pk_fma_f32). Each GEMM row depends
// only on its own LDS row -> waves run barrier-free until softmax combine.
__global__ __launch_bounds__(256,4) void k_edge(const float* __restrict__ pos,
    const int* __restrict__ soft_src, const float* __restrict__ top_v, const int* __restrict__ knn_src,
    const float* __restrict__ A, const float* __restrict__ B, const float* __restrict__ V,
    const float* __restrict__ Wp1, const float* __restrict__ bp1,
    const float* __restrict__ Wp2, const float* __restrict__ bp2,
    const float* __restrict__ Wa1, const float* __restrict__ ba1,
    const float* __restrict__ Wa2, const float* __restrict__ ba2,
    float* __restrict__ h){
  int i = blockIdx.x; int t = threadIdx.x;
  int l = t & 63; int w = t >> 6; int e0 = w*8;
  __shared__ float ein[32][128];
  __shared__ int   ssrc[32];
  __shared__ float sw[32];
  __shared__ float sdp[32][3];
  if (t < 32){
    int s; float wt;
    if (t < 16){ s = soft_src[i*16+t]; wt = top_v[i*16+t]; }
    else       { s = knn_src[i*16+(t-16)]; wt = 1.0f; }
    ssrc[t]=s; sw[t]=wt;
    sdp[t][0]=pos[i*3]-pos[s*3]; sdp[t][1]=pos[i*3+1]-pos[s*3+1]; sdp[t][2]=pos[i*3+2]-pos[s*3+2];
  }
  __syncthreads();
  float2 acc[8], dl[8];
  // ph = relu(dpos @ Wp1 + bp1)
  {
    const float2* W1v = (const float2*)Wp1;
    float2 r0 = W1v[l], r1 = W1v[64+l], r2 = W1v[128+l];
    float2 bb = ((const float2*)bp1)[l];
    #pragma unroll
    for (int e=0; e<8; e++){
      float d0=sdp[e0+e][0], d1=sdp[e0+e][1], d2=sdp[e0+e][2];
      float2 v;
      v.x = fmaxf(d0*r0.x + d1*r1.x + d2*r2.x + bb.x, 0.0f);
      v.y = fmaxf(d0*r0.y + d1*r1.y + d2*r2.y + bb.y, 0.0f);
      *(float2*)(&ein[e0+e][2*l]) = v;
    }
  }
  // delta = ph @ Wp2 + bp2
  GEMMW(Wp2, bp2);
  #pragma unroll
  for (int e=0; e<8; e++) dl[e] = acc[e];
  // q = B[i] - A[src] + delta
  {
    float2 bi = *(const float2*)(&B[i*128 + 2*l]);
    #pragma unroll
    for (int e=0; e<8; e++){
      float2 av = *(const float2*)(&A[ssrc[e0+e]*128 + 2*l]);
      float2 v; v.x = bi.x - av.x + dl[e].x; v.y = bi.y - av.y + dl[e].y;
      *(float2*)(&ein[e0+e][2*l]) = v;
    }
  }
  // ah = relu(q @ Wa1 + ba1)
  GEMMW(Wa1, ba1);
  #pragma unroll
  for (int e=0; e<8; e++){
    float2 v; v.x = fmaxf(acc[e].x, 0.0f); v.y = fmaxf(acc[e].y, 0.0f);
    *(float2*)(&ein[e0+e][2*l]) = v;
  }
  // logits = ah @ Wa2 + ba2
  GEMMW(Wa2, ba2);
  // cross-wave softmax over 32 edges; partial buffers reuse dead ein rows:
  // m: floats [0,512), s: [512,1024), h: [1024,1536)
  float* rbuf = &ein[0][0];
  float2 m2 = acc[0];
  #pragma unroll
  for (int e=1; e<8; e++){ m2.x = fmaxf(m2.x, acc[e].x); m2.y = fmaxf(m2.y, acc[e].y); }
  __syncthreads();                                   // all GEMM3 LDS reads done
  *(float2*)(&rbuf[w*128 + 2*l]) = m2;
  __syncthreads();
  float2 M; M.x = -1e30f; M.y = -1e30f;
  #pragma unroll
  for (int ww=0; ww<4; ww++){
    float2 mm = *(const float2*)(&rbuf[ww*128 + 2*l]);
    M.x = fmaxf(M.x, mm.x); M.y = fmaxf(M.y, mm.y);
  }
  float2 s2; s2.x=0.0f; s2.y=0.0f;
  float2 h2; h2.x=0.0f; h2.y=0.0f;
  #pragma unroll
  for (int e=0; e<8; e++){
    int s = ssrc[e0+e]; float wt = sw[e0+e];
    float2 vv = *(const float2*)(&V[s*128 + 2*l]);
    float px = __expf(acc[e].x - M.x);
    float py = __expf(acc[e].y - M.y);
    s2.x += px; s2.y += py;
    h2.x += px*(vv.x + dl[e].x)*wt;
    h2.y += py*(vv.y + dl[e].y)*wt;
  }
  *(float2*)(&rbuf[512  + w*128 + 2*l]) = s2;
  *(float2*)(&rbuf[1024 + w*128 + 2*l]) = h2;
  __syncthreads();
  if (w == 0){
    float2 S; S.x=0.0f; S.y=0.0f;
    float2 H; H.x=0.0f; H.y=0.0f;
    #pragma unroll
    for (int ww=0; ww<4; ww++){
      float2 sv = *(const float2*)(&rbuf[512  + ww*128 + 2*l]);
      float2 hv = *(const float2*)(&rbuf[1024 + ww*128 + 2*l]);
      S.x += sv.x; S.y += sv.y; H.x += hv.x; H.y += hv.y;
    }
    float2 o; o.x = H.x/(S.x + 1e-16f); o.y = H.y/(S.y + 1e-16f);
    *(float2*)(&h[i*128 + 2*l]) = o;
  }
}

// hd = relu(h @ Wd + bd)
__global__ __launch_bounds__(128) void k_down(const float* __restrict__ h,
    const float* __restrict__ Wd, const float* __restrict__ bd, float* __restrict__ hd){
  int g0 = blockIdx.x*8; int c = threadIdx.x;
  __shared__ float hs[8][128];
  for (int idx=c; idx<1024; idx+=128) hs[idx>>7][idx&127] = h[(g0 + (idx>>7))*128 + (idx&127)];
  __syncthreads();
  float acc[8]; float b = bd[c];
  #pragma unroll
  for (int g=0; g<8; g++) acc[g] = b;
  for (int k=0; k<128; k+=4){
    float w0=Wd[(k+0)*128+c], w1=Wd[(k+1)*128+c], w2=Wd[(k+2)*128+c], w3=Wd[(k+3)*128+c];
    #pragma unroll
    for (int g=0; g<8; g++){
      const float4 ev = *(const float4*)(&hs[g][k]);
      acc[g] += ev.x*w0 + ev.y*w1 + ev.z*w2 + ev.w*w3;
    }
  }
  #pragma unroll
  for (int g=0; g<8; g++) hd[(g0+g)*128+c] = fmaxf(acc[g], 0.0f);
}

// y = max(hd[i], max over 32 neighbors hd[src])
__global__ __launch_bounds__(128) void k_pool(const float* __restrict__ hd,
    const int* __restrict__ soft_src, const int* __restrict__ knn_src, float* __restrict__ y){
  int i = blockIdx.x; int c = threadIdx.x;
  __shared__ int ss[32];
  if (c < 16) ss[c] = soft_src[i*16+c];
  else if (c < 32) ss[c] = knn_src[i*16+(c-16)];
  __syncthreads();
  float p = hd[i*128+c];
  for (int e=0; e<32; e++) p = fmaxf(p, hd[ss[e]*128+c]);
  y[i*128+c] = p;
}

// ranks = sorted-unique inverse (count of nonzero bins with smaller vid)
__global__ __launch_bounds__(256) void k_scan(const int* __restrict__ hist,
    int* __restrict__ rank, int* __restrict__ ucnt, int* __restrict__ Uo){
  __shared__ int part[256];
  int t = threadIdx.x;
  int base = t*32;
  int cnt = 0;
  for (int b=0; b<32; b++) cnt += (hist[base+b] > 0);
  part[t] = cnt;
  __syncthreads();
  if (t == 0){
    int run = 0;
    for (int q=0; q<256; q++){ int v = part[q]; part[q] = run; run += v; }
    Uo[0] = run;
  }
  __syncthreads();
  int run = part[t];
  for (int b=0; b<32; b++){
    int bin = base + b;
    rank[bin] = run;
    int hv = hist[bin];
    if (hv > 0){ ucnt[run] = hv; run++; }
  }
}

__global__ __launch_bounds__(128) void k_agg(const float* __restrict__ y, const float* __restrict__ pos,
    const int* __restrict__ vid, const int* __restrict__ rank,
    float* __restrict__ accx, float* __restrict__ accp){
  int n = blockIdx.x; int c = threadIdx.x;
  int r = rank[vid[n]];
  atomicAdd(&accx[r*128+c], y[n*128+c]);
  if (c < 3) atomicAdd(&accp[r*3+c], pos[n*3+c]);
}

__global__ __launch_bounds__(128) void k_final(const float* __restrict__ accx, const float* __restrict__ accp,
    const int* __restrict__ ucnt, const int* __restrict__ Uo, float* __restrict__ out){
  int r = blockIdx.x; int c = threadIdx.x;
  int u = Uo[0];
  float cnt = (r < u) ? (float)ucnt[r] : 0.0f;
  float den = fmaxf(cnt, 1.0f);
  out[r*128+c] = (r < u) ? accx[r*128+c]/den : 0.0f;
  if (c < 3) out[(size_t)NN*128 + r*3 + c] = (r < u) ? accp[r*3+c]/den : 0.0f;
  if (c == 0) out[(size_t)NN*128 + (size_t)NN*3 + r] = cnt;
}

// ---------------- launcher ----------------
extern "C" void kernel_launch(void* const* d_in, const int* in_sizes, int n_in,
                              void* d_out, int out_size, void* d_ws, size_t ws_size,
                              hipStream_t stream){
  (void)in_sizes; (void)n_in; (void)out_size; (void)ws_size;
  const float* x    = (const float*)d_in[0];
  const float* pos  = (const float*)d_in[1];
  const float* Wg1  = (const float*)d_in[2];
  const float* bg1  = (const float*)d_in[3];
  const float* Wg2  = (const float*)d_in[4];
  const float* bg2  = (const float*)d_in[5];
  const float* Wlin = (const float*)d_in[6];
  const float* Wsrc = (const float*)d_in[7];
  const float* Wdst = (const float*)d_in[8];
  const float* Wp1  = (const float*)d_in[9];
  const float* bp1  = (const float*)d_in[10];
  const float* Wp2  = (const float*)d_in[11];
  const float* bp2  = (const float*)d_in[12];
  const float* Wa1  = (const float*)d_in[13];
  const float* ba1  = (const float*)d_in[14];
  const float* Wa2  = (const float*)d_in[15];
  const float* ba2  = (const float*)d_in[16];
  const float* Wd   = (const float*)d_in[17];
  const float* bd   = (const float*)d_in[18];

  char* ws = (char*)d_ws;
  float* embF   = (float*)(ws + OFF_EMBF);
  float* sp     = (float*)(ws + OFF_SP);
  float* psum   = (float*)(ws + OFF_PSUM);
  int*   ssrc   = (int*)  (ws + OFF_SSRC);
  float* topv   = (float*)(ws + OFF_TOPV);
  int*   ksrc   = (int*)  (ws + OFF_KSRC);
  float* A      = (float*)(ws + OFF_A);
  float* B      = (float*)(ws + OFF_B);
  float* V      = (float*)(ws + OFF_V);
  float* h      = (float*)(ws + OFF_H);
  float* hd     = (float*)(ws + OFF_HD);
  float* y      = (float*)(ws + OFF_Y);
  float* accx   = (float*)(ws + OFF_ACCX);
  float* accp   = (float*)(ws + OFF_ACCP);
  int*   hist   = (int*)  (ws + OFF_HIST);
  int*   rank   = (int*)  (ws + OFF_RANK);
  int*   ucnt   = (int*)  (ws + OFF_UCNT);
  int*   vid    = (int*)  (ws + OFF_VID);
  float* meta_f = (float*)(ws + OFF_META);
  int*   meta_i = (int*)  (ws + OFF_META + 16);
  int*   Uo     = (int*)  (ws + OFF_META + 32);

  // rk = jax.random.split(jax.random.key(42), 2)  -- host threefry
  u32 rk0a, rk0b, rk1a, rk1b;
  tf2x32(0u, 42u, 0u, 0u, rk0a, rk0b);   // foldlike split: key_j = threefry(key, (0, j))
  tf2x32(0u, 42u, 0u, 1u, rk1a, rk1b);

  hipMemsetAsync(hist, 0, 8192*4, stream);
  hipMemsetAsync(accx, 0, (size_t)8192*128*4, stream);
  hipMemsetAsync(accp, 0, (size_t)8192*3*4, stream);

  k_prep<<<1, 1024, 0, stream>>>(pos, meta_f, meta_i);
  k_vid<<<32, 256, 0, stream>>>(pos, meta_f, meta_i, vid, hist, sp);
  k_emb<<<8192, 64, 0, stream>>>(x, Wg1, bg1, Wg2, bg2, rk0a, rk0b, embF);
  k_knn<<<8192, 64, 0, stream>>>(pos, sp, ksrc);
  k_colstats<<<dim3(32,32), 256, 0, stream>>>(embF, rk1a, rk1b, psum);
  k_colfin<<<32, 256, 0, stream>>>(psum, embF);
  k_rowtopk<<<8192, 64, 0, stream>>>(embF, rk1a, rk1b, ssrc, topv);
  k_xw<<<1024, 128, 0, stream>>>(x, Wsrc, Wdst, Wlin, A, B, V);
  k_edge<<<8192, 256, 0, stream>>>(pos, ssrc, topv, ksrc, A, B, V,
                                   Wp1, bp1, Wp2, bp2, Wa1, ba1, Wa2, ba2, h);
  k_down<<<1024, 128, 0, stream>>>(h, Wd, bd, hd);
  k_pool<<<8192, 128, 0, stream>>>(hd, ssrc, ksrc, y);
  k_scan<<<1, 256, 0, stream>>>(hist, rank, ucnt, Uo);
  k_agg<<<8192, 128, 0, stream>>>(y, pos, vid, rank, accx, accp);
  k_final<<<8192, 128, 0, stream>>>(accx, accp, ucnt, Uo, (float*)d_out);
}

// Round 4
// 1508.372 us; speedup vs baseline: 1.0167x; 1.0167x over previous
//
#include <hip/hip_runtime.h>
#include <stdint.h>

// ---------------------------------------------------------------------------
// Enc_block: KNN graph + gumbel-softmax soft edges + PointTransformerConv +
// down + neighbor max-pool + GridSampling.  N=8192, Cin=64, Cout=128, K=16.
// ---------------------------------------------------------------------------

#define PARTITIONABLE 1   // JAX >= 0.5: threefry_partitionable default True

typedef unsigned int u32;

#define NN 8192
#define EPS20 1e-20f

// ---------------- threefry2x32 (JAX key schedule) ----------------
__host__ __device__ static inline u32 rotl32(u32 v, int r){ return (v<<r)|(v>>(32-r)); }

__host__ __device__ static inline void tf2x32(u32 k0, u32 k1, u32 c0, u32 c1, u32& o0, u32& o1){
  u32 ks2 = k0 ^ k1 ^ 0x1BD11BDAu;
  u32 x0 = c0 + k0;
  u32 x1 = c1 + k1;
#define TFR(r) x0 += x1; x1 = rotl32(x1,(r)); x1 ^= x0;
  TFR(13) TFR(15) TFR(26) TFR(6)
  x0 += k1;  x1 += ks2 + 1u;
  TFR(17) TFR(29) TFR(16) TFR(24)
  x0 += ks2; x1 += k0 + 2u;
  TFR(13) TFR(15) TFR(26) TFR(6)
  x0 += k0;  x1 += k1 + 3u;
  TFR(17) TFR(29) TFR(16) TFR(24)
  x0 += k1;  x1 += ks2 + 4u;
  TFR(13) TFR(15) TFR(26) TFR(6)
  x0 += ks2; x1 += k0 + 5u;
#undef TFR
  o0 = x0; o1 = x1;
}

__device__ static inline u32 rbits(u32 k0, u32 k1, u32 idx){
#if PARTITIONABLE
  u32 o0,o1; tf2x32(k0,k1, 0u, idx, o0,o1);   // 64-bit counter (0, idx)
  return o0 ^ o1;                              // 32-bit fold
#else
  u32 o0,o1; tf2x32(k0,k1, 0u, idx, o0,o1);
  return o0;
#endif
}

__device__ static inline float u01(u32 b){
  return __uint_as_float((b>>9) | 0x3f800000u) - 1.0f;   // [0,1), JAX formula
}

// ---------------- workspace layout ----------------
static constexpr size_t OFF_EMBF = 0;                              // [8192][12] f32: e[10], se, K
static constexpr size_t OFF_SP   = OFF_EMBF + (size_t)8192*12*4;
static constexpr size_t OFF_PSUM = OFF_SP   + (size_t)8192*4;      // [32][8192]
static constexpr size_t OFF_SSRC = OFF_PSUM + (size_t)32*8192*4;   // int [8192][16]
static constexpr size_t OFF_TOPV = OFF_SSRC + (size_t)8192*16*4;
static constexpr size_t OFF_KSRC = OFF_TOPV + (size_t)8192*16*4;   // int [8192][16]
static constexpr size_t OFF_A    = OFF_KSRC + (size_t)8192*16*4;   // x@Wsrc
static constexpr size_t OFF_B    = OFF_A    + (size_t)8192*128*4;  // x@Wdst
static constexpr size_t OFF_V    = OFF_B    + (size_t)8192*128*4;  // x@Wlin
static constexpr size_t OFF_H    = OFF_V    + (size_t)8192*128*4;  // conv out
static constexpr size_t OFF_HD   = OFF_H    + (size_t)8192*128*4;  // after down
static constexpr size_t OFF_Y    = OFF_HD   + (size_t)8192*128*4;  // after pool
static constexpr size_t OFF_ACCX = OFF_Y    + (size_t)8192*128*4;  // voxel sums
static constexpr size_t OFF_ACCP = OFF_ACCX + (size_t)8192*128*4;  // voxel pos sums
static constexpr size_t OFF_HIST = OFF_ACCP + (size_t)8192*3*4;    // int [8192]
static constexpr size_t OFF_RANK = OFF_HIST + (size_t)8192*4;      // int [8192]
static constexpr size_t OFF_UCNT = OFF_RANK + (size_t)8192*4;      // int [8192]
static constexpr size_t OFF_VID  = OFF_UCNT + (size_t)8192*4;      // int [8192]
static constexpr size_t OFF_META = OFF_VID  + (size_t)8192*4;      // posmin f[3] @0, nv i[3] @16B, U i @32B

// ---------------- kernels ----------------

// pos column-min and voxel-grid extents (single block)
__global__ __launch_bounds__(1024) void k_prep(const float* __restrict__ pos,
                                               float* __restrict__ meta_f, int* __restrict__ meta_i){
  __shared__ float red[1024][3];
  __shared__ int   redi[1024][3];
  __shared__ float pmn[3];
  int t = threadIdx.x;
  float mn[3] = {1e30f,1e30f,1e30f};
  for (int n=t; n<NN; n+=1024){
    #pragma unroll
    for (int d=0; d<3; d++) mn[d] = fminf(mn[d], pos[n*3+d]);
  }
  #pragma unroll
  for (int d=0; d<3; d++) red[t][d] = mn[d];
  __syncthreads();
  for (int s=512; s>0; s>>=1){
    if (t < s){ for (int d=0; d<3; d++) red[t][d] = fminf(red[t][d], red[t+s][d]); }
    __syncthreads();
  }
  if (t < 3) pmn[t] = red[0][t];
  __syncthreads();
  int mx[3] = {0,0,0};
  for (int n=t; n<NN; n+=1024){
    #pragma unroll
    for (int d=0; d<3; d++){
      int v = (int)floorf((pos[n*3+d] - pmn[d]) * 2.0f);   // /0.5 == *2 exactly
      mx[d] = max(mx[d], v);
    }
  }
  #pragma unroll
  for (int d=0; d<3; d++) redi[t][d] = mx[d];
  __syncthreads();
  for (int s=512; s>0; s>>=1){
    if (t < s){ for (int d=0; d<3; d++) redi[t][d] = max(redi[t][d], redi[t+s][d]); }
    __syncthreads();
  }
  if (t == 0){
    meta_f[0]=pmn[0]; meta_f[1]=pmn[1]; meta_f[2]=pmn[2];
    meta_i[0]=redi[0][0]+1; meta_i[1]=redi[0][1]+1; meta_i[2]=redi[0][2]+1;
  }
}

// voxel id + histogram + pos squared norms
__global__ __launch_bounds__(256) void k_vid(const float* __restrict__ pos,
                                             const float* __restrict__ meta_f, const int* __restrict__ meta_i,
                                             int* __restrict__ vid, int* __restrict__ hist,
                                             float* __restrict__ sp){
  int n = blockIdx.x*256 + threadIdx.x;
  float p0=pos[n*3], p1=pos[n*3+1], p2=pos[n*3+2];
  sp[n] = p0*p0 + p1*p1 + p2*p2;
  int v0 = (int)floorf((p0-meta_f[0])*2.0f);
  int v1 = (int)floorf((p1-meta_f[1])*2.0f);
  int v2 = (int)floorf((p2-meta_f[2])*2.0f);
  int id = (v0*meta_i[1] + v1)*meta_i[2] + v2;
  vid[n] = id;
  atomicAdd(&hist[id], 1);
}

// embF[i] = { relu(x@Wg1+bg1)@Wg2+bg2 + u*0.001  (10), |emb|^2, 0 }
__global__ __launch_bounds__(64) void k_emb(const float* __restrict__ x,
    const float* __restrict__ Wg1, const float* __restrict__ bg1,
    const float* __restrict__ Wg2, const float* __restrict__ bg2,
    u32 ka, u32 kb, float* __restrict__ embF){
  int i = blockIdx.x; int t = threadIdx.x;
  __shared__ float xs[64], hs[64], esq[10];
  xs[t] = x[i*64+t];
  __syncthreads();
  float a = bg1[t];
  for (int k=0; k<64; k++) a += xs[k]*Wg1[k*64+t];
  hs[t] = fmaxf(a, 0.0f);
  __syncthreads();
  if (t < 10){
    float e = bg2[t];
    for (int k=0; k<64; k++) e += hs[k]*Wg2[k*10+t];
    e += u01(rbits(ka, kb, (u32)(i*10+t))) * 0.001f;
    embF[i*12+t] = e;
    esq[t] = e*e;
  }
  __syncthreads();
  if (t == 0){
    float ssum = 0.0f;
    #pragma unroll
    for (int d=0; d<10; d++) ssum += esq[d];
    embF[i*12+10] = ssum;
    embF[i*12+11] = 0.0f;
  }
}

// KNN: top-16 smallest d2 per row (diag excluded), ties -> lower index
__global__ __launch_bounds__(64) void k_knn(const float* __restrict__ pos, const float* __restrict__ sp,
                                            int* __restrict__ knn_src){
  int i = blockIdx.x; int l = threadIdx.x;
  float pi0=pos[i*3], pi1=pos[i*3+1], pi2=pos[i*3+2];
  float spi = sp[i];
  float lv[16]; int lj[16];
  #pragma unroll
  for (int s=0; s<16; s++){ lv[s]=1e30f; lj[s]=0x7fffffff; }
  for (int tt=0; tt<128; tt++){
    int j = l + 64*tt;
    if (j == i) continue;
    float d = spi + sp[j] - 2.0f*(pi0*pos[j*3] + pi1*pos[j*3+1] + pi2*pos[j*3+2]);
    d = fmaxf(d, 0.0f);
    if (d < lv[15]){
      lv[15]=d; lj[15]=j;
      #pragma unroll
      for (int s=15; s>0; s--){
        if (lv[s] < lv[s-1]){ float tv=lv[s]; lv[s]=lv[s-1]; lv[s-1]=tv; int tj=lj[s]; lj[s]=lj[s-1]; lj[s-1]=tj; }
      }
    }
  }
  for (int r=0; r<16; r++){
    float bv = lv[0]; int bj = lj[0];
    #pragma unroll
    for (int off=32; off>=1; off>>=1){
      float ov = __shfl_xor(bv, off);
      int   oj = __shfl_xor(bj, off);
      if (ov < bv || (ov == bv && oj < bj)){ bv = ov; bj = oj; }
    }
    if (l == 0) knn_src[i*16+r] = bj;
    if (lj[0] == bj){
      #pragma unroll
      for (int s=0; s<15; s++){ lv[s]=lv[s+1]; lj[s]=lj[s+1]; }
      lv[15]=1e30f; lj[15]=0x7fffffff;
    }
  }
}

// z = 2*(log(exp(-d2)+eps) + gumbel).  Hard bound: z <= 2*g_max <= 33.3,
// so sum(exp(z-40)) never overflows -> no max pass needed at all.
// column partial sums of exp(z-40) over a 256-row chunk
__global__ __launch_bounds__(256) void k_colstats(const float* __restrict__ embF,
                                                  u32 ka, u32 kb, float* __restrict__ psum){
  __shared__ float4 sE4[768];                 // 256 rows x 12 floats
  int t = threadIdx.x;
  int j = blockIdx.x*256 + t;
  int i0 = blockIdx.y*256;
  const float4* gF = (const float4*)embF;
  #pragma unroll
  for (int q=0; q<3; q++) sE4[t + 256*q] = gF[(size_t)i0*3 + t + 256*q];
  __syncthreads();
  float4 b0 = gF[j*3+0], b1 = gF[j*3+1], b2 = gF[j*3+2];
  float sej = b2.z;
  float s = 0.0f;
  for (int r=0; r<256; r++){
    float4 a0 = sE4[r*3+0], a1 = sE4[r*3+1], a2 = sE4[r*3+2];
    float dot = a0.x*b0.x + a0.y*b0.y + a0.z*b0.z + a0.w*b0.w
              + a1.x*b1.x + a1.y*b1.y + a1.z*b1.z + a1.w*b1.w
              + a2.x*b2.x + a2.y*b2.y;
    float d2 = fmaxf(a2.z + sej - 2.0f*dot, 0.0f);
    float u = u01(rbits(ka, kb, (u32)(i0+r)*8192u + (u32)j));
    float g = -__logf(-__logf(u + EPS20) + EPS20);
    float z = 2.0f*(__logf(__expf(-d2) + EPS20) + g);
    s += __expf(z - 40.0f);
  }
  psum[blockIdx.y*NN + j] = s;
}

// K_j = 40 + log(sum_chunks psum) ; probs = exp(z - K_j).  Written into embF[j][11].
__global__ __launch_bounds__(256) void k_colfin(const float* __restrict__ psum, float* __restrict__ embF){
  int j = blockIdx.x*256 + threadIdx.x;
  float S = 0.0f;
  for (int c=0; c<32; c++) S += psum[c*NN + j];
  embF[j*12+11] = 40.0f + __logf(S);
}

// per-row top-16 of y = z - K_j  (== top-16 of probs, exp monotone); exp deferred
__global__ __launch_bounds__(64) void k_rowtopk(const float* __restrict__ embF,
    u32 ka, u32 kb, int* __restrict__ soft_src, float* __restrict__ top_v){
  int i = blockIdx.x; int l = threadIdx.x;
  const float4* gF = (const float4*)embF;
  float4 b0 = gF[i*3+0], b1 = gF[i*3+1], b2 = gF[i*3+2];
  float sei = b2.z;
  float lv[16]; int lj[16];
  #pragma unroll
  for (int s=0; s<16; s++){ lv[s]=-1e30f; lj[s]=0x7fffffff; }
  for (int tt=0; tt<128; tt++){
    int j = l + 64*tt;
    float4 a0 = gF[j*3+0], a1 = gF[j*3+1], a2 = gF[j*3+2];
    float dot = a0.x*b0.x + a0.y*b0.y + a0.z*b0.z + a0.w*b0.w
              + a1.x*b1.x + a1.y*b1.y + a1.z*b1.z + a1.w*b1.w
              + a2.x*b2.x + a2.y*b2.y;
    float d2 = fmaxf(a2.z + sei - 2.0f*dot, 0.0f);
    float u = u01(rbits(ka, kb, (u32)i*8192u + (u32)j));
    float g = -__logf(-__logf(u + EPS20) + EPS20);
    float z = 2.0f*(__logf(__expf(-d2) + EPS20) + g);
    float y = z - a2.w;
    if (y > lv[15]){
      lv[15]=y; lj[15]=j;
      #pragma unroll
      for (int s=15; s>0; s--){
        if (lv[s] > lv[s-1]){ float tv=lv[s]; lv[s]=lv[s-1]; lv[s-1]=tv; int tj=lj[s]; lj[s]=lj[s-1]; lj[s-1]=tj; }
      }
    }
  }
  for (int r=0; r<16; r++){
    float bv = lv[0]; int bj = lj[0];
    #pragma unroll
    for (int off=32; off>=1; off>>=1){
      float ov = __shfl_xor(bv, off);
      int   oj = __shfl_xor(bj, off);
      if (ov > bv || (ov == bv && oj < bj)){ bv = ov; bj = oj; }
    }
    if (l == 0){ soft_src[i*16+r] = bj; top_v[i*16+r] = __expf(bv); }
    if (lj[0] == bj){
      #pragma unroll
      for (int s=0; s<15; s++){ lv[s]=lv[s+1]; lj[s]=lj[s+1]; }
      lv[15]=-1e30f; lj[15]=0x7fffffff;
    }
  }
}

// A = x@Wsrc, B = x@Wdst, V = x@Wlin  (8 rows per block)
__global__ __launch_bounds__(128) void k_xw(const float* __restrict__ x,
    const float* __restrict__ Wsrc, const float* __restrict__ Wdst, const float* __restrict__ Wlin,
    float* __restrict__ A, float* __restrict__ B, float* __restrict__ V){
  int g0 = blockIdx.x*8; int c = threadIdx.x;
  __shared__ float xs[8][64];
  for (int idx=c; idx<512; idx+=128) xs[idx>>6][idx&63] = x[(g0 + (idx>>6))*64 + (idx&63)];
  __syncthreads();
  float aA[8], aB[8], aV[8];
  #pragma unroll
  for (int g=0; g<8; g++){ aA[g]=0.0f; aB[g]=0.0f; aV[g]=0.0f; }
  for (int k=0; k<64; k++){
    float ws=Wsrc[k*128+c], wd=Wdst[k*128+c], wl=Wlin[k*128+c];
    #pragma unroll
    for (int g=0; g<8; g++){
      float xv = xs[g][k];
      aA[g] += xv*ws; aB[g] += xv*wd; aV[g] += xv*wl;
    }
  }
  #pragma unroll
  for (int g=0; g<8; g++){
    A[(g0+g)*128+c]=aA[g]; B[(g0+g)*128+c]=aB[g]; V[(g0+g)*128+c]=aV[g];
  }
}

// wave-private 8-edge x (2-col float2) GEMM over k=128: acc[e] = bias + ein[e]@W
#define GEMMW(WPTR, BPTR)                                                  \
  {                                                                        \
    const float2* __restrict__ Wv = (const float2*)(WPTR);                 \
    float2 bb = ((const float2*)(BPTR))[l];                                \
    _Pragma("unroll")                                                      \
    for (int e=0; e<8; e++) acc[e] = bb;                                   \
    const float2* __restrict__ Wp = Wv + l;                                \
    for (int kg=0; kg<32; kg++){                                           \
      float2 w0 = Wp[0];                                                   \
      float2 w1 = Wp[64];                                                  \
      float2 w2 = Wp[128];                                                 \
      float2 w3 = Wp[192];                                                 \
      Wp += 256;                                                           \
      _Pragma("unroll")                                                    \
      for (int e=0; e<8; e++){                                             \
        const float4 ev = *(const float4*)(&ein[e0+e][4*kg]);              \
        acc[e].x += ev.x*w0.x + ev.y*w1.x + ev.z*w2.x + ev.w*w3.x;         \
        acc[e].y += ev.x*w0.y + ev.y*w1.y + ev.z*w2.y + ev.w*w3.y;         \
      }                                                                    \
    }                                                                      \
  }

// PointTransformerConv, per-target fused. 256 threads = 4 waves x 8 edges,
// 2 adjacent cols per thread (float2). Each GEMM row depends only on its own
// LDS row -> waves run barrier-free until softmax combine.
// NOTE: no min-waves clause -- (256,4) forced VGPR=64 and catastrophic scratch
// spill (WRITE_SIZE 4MB -> 176MB, dur 580 -> 695us). Live state needs ~100 VGPR.
__global__ __launch_bounds__(256) void k_edge(const float* __restrict__ pos,
    const int* __restrict__ soft_src, const float* __restrict__ top_v, const int* __restrict__ knn_src,
    const float* __restrict__ A, const float* __restrict__ B, const float* __restrict__ V,
    const float* __restrict__ Wp1, const float* __restrict__ bp1,
    const float* __restrict__ Wp2, const float* __restrict__ bp2,
    const float* __restrict__ Wa1, const float* __restrict__ ba1,
    const float* __restrict__ Wa2, const float* __restrict__ ba2,
    float* __restrict__ h){
  int i = blockIdx.x; int t = threadIdx.x;
  int l = t & 63; int w = t >> 6; int e0 = w*8;
  __shared__ float ein[32][128];
  __shared__ int   ssrc[32];
  __shared__ float sw[32];
  __shared__ float sdp[32][3];
  if (t < 32){
    int s; float wt;
    if (t < 16){ s = soft_src[i*16+t]; wt = top_v[i*16+t]; }
    else       { s = knn_src[i*16+(t-16)]; wt = 1.0f; }
    ssrc[t]=s; sw[t]=wt;
    sdp[t][0]=pos[i*3]-pos[s*3]; sdp[t][1]=pos[i*3+1]-pos[s*3+1]; sdp[t][2]=pos[i*3+2]-pos[s*3+2];
  }
  __syncthreads();
  float2 acc[8], dl[8];
  // ph = relu(dpos @ Wp1 + bp1)
  {
    const float2* W1v = (const float2*)Wp1;
    float2 r0 = W1v[l], r1 = W1v[64+l], r2 = W1v[128+l];
    float2 bb = ((const float2*)bp1)[l];
    #pragma unroll
    for (int e=0; e<8; e++){
      float d0=sdp[e0+e][0], d1=sdp[e0+e][1], d2=sdp[e0+e][2];
      float2 v;
      v.x = fmaxf(d0*r0.x + d1*r1.x + d2*r2.x + bb.x, 0.0f);
      v.y = fmaxf(d0*r0.y + d1*r1.y + d2*r2.y + bb.y, 0.0f);
      *(float2*)(&ein[e0+e][2*l]) = v;
    }
  }
  // delta = ph @ Wp2 + bp2
  GEMMW(Wp2, bp2);
  #pragma unroll
  for (int e=0; e<8; e++) dl[e] = acc[e];
  // q = B[i] - A[src] + delta
  {
    float2 bi = *(const float2*)(&B[i*128 + 2*l]);
    #pragma unroll
    for (int e=0; e<8; e++){
      float2 av = *(const float2*)(&A[ssrc[e0+e]*128 + 2*l]);
      float2 v; v.x = bi.x - av.x + dl[e].x; v.y = bi.y - av.y + dl[e].y;
      *(float2*)(&ein[e0+e][2*l]) = v;
    }
  }
  // ah = relu(q @ Wa1 + ba1)
  GEMMW(Wa1, ba1);
  #pragma unroll
  for (int e=0; e<8; e++){
    float2 v; v.x = fmaxf(acc[e].x, 0.0f); v.y = fmaxf(acc[e].y, 0.0f);
    *(float2*)(&ein[e0+e][2*l]) = v;
  }
  // logits = ah @ Wa2 + ba2
  GEMMW(Wa2, ba2);
  // cross-wave softmax over 32 edges; partial buffers reuse dead ein rows:
  // m: floats [0,512), s: [512,1024), h: [1024,1536)
  float* rbuf = &ein[0][0];
  float2 m2 = acc[0];
  #pragma unroll
  for (int e=1; e<8; e++){ m2.x = fmaxf(m2.x, acc[e].x); m2.y = fmaxf(m2.y, acc[e].y); }
  __syncthreads();                                   // all GEMM3 LDS reads done
  *(float2*)(&rbuf[w*128 + 2*l]) = m2;
  __syncthreads();
  float2 M; M.x = -1e30f; M.y = -1e30f;
  #pragma unroll
  for (int ww=0; ww<4; ww++){
    float2 mm = *(const float2*)(&rbuf[ww*128 + 2*l]);
    M.x = fmaxf(M.x, mm.x); M.y = fmaxf(M.y, mm.y);
  }
  float2 s2; s2.x=0.0f; s2.y=0.0f;
  float2 h2; h2.x=0.0f; h2.y=0.0f;
  #pragma unroll
  for (int e=0; e<8; e++){
    int s = ssrc[e0+e]; float wt = sw[e0+e];
    float2 vv = *(const float2*)(&V[s*128 + 2*l]);
    float px = __expf(acc[e].x - M.x);
    float py = __expf(acc[e].y - M.y);
    s2.x += px; s2.y += py;
    h2.x += px*(vv.x + dl[e].x)*wt;
    h2.y += py*(vv.y + dl[e].y)*wt;
  }
  *(float2*)(&rbuf[512  + w*128 + 2*l]) = s2;
  *(float2*)(&rbuf[1024 + w*128 + 2*l]) = h2;
  __syncthreads();
  if (w == 0){
    float2 S; S.x=0.0f; S.y=0.0f;
    float2 H; H.x=0.0f; H.y=0.0f;
    #pragma unroll
    for (int ww=0; ww<4; ww++){
      float2 sv = *(const float2*)(&rbuf[512  + ww*128 + 2*l]);
      float2 hv = *(const float2*)(&rbuf[1024 + ww*128 + 2*l]);
      S.x += sv.x; S.y += sv.y; H.x += hv.x; H.y += hv.y;
    }
    float2 o; o.x = H.x/(S.x + 1e-16f); o.y = H.y/(S.y + 1e-16f);
    *(float2*)(&h[i*128 + 2*l]) = o;
  }
}

// hd = relu(h @ Wd + bd)
__global__ __launch_bounds__(128) void k_down(const float* __restrict__ h,
    const float* __restrict__ Wd, const float* __restrict__ bd, float* __restrict__ hd){
  int g0 = blockIdx.x*8; int c = threadIdx.x;
  __shared__ float hs[8][128];
  for (int idx=c; idx<1024; idx+=128) hs[idx>>7][idx&127] = h[(g0 + (idx>>7))*128 + (idx&127)];
  __syncthreads();
  float acc[8]; float b = bd[c];
  #pragma unroll
  for (int g=0; g<8; g++) acc[g] = b;
  for (int k=0; k<128; k+=4){
    float w0=Wd[(k+0)*128+c], w1=Wd[(k+1)*128+c], w2=Wd[(k+2)*128+c], w3=Wd[(k+3)*128+c];
    #pragma unroll
    for (int g=0; g<8; g++){
      const float4 ev = *(const float4*)(&hs[g][k]);
      acc[g] += ev.x*w0 + ev.y*w1 + ev.z*w2 + ev.w*w3;
    }
  }
  #pragma unroll
  for (int g=0; g<8; g++) hd[(g0+g)*128+c] = fmaxf(acc[g], 0.0f);
}

// y = max(hd[i], max over 32 neighbors hd[src])
__global__ __launch_bounds__(128) void k_pool(const float* __restrict__ hd,
    const int* __restrict__ soft_src, const int* __restrict__ knn_src, float* __restrict__ y){
  int i = blockIdx.x; int c = threadIdx.x;
  __shared__ int ss[32];
  if (c < 16) ss[c] = soft_src[i*16+c];
  else if (c < 32) ss[c] = knn_src[i*16+(c-16)];
  __syncthreads();
  float p = hd[i*128+c];
  for (int e=0; e<32; e++) p = fmaxf(p, hd[ss[e]*128+c]);
  y[i*128+c] = p;
}

// ranks = sorted-unique inverse (count of nonzero bins with smaller vid)
__global__ __launch_bounds__(256) void k_scan(const int* __restrict__ hist,
    int* __restrict__ rank, int* __restrict__ ucnt, int* __restrict__ Uo){
  __shared__ int part[256];
  int t = threadIdx.x;
  int base = t*32;
  int cnt = 0;
  for (int b=0; b<32; b++) cnt += (hist[base+b] > 0);
  part[t] = cnt;
  __syncthreads();
  if (t == 0){
    int run = 0;
    for (int q=0; q<256; q++){ int v = part[q]; part[q] = run; run += v; }
    Uo[0] = run;
  }
  __syncthreads();
  int run = part[t];
  for (int b=0; b<32; b++){
    int bin = base + b;
    rank[bin] = run;
    int hv = hist[bin];
    if (hv > 0){ ucnt[run] = hv; run++; }
  }
}

__global__ __launch_bounds__(128) void k_agg(const float* __restrict__ y, const float* __restrict__ pos,
    const int* __restrict__ vid, const int* __restrict__ rank,
    float* __restrict__ accx, float* __restrict__ accp){
  int n = blockIdx.x; int c = threadIdx.x;
  int r = rank[vid[n]];
  atomicAdd(&accx[r*128+c], y[n*128+c]);
  if (c < 3) atomicAdd(&accp[r*3+c], pos[n*3+c]);
}

__global__ __launch_bounds__(128) void k_final(const float* __restrict__ accx, const float* __restrict__ accp,
    const int* __restrict__ ucnt, const int* __restrict__ Uo, float* __restrict__ out){
  int r = blockIdx.x; int c = threadIdx.x;
  int u = Uo[0];
  float cnt = (r < u) ? (float)ucnt[r] : 0.0f;
  float den = fmaxf(cnt, 1.0f);
  out[r*128+c] = (r < u) ? accx[r*128+c]/den : 0.0f;
  if (c < 3) out[(size_t)NN*128 + r*3 + c] = (r < u) ? accp[r*3+c]/den : 0.0f;
  if (c == 0) out[(size_t)NN*128 + (size_t)NN*3 + r] = cnt;
}

// ---------------- launcher ----------------
extern "C" void kernel_launch(void* const* d_in, const int* in_sizes, int n_in,
                              void* d_out, int out_size, void* d_ws, size_t ws_size,
                              hipStream_t stream){
  (void)in_sizes; (void)n_in; (void)out_size; (void)ws_size;
  const float* x    = (const float*)d_in[0];
  const float* pos  = (const float*)d_in[1];
  const float* Wg1  = (const float*)d_in[2];
  const float* bg1  = (const float*)d_in[3];
  const float* Wg2  = (const float*)d_in[4];
  const float* bg2  = (const float*)d_in[5];
  const float* Wlin = (const float*)d_in[6];
  const float* Wsrc = (const float*)d_in[7];
  const float* Wdst = (const float*)d_in[8];
  const float* Wp1  = (const float*)d_in[9];
  const float* bp1  = (const float*)d_in[10];
  const float* Wp2  = (const float*)d_in[11];
  const float* bp2  = (const float*)d_in[12];
  const float* Wa1  = (const float*)d_in[13];
  const float* ba1  = (const float*)d_in[14];
  const float* Wa2  = (const float*)d_in[15];
  const float* ba2  = (const float*)d_in[16];
  const float* Wd   = (const float*)d_in[17];
  const float* bd   = (const float*)d_in[18];

  char* ws = (char*)d_ws;
  float* embF   = (float*)(ws + OFF_EMBF);
  float* sp     = (float*)(ws + OFF_SP);
  float* psum   = (float*)(ws + OFF_PSUM);
  int*   ssrc   = (int*)  (ws + OFF_SSRC);
  float* topv   = (float*)(ws + OFF_TOPV);
  int*   ksrc   = (int*)  (ws + OFF_KSRC);
  float* A      = (float*)(ws + OFF_A);
  float* B      = (float*)(ws + OFF_B);
  float* V      = (float*)(ws + OFF_V);
  float* h      = (float*)(ws + OFF_H);
  float* hd     = (float*)(ws + OFF_HD);
  float* y      = (float*)(ws + OFF_Y);
  float* accx   = (float*)(ws + OFF_ACCX);
  float* accp   = (float*)(ws + OFF_ACCP);
  int*   hist   = (int*)  (ws + OFF_HIST);
  int*   rank   = (int*)  (ws + OFF_RANK);
  int*   ucnt   = (int*)  (ws + OFF_UCNT);
  int*   vid    = (int*)  (ws + OFF_VID);
  float* meta_f = (float*)(ws + OFF_META);
  int*   meta_i = (int*)  (ws + OFF_META + 16);
  int*   Uo     = (int*)  (ws + OFF_META + 32);

  // rk = jax.random.split(jax.random.key(42), 2)  -- host threefry
  u32 rk0a, rk0b, rk1a, rk1b;
  tf2x32(0u, 42u, 0u, 0u, rk0a, rk0b);   // foldlike split: key_j = threefry(key, (0, j))
  tf2x32(0u, 42u, 0u, 1u, rk1a, rk1b);

  hipMemsetAsync(hist, 0, 8192*4, stream);
  hipMemsetAsync(accx, 0, (size_t)8192*128*4, stream);
  hipMemsetAsync(accp, 0, (size_t)8192*3*4, stream);

  k_prep<<<1, 1024, 0, stream>>>(pos, meta_f, meta_i);
  k_vid<<<32, 256, 0, stream>>>(pos, meta_f, meta_i, vid, hist, sp);
  k_emb<<<8192, 64, 0, stream>>>(x, Wg1, bg1, Wg2, bg2, rk0a, rk0b, embF);
  k_knn<<<8192, 64, 0, stream>>>(pos, sp, ksrc);
  k_colstats<<<dim3(32,32), 256, 0, stream>>>(embF, rk1a, rk1b, psum);
  k_colfin<<<32, 256, 0, stream>>>(psum, embF);
  k_rowtopk<<<8192, 64, 0, stream>>>(embF, rk1a, rk1b, ssrc, topv);
  k_xw<<<1024, 128, 0, stream>>>(x, Wsrc, Wdst, Wlin, A, B, V);
  k_edge<<<8192, 256, 0, stream>>>(pos, ssrc, topv, ksrc, A, B, V,
                                   Wp1, bp1, Wp2, bp2, Wa1, ba1, Wa2, ba2, h);
  k_down<<<1024, 128, 0, stream>>>(h, Wd, bd, hd);
  k_pool<<<8192, 128, 0, stream>>>(hd, ssrc, ksrc, y);
  k_scan<<<1, 256, 0, stream>>>(hist, rank, ucnt, Uo);
  k_agg<<<8192, 128, 0, stream>>>(y, pos, vid, rank, accx, accp);
  k_final<<<8192, 128, 0, stream>>>(accx, accp, ucnt, Uo, (float*)d_out);
}

// Round 5
// 1345.333 us; speedup vs baseline: 1.1399x; 1.1212x over previous
//
#include <hip/hip_runtime.h>
#include <stdint.h>

// ---------------------------------------------------------------------------
// Enc_block: KNN graph + gumbel-softmax soft edges + PointTransformerConv +
// down + neighbor max-pool + GridSampling.  N=8192, Cin=64, Cout=128, K=16.
// ---------------------------------------------------------------------------

#define PARTITIONABLE 1   // JAX >= 0.5: threefry_partitionable default True

typedef unsigned int u32;

#define NN 8192
#define EPS20 1e-20f

// ---------------- threefry2x32 (JAX key schedule) ----------------
__host__ __device__ static inline u32 rotl32(u32 v, int r){ return (v<<r)|(v>>(32-r)); }

__host__ __device__ static inline void tf2x32(u32 k0, u32 k1, u32 c0, u32 c1, u32& o0, u32& o1){
  u32 ks2 = k0 ^ k1 ^ 0x1BD11BDAu;
  u32 x0 = c0 + k0;
  u32 x1 = c1 + k1;
#define TFR(r) x0 += x1; x1 = rotl32(x1,(r)); x1 ^= x0;
  TFR(13) TFR(15) TFR(26) TFR(6)
  x0 += k1;  x1 += ks2 + 1u;
  TFR(17) TFR(29) TFR(16) TFR(24)
  x0 += ks2; x1 += k0 + 2u;
  TFR(13) TFR(15) TFR(26) TFR(6)
  x0 += k0;  x1 += k1 + 3u;
  TFR(17) TFR(29) TFR(16) TFR(24)
  x0 += k1;  x1 += ks2 + 4u;
  TFR(13) TFR(15) TFR(26) TFR(6)
  x0 += ks2; x1 += k0 + 5u;
#undef TFR
  o0 = x0; o1 = x1;
}

__device__ static inline u32 rbits(u32 k0, u32 k1, u32 idx){
  u32 o0,o1; tf2x32(k0,k1, 0u, idx, o0,o1);   // 64-bit counter (0, idx)
  return o0 ^ o1;                              // 32-bit fold
}

__device__ static inline float u01(u32 b){
  return __uint_as_float((b>>9) | 0x3f800000u) - 1.0f;   // [0,1), JAX formula
}

// ---------------- workspace layout ----------------
static constexpr size_t OFF_EMBF = 0;                              // [8192][12] f32: e[10], se, K
static constexpr size_t OFF_SP   = OFF_EMBF + (size_t)8192*12*4;
static constexpr size_t OFF_PSUM = OFF_SP   + (size_t)8192*4;      // [32][8192]
static constexpr size_t OFF_SSRC = OFF_PSUM + (size_t)32*8192*4;   // int [8192][16]
static constexpr size_t OFF_TOPV = OFF_SSRC + (size_t)8192*16*4;
static constexpr size_t OFF_KSRC = OFF_TOPV + (size_t)8192*16*4;   // int [8192][16]
static constexpr size_t OFF_A    = OFF_KSRC + (size_t)8192*16*4;   // x@Wsrc
static constexpr size_t OFF_B    = OFF_A    + (size_t)8192*128*4;  // x@Wdst
static constexpr size_t OFF_V    = OFF_B    + (size_t)8192*128*4;  // x@Wlin
static constexpr size_t OFF_H    = OFF_V    + (size_t)8192*128*4;  // conv out
static constexpr size_t OFF_HD   = OFF_H    + (size_t)8192*128*4;  // after down
static constexpr size_t OFF_Y    = OFF_HD   + (size_t)8192*128*4;  // after pool
static constexpr size_t OFF_ACCX = OFF_Y    + (size_t)8192*128*4;  // voxel sums
static constexpr size_t OFF_ACCP = OFF_ACCX + (size_t)8192*128*4;  // voxel pos sums
static constexpr size_t OFF_HIST = OFF_ACCP + (size_t)8192*3*4;    // int [8192]
static constexpr size_t OFF_RANK = OFF_HIST + (size_t)8192*4;      // int [8192]
static constexpr size_t OFF_UCNT = OFF_RANK + (size_t)8192*4;      // int [8192]
static constexpr size_t OFF_VID  = OFF_UCNT + (size_t)8192*4;      // int [8192]
static constexpr size_t OFF_META = OFF_VID  + (size_t)8192*4;      // posmin f[3] @0, nv i[3] @16B, U i @32B
static constexpr size_t OFF_KF   = OFF_META + 64;                  // f32 [8192] colmax-free K_j
static constexpr size_t OFF_Z    = (OFF_KF + (size_t)8192*4 + 255) & ~(size_t)255;  // f32 [8192][8192]
static constexpr size_t Z_BYTES  = (size_t)NN*NN*4;

// ---------------- kernels ----------------

// pos column-min and voxel-grid extents (single block)
__global__ __launch_bounds__(1024) void k_prep(const float* __restrict__ pos,
                                               float* __restrict__ meta_f, int* __restrict__ meta_i){
  __shared__ float red[1024][3];
  __shared__ int   redi[1024][3];
  __shared__ float pmn[3];
  int t = threadIdx.x;
  float mn[3] = {1e30f,1e30f,1e30f};
  for (int n=t; n<NN; n+=1024){
    #pragma unroll
    for (int d=0; d<3; d++) mn[d] = fminf(mn[d], pos[n*3+d]);
  }
  #pragma unroll
  for (int d=0; d<3; d++) red[t][d] = mn[d];
  __syncthreads();
  for (int s=512; s>0; s>>=1){
    if (t < s){ for (int d=0; d<3; d++) red[t][d] = fminf(red[t][d], red[t+s][d]); }
    __syncthreads();
  }
  if (t < 3) pmn[t] = red[0][t];
  __syncthreads();
  int mx[3] = {0,0,0};
  for (int n=t; n<NN; n+=1024){
    #pragma unroll
    for (int d=0; d<3; d++){
      int v = (int)floorf((pos[n*3+d] - pmn[d]) * 2.0f);   // /0.5 == *2 exactly
      mx[d] = max(mx[d], v);
    }
  }
  #pragma unroll
  for (int d=0; d<3; d++) redi[t][d] = mx[d];
  __syncthreads();
  for (int s=512; s>0; s>>=1){
    if (t < s){ for (int d=0; d<3; d++) redi[t][d] = max(redi[t][d], redi[t+s][d]); }
    __syncthreads();
  }
  if (t == 0){
    meta_f[0]=pmn[0]; meta_f[1]=pmn[1]; meta_f[2]=pmn[2];
    meta_i[0]=redi[0][0]+1; meta_i[1]=redi[0][1]+1; meta_i[2]=redi[0][2]+1;
  }
}

// voxel id + histogram + pos squared norms
__global__ __launch_bounds__(256) void k_vid(const float* __restrict__ pos,
                                             const float* __restrict__ meta_f, const int* __restrict__ meta_i,
                                             int* __restrict__ vid, int* __restrict__ hist,
                                             float* __restrict__ sp){
  int n = blockIdx.x*256 + threadIdx.x;
  float p0=pos[n*3], p1=pos[n*3+1], p2=pos[n*3+2];
  sp[n] = p0*p0 + p1*p1 + p2*p2;
  int v0 = (int)floorf((p0-meta_f[0])*2.0f);
  int v1 = (int)floorf((p1-meta_f[1])*2.0f);
  int v2 = (int)floorf((p2-meta_f[2])*2.0f);
  int id = (v0*meta_i[1] + v1)*meta_i[2] + v2;
  vid[n] = id;
  atomicAdd(&hist[id], 1);
}

// embF[i] = { relu(x@Wg1+bg1)@Wg2+bg2 + u*0.001  (10), |emb|^2, 0 }
__global__ __launch_bounds__(64) void k_emb(const float* __restrict__ x,
    const float* __restrict__ Wg1, const float* __restrict__ bg1,
    const float* __restrict__ Wg2, const float* __restrict__ bg2,
    u32 ka, u32 kb, float* __restrict__ embF){
  int i = blockIdx.x; int t = threadIdx.x;
  __shared__ float xs[64], hs[64], esq[10];
  xs[t] = x[i*64+t];
  __syncthreads();
  float a = bg1[t];
  for (int k=0; k<64; k++) a += xs[k]*Wg1[k*64+t];
  hs[t] = fmaxf(a, 0.0f);
  __syncthreads();
  if (t < 10){
    float e = bg2[t];
    for (int k=0; k<64; k++) e += hs[k]*Wg2[k*10+t];
    e += u01(rbits(ka, kb, (u32)(i*10+t))) * 0.001f;
    embF[i*12+t] = e;
    esq[t] = e*e;
  }
  __syncthreads();
  if (t == 0){
    float ssum = 0.0f;
    #pragma unroll
    for (int d=0; d<10; d++) ssum += esq[d];
    embF[i*12+10] = ssum;
    embF[i*12+11] = 0.0f;
  }
}

// KNN: top-16 smallest d2 per row (diag excluded), ties -> lower index
__global__ __launch_bounds__(64) void k_knn(const float* __restrict__ pos, const float* __restrict__ sp,
                                            int* __restrict__ knn_src){
  int i = blockIdx.x; int l = threadIdx.x;
  float pi0=pos[i*3], pi1=pos[i*3+1], pi2=pos[i*3+2];
  float spi = sp[i];
  float lv[16]; int lj[16];
  #pragma unroll
  for (int s=0; s<16; s++){ lv[s]=1e30f; lj[s]=0x7fffffff; }
  for (int tt=0; tt<128; tt++){
    int j = l + 64*tt;
    if (j == i) continue;
    float d = spi + sp[j] - 2.0f*(pi0*pos[j*3] + pi1*pos[j*3+1] + pi2*pos[j*3+2]);
    d = fmaxf(d, 0.0f);
    if (d < lv[15]){
      lv[15]=d; lj[15]=j;
      #pragma unroll
      for (int s=15; s>0; s--){
        if (lv[s] < lv[s-1]){ float tv=lv[s]; lv[s]=lv[s-1]; lv[s-1]=tv; int tj=lj[s]; lj[s]=lj[s-1]; lj[s-1]=tj; }
      }
    }
  }
  for (int r=0; r<16; r++){
    float bv = lv[0]; int bj = lj[0];
    #pragma unroll
    for (int off=32; off>=1; off>>=1){
      float ov = __shfl_xor(bv, off);
      int   oj = __shfl_xor(bj, off);
      if (ov < bv || (ov == bv && oj < bj)){ bv = ov; bj = oj; }
    }
    if (l == 0) knn_src[i*16+r] = bj;
    if (lj[0] == bj){
      #pragma unroll
      for (int s=0; s<15; s++){ lv[s]=lv[s+1]; lj[s]=lj[s+1]; }
      lv[15]=1e30f; lj[15]=0x7fffffff;
    }
  }
}

// z = 2*(log(exp(-d2)+eps) + gumbel).  Hard bound: z <= 2*g_max <= 33.3,
// so sum(exp(z-40)) never overflows -> no max pass needed at all.
// column partial sums of exp(z-40) over a 256-row chunk; optional z-cache store.
template<bool STZ>
__global__ __launch_bounds__(256) void k_colstats(const float* __restrict__ embF,
                                                  u32 ka, u32 kb, float* __restrict__ psum,
                                                  float* __restrict__ zc){
  __shared__ float4 sE4[768];                 // 256 rows x 12 floats
  int t = threadIdx.x;
  int j = blockIdx.x*256 + t;
  int i0 = blockIdx.y*256;
  const float4* gF = (const float4*)embF;
  #pragma unroll
  for (int q=0; q<3; q++) sE4[t + 256*q] = gF[(size_t)i0*3 + t + 256*q];
  __syncthreads();
  float4 b0 = gF[j*3+0], b1 = gF[j*3+1], b2 = gF[j*3+2];
  float sej = b2.z;
  float s = 0.0f;
  float* zp = STZ ? (zc + ((size_t)i0<<13) + j) : nullptr;
  for (int r=0; r<256; r++){
    float4 a0 = sE4[r*3+0], a1 = sE4[r*3+1], a2 = sE4[r*3+2];
    float dot = a0.x*b0.x + a0.y*b0.y + a0.z*b0.z + a0.w*b0.w
              + a1.x*b1.x + a1.y*b1.y + a1.z*b1.z + a1.w*b1.w
              + a2.x*b2.x + a2.y*b2.y;
    float d2 = fmaxf(a2.z + sej - 2.0f*dot, 0.0f);
    float u = u01(rbits(ka, kb, (u32)(i0+r)*8192u + (u32)j));
    float g = -__logf(-__logf(u + EPS20) + EPS20);
    float z = 2.0f*(__logf(__expf(-d2) + EPS20) + g);
    s += __expf(z - 40.0f);
    if (STZ){ zp[0] = z; zp += NN; }
  }
  psum[blockIdx.y*NN + j] = s;
}

// K_j = 40 + log(sum_chunks psum); probs = exp(z - K_j). -> embF[j][11] and Kf[j]
__global__ __launch_bounds__(256) void k_colfin(const float* __restrict__ psum, float* __restrict__ embF,
                                                float* __restrict__ Kf){
  int j = blockIdx.x*256 + threadIdx.x;
  float S = 0.0f;
  for (int c=0; c<32; c++) S += psum[c*NN + j];
  float K = 40.0f + __logf(S);
  embF[j*12+11] = K;
  Kf[j] = K;
}

// per-row top-16 of y = z - K_j (== top-16 of probs, exp monotone); recompute path
__global__ __launch_bounds__(64) void k_rowtopk(const float* __restrict__ embF,
    u32 ka, u32 kb, int* __restrict__ soft_src, float* __restrict__ top_v){
  int i = blockIdx.x; int l = threadIdx.x;
  const float4* gF = (const float4*)embF;
  float4 b0 = gF[i*3+0], b1 = gF[i*3+1], b2 = gF[i*3+2];
  float sei = b2.z;
  float lv[16]; int lj[16];
  #pragma unroll
  for (int s=0; s<16; s++){ lv[s]=-1e30f; lj[s]=0x7fffffff; }
  for (int tt=0; tt<128; tt++){
    int j = l + 64*tt;
    float4 a0 = gF[j*3+0], a1 = gF[j*3+1], a2 = gF[j*3+2];
    float dot = a0.x*b0.x + a0.y*b0.y + a0.z*b0.z + a0.w*b0.w
              + a1.x*b1.x + a1.y*b1.y + a1.z*b1.z + a1.w*b1.w
              + a2.x*b2.x + a2.y*b2.y;
    float d2 = fmaxf(a2.z + sei - 2.0f*dot, 0.0f);
    float u = u01(rbits(ka, kb, (u32)i*8192u + (u32)j));
    float g = -__logf(-__logf(u + EPS20) + EPS20);
    float z = 2.0f*(__logf(__expf(-d2) + EPS20) + g);
    float y = z - a2.w;
    if (y > lv[15]){
      lv[15]=y; lj[15]=j;
      #pragma unroll
      for (int s=15; s>0; s--){
        if (lv[s] > lv[s-1]){ float tv=lv[s]; lv[s]=lv[s-1]; lv[s-1]=tv; int tj=lj[s]; lj[s]=lj[s-1]; lj[s-1]=tj; }
      }
    }
  }
  for (int r=0; r<16; r++){
    float bv = lv[0]; int bj = lj[0];
    #pragma unroll
    for (int off=32; off>=1; off>>=1){
      float ov = __shfl_xor(bv, off);
      int   oj = __shfl_xor(bj, off);
      if (ov > bv || (ov == bv && oj < bj)){ bv = ov; bj = oj; }
    }
    if (l == 0){ soft_src[i*16+r] = bj; top_v[i*16+r] = __expf(bv); }
    if (lj[0] == bj){
      #pragma unroll
      for (int s=0; s<15; s++){ lv[s]=lv[s+1]; lj[s]=lj[s+1]; }
      lv[15]=-1e30f; lj[15]=0x7fffffff;
    }
  }
}

// z-cached variant: pure streaming read of z row + K, no threefry/transcendentals
__global__ __launch_bounds__(64) void k_rowtopk_z(const float* __restrict__ zc,
    const float* __restrict__ Kf, int* __restrict__ soft_src, float* __restrict__ top_v){
  int i = blockIdx.x; int l = threadIdx.x;
  const float4* zrow = (const float4*)(zc + ((size_t)i<<13));
  const float4* K4 = (const float4*)Kf;
  float lv[16]; int lj[16];
  #pragma unroll
  for (int s=0; s<16; s++){ lv[s]=-1e30f; lj[s]=0x7fffffff; }
  for (int tt=0; tt<32; tt++){
    int jq = l + 64*tt;
    float4 z4 = zrow[jq];
    float4 k4 = K4[jq];
    float yv[4] = {z4.x-k4.x, z4.y-k4.y, z4.z-k4.z, z4.w-k4.w};
    #pragma unroll
    for (int c=0; c<4; c++){
      float y = yv[c];
      if (y > lv[15]){
        lv[15]=y; lj[15]=4*jq+c;
        #pragma unroll
        for (int s=15; s>0; s--){
          if (lv[s] > lv[s-1]){ float tv=lv[s]; lv[s]=lv[s-1]; lv[s-1]=tv; int tj=lj[s]; lj[s]=lj[s-1]; lj[s-1]=tj; }
        }
      }
    }
  }
  for (int r=0; r<16; r++){
    float bv = lv[0]; int bj = lj[0];
    #pragma unroll
    for (int off=32; off>=1; off>>=1){
      float ov = __shfl_xor(bv, off);
      int   oj = __shfl_xor(bj, off);
      if (ov > bv || (ov == bv && oj < bj)){ bv = ov; bj = oj; }
    }
    if (l == 0){ soft_src[i*16+r] = bj; top_v[i*16+r] = __expf(bv); }
    if (lj[0] == bj){
      #pragma unroll
      for (int s=0; s<15; s++){ lv[s]=lv[s+1]; lj[s]=lj[s+1]; }
      lv[15]=-1e30f; lj[15]=0x7fffffff;
    }
  }
}

// A = x@Wsrc, B = x@Wdst, V = x@Wlin  (8 rows per block)
__global__ __launch_bounds__(128) void k_xw(const float* __restrict__ x,
    const float* __restrict__ Wsrc, const float* __restrict__ Wdst, const float* __restrict__ Wlin,
    float* __restrict__ A, float* __restrict__ B, float* __restrict__ V){
  int g0 = blockIdx.x*8; int c = threadIdx.x;
  __shared__ float xs[8][64];
  for (int idx=c; idx<512; idx+=128) xs[idx>>6][idx&63] = x[(g0 + (idx>>6))*64 + (idx&63)];
  __syncthreads();
  float aA[8], aB[8], aV[8];
  #pragma unroll
  for (int g=0; g<8; g++){ aA[g]=0.0f; aB[g]=0.0f; aV[g]=0.0f; }
  for (int k=0; k<64; k++){
    float ws=Wsrc[k*128+c], wd=Wdst[k*128+c], wl=Wlin[k*128+c];
    #pragma unroll
    for (int g=0; g<8; g++){
      float xv = xs[g][k];
      aA[g] += xv*ws; aB[g] += xv*wd; aV[g] += xv*wl;
    }
  }
  #pragma unroll
  for (int g=0; g<8; g++){
    A[(g0+g)*128+c]=aA[g]; B[(g0+g)*128+c]=aB[g]; V[(g0+g)*128+c]=aV[g];
  }
}

// k-split GEMM over wave: lane (kh = l>>5, q = l&31) accumulates 8 edges x 4 cols
// (c = 4q..4q+3) over its 64-k half; ds_read_b128 serves 2 distinct lines/inst
// (2-way aliasing = free).  LDS broadcasts per block: 1536 (was 3072).
#define GEMMW2(WPTR)                                                        \
  {                                                                         \
    const float4* __restrict__ Wp = ((const float4*)(WPTR)) + khbase*32 + q; \
    _Pragma("unroll")                                                       \
    for (int e=0; e<8; e++){ acc[e].x=0.f; acc[e].y=0.f; acc[e].z=0.f; acc[e].w=0.f; } \
    for (int kk=0; kk<16; kk++){                                            \
      float4 w0 = Wp[0], w1 = Wp[32], w2 = Wp[64], w3 = Wp[96];             \
      Wp += 128;                                                            \
      _Pragma("unroll")                                                     \
      for (int e=0; e<8; e++){                                              \
        const float4 ev = *(const float4*)(&ein[e0+e][khbase + 4*kk]);      \
        acc[e].x += ev.x*w0.x + ev.y*w1.x + ev.z*w2.x + ev.w*w3.x;          \
        acc[e].y += ev.x*w0.y + ev.y*w1.y + ev.z*w2.y + ev.w*w3.y;          \
        acc[e].z += ev.x*w0.z + ev.y*w1.z + ev.z*w2.z + ev.w*w3.z;          \
        acc[e].w += ev.x*w0.w + ev.y*w1.w + ev.z*w2.w + ev.w*w3.w;          \
      }                                                                     \
    }                                                                       \
  }

// cross-half reduction (lane ^ 32) + bias: both halves end with the full dot
#define KREDUCE(BPTR)                                                       \
  {                                                                         \
    float4 bb = ((const float4*)(BPTR))[q];                                 \
    _Pragma("unroll")                                                       \
    for (int e=0; e<8; e++){                                                \
      acc[e].x += __shfl_xor(acc[e].x, 32); acc[e].x += bb.x;               \
      acc[e].y += __shfl_xor(acc[e].y, 32); acc[e].y += bb.y;               \
      acc[e].z += __shfl_xor(acc[e].z, 32); acc[e].z += bb.z;               \
      acc[e].w += __shfl_xor(acc[e].w, 32); acc[e].w += bb.w;               \
    }                                                                       \
  }

// PointTransformerConv, per-target fused. 256 threads = 4 waves x 8 edges.
// NOTE: no min-waves clause -- (256,4) forced VGPR=64 + catastrophic spill (R2).
__global__ __launch_bounds__(256) void k_edge(const float* __restrict__ pos,
    const int* __restrict__ soft_src, const float* __restrict__ top_v, const int* __restrict__ knn_src,
    const float* __restrict__ A, const float* __restrict__ B, const float* __restrict__ V,
    const float* __restrict__ Wp1, const float* __restrict__ bp1,
    const float* __restrict__ Wp2, const float* __restrict__ bp2,
    const float* __restrict__ Wa1, const float* __restrict__ ba1,
    const float* __restrict__ Wa2, const float* __restrict__ ba2,
    float* __restrict__ h){
  int i = blockIdx.x; int t = threadIdx.x;
  int l = t & 63; int w = t >> 6; int e0 = w*8;
  int kh = l >> 5; int q = l & 31;
  const int khbase = kh*64;
  __shared__ float ein[32][128];
  __shared__ int   ssrc[32];
  __shared__ float sw[32];
  __shared__ float sdp[32][3];
  if (t < 32){
    int s; float wt;
    if (t < 16){ s = soft_src[i*16+t]; wt = top_v[i*16+t]; }
    else       { s = knn_src[i*16+(t-16)]; wt = 1.0f; }
    ssrc[t]=s; sw[t]=wt;
    sdp[t][0]=pos[i*3]-pos[s*3]; sdp[t][1]=pos[i*3+1]-pos[s*3+1]; sdp[t][2]=pos[i*3+2]-pos[s*3+2];
  }
  __syncthreads();
  float4 acc[8], dl[8];
  // stage 1: ph = relu(dpos @ Wp1 + bp1), lane writes cols 2l,2l+1 of its wave's rows
  {
    const float2* W1v = (const float2*)Wp1;
    float2 r0 = W1v[l], r1 = W1v[64+l], r2 = W1v[128+l];
    float2 bb = ((const float2*)bp1)[l];
    #pragma unroll
    for (int e=0; e<8; e++){
      float d0=sdp[e0+e][0], d1=sdp[e0+e][1], d2=sdp[e0+e][2];
      float2 v;
      v.x = fmaxf(d0*r0.x + d1*r1.x + d2*r2.x + bb.x, 0.0f);
      v.y = fmaxf(d0*r0.y + d1*r1.y + d2*r2.y + bb.y, 0.0f);
      *(float2*)(&ein[e0+e][2*l]) = v;
    }
  }
  // delta = ph @ Wp2 + bp2
  GEMMW2(Wp2); KREDUCE(bp2);
  #pragma unroll
  for (int e=0; e<8; e++) dl[e] = acc[e];
  // q = B[i] - A[src] + delta   (kh==0 lanes write float4)
  if (kh == 0){
    float4 bi = ((const float4*)(&B[(size_t)i*128]))[q];
    #pragma unroll
    for (int e=0; e<8; e++){
      float4 av = ((const float4*)(&A[(size_t)ssrc[e0+e]*128]))[q];
      float4 v; v.x = bi.x - av.x + dl[e].x; v.y = bi.y - av.y + dl[e].y;
      v.z = bi.z - av.z + dl[e].z; v.w = bi.w - av.w + dl[e].w;
      *(float4*)(&ein[e0+e][4*q]) = v;
    }
  }
  // ah = relu(q @ Wa1 + ba1)
  GEMMW2(Wa1); KREDUCE(ba1);
  if (kh == 0){
    #pragma unroll
    for (int e=0; e<8; e++){
      float4 v; v.x=fmaxf(acc[e].x,0.f); v.y=fmaxf(acc[e].y,0.f);
      v.z=fmaxf(acc[e].z,0.f); v.w=fmaxf(acc[e].w,0.f);
      *(float4*)(&ein[e0+e][4*q]) = v;
    }
  }
  // logits = ah @ Wa2 + ba2
  GEMMW2(Wa2); KREDUCE(ba2);
  // cross-wave softmax over 32 edges; partials reuse dead ein rows:
  // m: floats [0,512), s: [512,1024), h: [1024,1536)
  float* rbuf = &ein[0][0];
  float4 mx = acc[0];
  #pragma unroll
  for (int e=1; e<8; e++){
    mx.x=fmaxf(mx.x,acc[e].x); mx.y=fmaxf(mx.y,acc[e].y);
    mx.z=fmaxf(mx.z,acc[e].z); mx.w=fmaxf(mx.w,acc[e].w);
  }
  __syncthreads();                                   // all GEMM3 LDS reads done
  if (kh == 0) *(float4*)(&rbuf[w*128 + 4*q]) = mx;
  __syncthreads();
  float4 M; M.x=-1e30f; M.y=-1e30f; M.z=-1e30f; M.w=-1e30f;
  #pragma unroll
  for (int ww=0; ww<4; ww++){
    float4 mm = *(const float4*)(&rbuf[ww*128 + 4*q]);
    M.x=fmaxf(M.x,mm.x); M.y=fmaxf(M.y,mm.y); M.z=fmaxf(M.z,mm.z); M.w=fmaxf(M.w,mm.w);
  }
  if (kh == 0){
    float4 s2; s2.x=0.f; s2.y=0.f; s2.z=0.f; s2.w=0.f;
    float4 h2; h2.x=0.f; h2.y=0.f; h2.z=0.f; h2.w=0.f;
    #pragma unroll
    for (int e=0; e<8; e++){
      int s = ssrc[e0+e]; float wt = sw[e0+e];
      float4 vv = ((const float4*)(&V[(size_t)s*128]))[q];
      float p;
      p = __expf(acc[e].x - M.x); s2.x += p; h2.x += p*(vv.x + dl[e].x)*wt;
      p = __expf(acc[e].y - M.y); s2.y += p; h2.y += p*(vv.y + dl[e].y)*wt;
      p = __expf(acc[e].z - M.z); s2.z += p; h2.z += p*(vv.z + dl[e].z)*wt;
      p = __expf(acc[e].w - M.w); s2.w += p; h2.w += p*(vv.w + dl[e].w)*wt;
    }
    *(float4*)(&rbuf[512  + w*128 + 4*q]) = s2;
    *(float4*)(&rbuf[1024 + w*128 + 4*q]) = h2;
  }
  __syncthreads();
  if (w == 0 && kh == 0){
    float4 S; S.x=0.f; S.y=0.f; S.z=0.f; S.w=0.f;
    float4 H; H.x=0.f; H.y=0.f; H.z=0.f; H.w=0.f;
    #pragma unroll
    for (int ww=0; ww<4; ww++){
      float4 sv = *(const float4*)(&rbuf[512  + ww*128 + 4*q]);
      float4 hv = *(const float4*)(&rbuf[1024 + ww*128 + 4*q]);
      S.x+=sv.x; S.y+=sv.y; S.z+=sv.z; S.w+=sv.w;
      H.x+=hv.x; H.y+=hv.y; H.z+=hv.z; H.w+=hv.w;
    }
    float4 o; o.x=H.x/(S.x+1e-16f); o.y=H.y/(S.y+1e-16f);
    o.z=H.z/(S.z+1e-16f); o.w=H.w/(S.w+1e-16f);
    *(float4*)(&h[(size_t)i*128 + 4*q]) = o;
  }
}

// hd = relu(h @ Wd + bd)
__global__ __launch_bounds__(128) void k_down(const float* __restrict__ h,
    const float* __restrict__ Wd, const float* __restrict__ bd, float* __restrict__ hd){
  int g0 = blockIdx.x*8; int c = threadIdx.x;
  __shared__ float hs[8][128];
  for (int idx=c; idx<1024; idx+=128) hs[idx>>7][idx&127] = h[(g0 + (idx>>7))*128 + (idx&127)];
  __syncthreads();
  float acc[8]; float b = bd[c];
  #pragma unroll
  for (int g=0; g<8; g++) acc[g] = b;
  for (int k=0; k<128; k+=4){
    float w0=Wd[(k+0)*128+c], w1=Wd[(k+1)*128+c], w2=Wd[(k+2)*128+c], w3=Wd[(k+3)*128+c];
    #pragma unroll
    for (int g=0; g<8; g++){
      const float4 ev = *(const float4*)(&hs[g][k]);
      acc[g] += ev.x*w0 + ev.y*w1 + ev.z*w2 + ev.w*w3;
    }
  }
  #pragma unroll
  for (int g=0; g<8; g++) hd[(g0+g)*128+c] = fmaxf(acc[g], 0.0f);
}

// y = max(hd[i], max over 32 neighbors hd[src])
__global__ __launch_bounds__(128) void k_pool(const float* __restrict__ hd,
    const int* __restrict__ soft_src, const int* __restrict__ knn_src, float* __restrict__ y){
  int i = blockIdx.x; int c = threadIdx.x;
  __shared__ int ss[32];
  if (c < 16) ss[c] = soft_src[i*16+c];
  else if (c < 32) ss[c] = knn_src[i*16+(c-16)];
  __syncthreads();
  float p = hd[i*128+c];
  for (int e=0; e<32; e++) p = fmaxf(p, hd[ss[e]*128+c]);
  y[i*128+c] = p;
}

// ranks = sorted-unique inverse (count of nonzero bins with smaller vid)
__global__ __launch_bounds__(256) void k_scan(const int* __restrict__ hist,
    int* __restrict__ rank, int* __restrict__ ucnt, int* __restrict__ Uo){
  __shared__ int part[256];
  int t = threadIdx.x;
  int base = t*32;
  int cnt = 0;
  for (int b=0; b<32; b++) cnt += (hist[base+b] > 0);
  part[t] = cnt;
  __syncthreads();
  if (t == 0){
    int run = 0;
    for (int q=0; q<256; q++){ int v = part[q]; part[q] = run; run += v; }
    Uo[0] = run;
  }
  __syncthreads();
  int run = part[t];
  for (int b=0; b<32; b++){
    int bin = base + b;
    rank[bin] = run;
    int hv = hist[bin];
    if (hv > 0){ ucnt[run] = hv; run++; }
  }
}

__global__ __launch_bounds__(128) void k_agg(const float* __restrict__ y, const float* __restrict__ pos,
    const int* __restrict__ vid, const int* __restrict__ rank,
    float* __restrict__ accx, float* __restrict__ accp){
  int n = blockIdx.x; int c = threadIdx.x;
  int r = rank[vid[n]];
  atomicAdd(&accx[r*128+c], y[n*128+c]);
  if (c < 3) atomicAdd(&accp[r*3+c], pos[n*3+c]);
}

__global__ __launch_bounds__(128) void k_final(const float* __restrict__ accx, const float* __restrict__ accp,
    const int* __restrict__ ucnt, const int* __restrict__ Uo, float* __restrict__ out){
  int r = blockIdx.x; int c = threadIdx.x;
  int u = Uo[0];
  float cnt = (r < u) ? (float)ucnt[r] : 0.0f;
  float den = fmaxf(cnt, 1.0f);
  out[r*128+c] = (r < u) ? accx[r*128+c]/den : 0.0f;
  if (c < 3) out[(size_t)NN*128 + r*3 + c] = (r < u) ? accp[r*3+c]/den : 0.0f;
  if (c == 0) out[(size_t)NN*128 + (size_t)NN*3 + r] = cnt;
}

// ---------------- launcher ----------------
extern "C" void kernel_launch(void* const* d_in, const int* in_sizes, int n_in,
                              void* d_out, int out_size, void* d_ws, size_t ws_size,
                              hipStream_t stream){
  (void)in_sizes; (void)n_in; (void)out_size;
  const float* x    = (const float*)d_in[0];
  const float* pos  = (const float*)d_in[1];
  const float* Wg1  = (const float*)d_in[2];
  const float* bg1  = (const float*)d_in[3];
  const float* Wg2  = (const float*)d_in[4];
  const float* bg2  = (const float*)d_in[5];
  const float* Wlin = (const float*)d_in[6];
  const float* Wsrc = (const float*)d_in[7];
  const float* Wdst = (const float*)d_in[8];
  const float* Wp1  = (const float*)d_in[9];
  const float* bp1  = (const float*)d_in[10];
  const float* Wp2  = (const float*)d_in[11];
  const float* bp2  = (const float*)d_in[12];
  const float* Wa1  = (const float*)d_in[13];
  const float* ba1  = (const float*)d_in[14];
  const float* Wa2  = (const float*)d_in[15];
  const float* ba2  = (const float*)d_in[16];
  const float* Wd   = (const float*)d_in[17];
  const float* bd   = (const float*)d_in[18];

  char* ws = (char*)d_ws;
  float* embF   = (float*)(ws + OFF_EMBF);
  float* sp     = (float*)(ws + OFF_SP);
  float* psum   = (float*)(ws + OFF_PSUM);
  int*   ssrc   = (int*)  (ws + OFF_SSRC);
  float* topv   = (float*)(ws + OFF_TOPV);
  int*   ksrc   = (int*)  (ws + OFF_KSRC);
  float* A      = (float*)(ws + OFF_A);
  float* B      = (float*)(ws + OFF_B);
  float* V      = (float*)(ws + OFF_V);
  float* h      = (float*)(ws + OFF_H);
  float* hd     = (float*)(ws + OFF_HD);
  float* y      = (float*)(ws + OFF_Y);
  float* accx   = (float*)(ws + OFF_ACCX);
  float* accp   = (float*)(ws + OFF_ACCP);
  int*   hist   = (int*)  (ws + OFF_HIST);
  int*   rank   = (int*)  (ws + OFF_RANK);
  int*   ucnt   = (int*)  (ws + OFF_UCNT);
  int*   vid    = (int*)  (ws + OFF_VID);
  float* meta_f = (float*)(ws + OFF_META);
  int*   meta_i = (int*)  (ws + OFF_META + 16);
  int*   Uo     = (int*)  (ws + OFF_META + 32);
  float* Kf     = (float*)(ws + OFF_KF);
  float* zc     = (float*)(ws + OFF_Z);

  const bool use_z = (ws_size >= OFF_Z + Z_BYTES);   // constant per run -> deterministic

  // rk = jax.random.split(jax.random.key(42), 2)  -- host threefry
  u32 rk0a, rk0b, rk1a, rk1b;
  tf2x32(0u, 42u, 0u, 0u, rk0a, rk0b);   // foldlike split: key_j = threefry(key, (0, j))
  tf2x32(0u, 42u, 0u, 1u, rk1a, rk1b);

  hipMemsetAsync(hist, 0, 8192*4, stream);
  hipMemsetAsync(accx, 0, (size_t)8192*128*4, stream);
  hipMemsetAsync(accp, 0, (size_t)8192*3*4, stream);

  k_prep<<<1, 1024, 0, stream>>>(pos, meta_f, meta_i);
  k_vid<<<32, 256, 0, stream>>>(pos, meta_f, meta_i, vid, hist, sp);
  k_emb<<<8192, 64, 0, stream>>>(x, Wg1, bg1, Wg2, bg2, rk0a, rk0b, embF);
  k_knn<<<8192, 64, 0, stream>>>(pos, sp, ksrc);
  if (use_z){
    k_colstats<true><<<dim3(32,32), 256, 0, stream>>>(embF, rk1a, rk1b, psum, zc);
    k_colfin<<<32, 256, 0, stream>>>(psum, embF, Kf);
    k_rowtopk_z<<<8192, 64, 0, stream>>>(zc, Kf, ssrc, topv);
  } else {
    k_colstats<false><<<dim3(32,32), 256, 0, stream>>>(embF, rk1a, rk1b, psum, nullptr);
    k_colfin<<<32, 256, 0, stream>>>(psum, embF, Kf);
    k_rowtopk<<<8192, 64, 0, stream>>>(embF, rk1a, rk1b, ssrc, topv);
  }
  k_xw<<<1024, 128, 0, stream>>>(x, Wsrc, Wdst, Wlin, A, B, V);
  k_edge<<<8192, 256, 0, stream>>>(pos, ssrc, topv, ksrc, A, B, V,
                                   Wp1, bp1, Wp2, bp2, Wa1, ba1, Wa2, ba2, h);
  k_down<<<1024, 128, 0, stream>>>(h, Wd, bd, hd);
  k_pool<<<8192, 128, 0, stream>>>(hd, ssrc, ksrc, y);
  k_scan<<<1, 256, 0, stream>>>(hist, rank, ucnt, Uo);
  k_agg<<<8192, 128, 0, stream>>>(y, pos, vid, rank, accx, accp);
  k_final<<<8192, 128, 0, stream>>>(accx, accp, ucnt, Uo, (float*)d_out);
}

// Round 6
// 1269.117 us; speedup vs baseline: 1.2084x; 1.0601x over previous
//
#include <hip/hip_runtime.h>
#include <stdint.h>

// ---------------------------------------------------------------------------
// Enc_block: KNN graph + gumbel-softmax soft edges + PointTransformerConv +
// down + neighbor max-pool + GridSampling.  N=8192, Cin=64, Cout=128, K=16.
// ---------------------------------------------------------------------------

typedef unsigned int u32;
typedef float v2f __attribute__((ext_vector_type(2)));

#define NN 8192
#define EPS20 1e-20f

// ---------------- threefry2x32 (JAX key schedule) ----------------
__host__ __device__ static inline u32 rotl32(u32 v, int r){ return (v<<r)|(v>>(32-r)); }

__host__ __device__ static inline void tf2x32(u32 k0, u32 k1, u32 c0, u32 c1, u32& o0, u32& o1){
  u32 ks2 = k0 ^ k1 ^ 0x1BD11BDAu;
  u32 x0 = c0 + k0;
  u32 x1 = c1 + k1;
#define TFR(r) x0 += x1; x1 = rotl32(x1,(r)); x1 ^= x0;
  TFR(13) TFR(15) TFR(26) TFR(6)
  x0 += k1;  x1 += ks2 + 1u;
  TFR(17) TFR(29) TFR(16) TFR(24)
  x0 += ks2; x1 += k0 + 2u;
  TFR(13) TFR(15) TFR(26) TFR(6)
  x0 += k0;  x1 += k1 + 3u;
  TFR(17) TFR(29) TFR(16) TFR(24)
  x0 += k1;  x1 += ks2 + 4u;
  TFR(13) TFR(15) TFR(26) TFR(6)
  x0 += ks2; x1 += k0 + 5u;
#undef TFR
  o0 = x0; o1 = x1;
}

__device__ static inline u32 rbits(u32 k0, u32 k1, u32 idx){
  u32 o0,o1; tf2x32(k0,k1, 0u, idx, o0,o1);   // partitionable: counter (0, idx)
  return o0 ^ o1;                              // 32-bit fold
}

__device__ static inline float u01(u32 b){
  return __uint_as_float((b>>9) | 0x3f800000u) - 1.0f;   // [0,1), JAX formula
}

// ---------------- workspace layout ----------------
static constexpr size_t OFF_EMBF = 0;                              // [8192][12] f32: e[10], se, K
static constexpr size_t OFF_SP   = OFF_EMBF + (size_t)8192*12*4;
static constexpr size_t OFF_PSUM = OFF_SP   + (size_t)8192*4;      // [32][8192]
static constexpr size_t OFF_SSRC = OFF_PSUM + (size_t)32*8192*4;   // int [8192][16]
static constexpr size_t OFF_TOPV = OFF_SSRC + (size_t)8192*16*4;
static constexpr size_t OFF_KSRC = OFF_TOPV + (size_t)8192*16*4;   // int [8192][16]
static constexpr size_t OFF_A    = OFF_KSRC + (size_t)8192*16*4;   // x@Wsrc
static constexpr size_t OFF_B    = OFF_A    + (size_t)8192*128*4;  // x@Wdst
static constexpr size_t OFF_V    = OFF_B    + (size_t)8192*128*4;  // x@Wlin
static constexpr size_t OFF_H    = OFF_V    + (size_t)8192*128*4;  // conv out
static constexpr size_t OFF_HD   = OFF_H    + (size_t)8192*128*4;  // after down
static constexpr size_t OFF_Y    = OFF_HD   + (size_t)8192*128*4;  // after pool
static constexpr size_t OFF_ACCX = OFF_Y    + (size_t)8192*128*4;  // voxel sums
static constexpr size_t OFF_ACCP = OFF_ACCX + (size_t)8192*128*4;  // voxel pos sums
static constexpr size_t OFF_HIST = OFF_ACCP + (size_t)8192*3*4;    // int [8192]
static constexpr size_t OFF_RANK = OFF_HIST + (size_t)8192*4;      // int [8192]
static constexpr size_t OFF_UCNT = OFF_RANK + (size_t)8192*4;      // int [8192]
static constexpr size_t OFF_VID  = OFF_UCNT + (size_t)8192*4;      // int [8192]
static constexpr size_t OFF_META = OFF_VID  + (size_t)8192*4;      // mi i[3] @0, mx i[3] @16B, U i @32B
static constexpr size_t OFF_KF   = OFF_META + 64;                  // f32 [8192]
static constexpr size_t OFF_Z    = (OFF_KF + (size_t)8192*4 + 255) & ~(size_t)255;  // f32 [8192][8192]
static constexpr size_t Z_BYTES  = (size_t)NN*NN*4;

// ---------------- kernels ----------------

// init the atomic-reduction cells
__global__ void k_init0(int* __restrict__ mi, int* __restrict__ mx){
  int t = threadIdx.x;
  if (t < 3){ mi[t] = 0x7f7fffff; mx[t] = 0; }
}

// per-dim min of pos (positive floats: int-bit compare is order-preserving)
__global__ __launch_bounds__(256) void k_min(const float* __restrict__ pos, int* __restrict__ mi){
  __shared__ int red[768];
  int t = threadIdx.x;
  int n = blockIdx.x*256 + t;
  red[t]     = __float_as_int(pos[n*3+0]);
  red[256+t] = __float_as_int(pos[n*3+1]);
  red[512+t] = __float_as_int(pos[n*3+2]);
  __syncthreads();
  for (int s=128; s>0; s>>=1){
    if (t < s){
      red[t]     = min(red[t],     red[t+s]);
      red[256+t] = min(red[256+t], red[256+t+s]);
      red[512+t] = min(red[512+t], red[512+t+s]);
    }
    __syncthreads();
  }
  if (t == 0){ atomicMin(&mi[0], red[0]); atomicMin(&mi[1], red[256]); atomicMin(&mi[2], red[512]); }
}

// per-dim max voxel index
__global__ __launch_bounds__(256) void k_ext(const float* __restrict__ pos, const int* __restrict__ mi,
                                             int* __restrict__ mx){
  __shared__ int red[768];
  int t = threadIdx.x;
  int n = blockIdx.x*256 + t;
  float p0 = __int_as_float(mi[0]), p1 = __int_as_float(mi[1]), p2 = __int_as_float(mi[2]);
  red[t]     = (int)floorf((pos[n*3+0]-p0)*2.0f);   // /0.5 == *2 exactly
  red[256+t] = (int)floorf((pos[n*3+1]-p1)*2.0f);
  red[512+t] = (int)floorf((pos[n*3+2]-p2)*2.0f);
  __syncthreads();
  for (int s=128; s>0; s>>=1){
    if (t < s){
      red[t]     = max(red[t],     red[t+s]);
      red[256+t] = max(red[256+t], red[256+t+s]);
      red[512+t] = max(red[512+t], red[512+t+s]);
    }
    __syncthreads();
  }
  if (t == 0){ atomicMax(&mx[0], red[0]); atomicMax(&mx[1], red[256]); atomicMax(&mx[2], red[512]); }
}

// voxel id + histogram + pos squared norms
__global__ __launch_bounds__(256) void k_vid(const float* __restrict__ pos,
                                             const int* __restrict__ mi, const int* __restrict__ mx,
                                             int* __restrict__ vid, int* __restrict__ hist,
                                             float* __restrict__ sp){
  int n = blockIdx.x*256 + threadIdx.x;
  float p0=pos[n*3], p1=pos[n*3+1], p2=pos[n*3+2];
  sp[n] = p0*p0 + p1*p1 + p2*p2;
  float q0 = __int_as_float(mi[0]), q1 = __int_as_float(mi[1]), q2 = __int_as_float(mi[2]);
  int v0 = (int)floorf((p0-q0)*2.0f);
  int v1 = (int)floorf((p1-q1)*2.0f);
  int v2 = (int)floorf((p2-q2)*2.0f);
  int nv1 = mx[1]+1, nv2 = mx[2]+1;
  int id = (v0*nv1 + v1)*nv2 + v2;
  vid[n] = id;
  atomicAdd(&hist[id], 1);
}

// embF[i] = { relu(x@Wg1+bg1)@Wg2+bg2 + u*0.001  (10), |emb|^2, 0 }
__global__ __launch_bounds__(64) void k_emb(const float* __restrict__ x,
    const float* __restrict__ Wg1, const float* __restrict__ bg1,
    const float* __restrict__ Wg2, const float* __restrict__ bg2,
    u32 ka, u32 kb, float* __restrict__ embF){
  int i = blockIdx.x; int t = threadIdx.x;
  __shared__ float xs[64], hs[64], esq[10];
  xs[t] = x[i*64+t];
  __syncthreads();
  float a = bg1[t];
  for (int k=0; k<64; k++) a += xs[k]*Wg1[k*64+t];
  hs[t] = fmaxf(a, 0.0f);
  __syncthreads();
  if (t < 10){
    float e = bg2[t];
    for (int k=0; k<64; k++) e += hs[k]*Wg2[k*10+t];
    e += u01(rbits(ka, kb, (u32)(i*10+t))) * 0.001f;
    embF[i*12+t] = e;
    esq[t] = e*e;
  }
  __syncthreads();
  if (t == 0){
    float ssum = 0.0f;
    #pragma unroll
    for (int d=0; d<10; d++) ssum += esq[d];
    embF[i*12+10] = ssum;
    embF[i*12+11] = 0.0f;
  }
}

// KNN: top-16 smallest d2 per row (diag excluded), ties -> lower index
__global__ __launch_bounds__(64) void k_knn(const float* __restrict__ pos, const float* __restrict__ sp,
                                            int* __restrict__ knn_src){
  int i = blockIdx.x; int l = threadIdx.x;
  float pi0=pos[i*3], pi1=pos[i*3+1], pi2=pos[i*3+2];
  float spi = sp[i];
  float lv[16]; int lj[16];
  #pragma unroll
  for (int s=0; s<16; s++){ lv[s]=1e30f; lj[s]=0x7fffffff; }
  for (int tt=0; tt<128; tt++){
    int j = l + 64*tt;
    if (j == i) continue;
    float d = spi + sp[j] - 2.0f*(pi0*pos[j*3] + pi1*pos[j*3+1] + pi2*pos[j*3+2]);
    d = fmaxf(d, 0.0f);
    if (d < lv[15]){
      lv[15]=d; lj[15]=j;
      #pragma unroll
      for (int s=15; s>0; s--){
        if (lv[s] < lv[s-1]){ float tv=lv[s]; lv[s]=lv[s-1]; lv[s-1]=tv; int tj=lj[s]; lj[s]=lj[s-1]; lj[s-1]=tj; }
      }
    }
  }
  for (int r=0; r<16; r++){
    float bv = lv[0]; int bj = lj[0];
    #pragma unroll
    for (int off=32; off>=1; off>>=1){
      float ov = __shfl_xor(bv, off);
      int   oj = __shfl_xor(bj, off);
      if (ov < bv || (ov == bv && oj < bj)){ bv = ov; bj = oj; }
    }
    if (l == 0) knn_src[i*16+r] = bj;
    if (lj[0] == bj){
      #pragma unroll
      for (int s=0; s<15; s++){ lv[s]=lv[s+1]; lj[s]=lj[s+1]; }
      lv[15]=1e30f; lj[15]=0x7fffffff;
    }
  }
}

// z = 2*(log(exp(-d2)+eps) + gumbel).  Hard bound: z <= 2*g_max <= 33.3,
// so sum(exp(z-40)) never overflows -> no max pass needed at all.
template<bool STZ>
__global__ __launch_bounds__(256) void k_colstats(const float* __restrict__ embF,
                                                  u32 ka, u32 kb, float* __restrict__ psum,
                                                  float* __restrict__ zc){
  __shared__ float4 sE4[768];                 // 256 rows x 12 floats
  int t = threadIdx.x;
  int j = blockIdx.x*256 + t;
  int i0 = blockIdx.y*256;
  const float4* gF = (const float4*)embF;
  #pragma unroll
  for (int q=0; q<3; q++) sE4[t + 256*q] = gF[(size_t)i0*3 + t + 256*q];
  __syncthreads();
  float4 b0 = gF[j*3+0], b1 = gF[j*3+1], b2 = gF[j*3+2];
  float sej = b2.z;
  float s = 0.0f;
  float* zp = STZ ? (zc + ((size_t)i0<<13) + j) : nullptr;
  for (int r=0; r<256; r++){
    float4 a0 = sE4[r*3+0], a1 = sE4[r*3+1], a2 = sE4[r*3+2];
    float dot = a0.x*b0.x + a0.y*b0.y + a0.z*b0.z + a0.w*b0.w
              + a1.x*b1.x + a1.y*b1.y + a1.z*b1.z + a1.w*b1.w
              + a2.x*b2.x + a2.y*b2.y;
    float d2 = fmaxf(a2.z + sej - 2.0f*dot, 0.0f);
    float u = u01(rbits(ka, kb, (u32)(i0+r)*8192u + (u32)j));
    float g = -__logf(-__logf(u + EPS20) + EPS20);
    float z = 2.0f*(__logf(__expf(-d2) + EPS20) + g);
    s += __expf(z - 40.0f);
    if (STZ){ zp[0] = z; zp += NN; }
  }
  psum[blockIdx.y*NN + j] = s;
}

// K_j = 40 + log(sum_chunks psum); probs = exp(z - K_j). -> embF[j][11] and Kf[j]
__global__ __launch_bounds__(256) void k_colfin(const float* __restrict__ psum, float* __restrict__ embF,
                                                float* __restrict__ Kf){
  int j = blockIdx.x*256 + threadIdx.x;
  float S = 0.0f;
  for (int c=0; c<32; c++) S += psum[c*NN + j];
  float K = 40.0f + __logf(S);
  embF[j*12+11] = K;
  Kf[j] = K;
}

// per-row top-16 of y = z - K_j (== top-16 of probs, exp monotone)
__global__ __launch_bounds__(64) void k_rowtopk(const float* __restrict__ embF,
    u32 ka, u32 kb, int* __restrict__ soft_src, float* __restrict__ top_v){
  int i = blockIdx.x; int l = threadIdx.x;
  const float4* gF = (const float4*)embF;
  float4 b0 = gF[i*3+0], b1 = gF[i*3+1], b2 = gF[i*3+2];
  float sei = b2.z;
  float lv[16]; int lj[16];
  #pragma unroll
  for (int s=0; s<16; s++){ lv[s]=-1e30f; lj[s]=0x7fffffff; }
  for (int tt=0; tt<128; tt++){
    int j = l + 64*tt;
    float4 a0 = gF[j*3+0], a1 = gF[j*3+1], a2 = gF[j*3+2];
    float dot = a0.x*b0.x + a0.y*b0.y + a0.z*b0.z + a0.w*b0.w
              + a1.x*b1.x + a1.y*b1.y + a1.z*b1.z + a1.w*b1.w
              + a2.x*b2.x + a2.y*b2.y;
    float d2 = fmaxf(a2.z + sei - 2.0f*dot, 0.0f);
    float u = u01(rbits(ka, kb, (u32)i*8192u + (u32)j));
    float g = -__logf(-__logf(u + EPS20) + EPS20);
    float z = 2.0f*(__logf(__expf(-d2) + EPS20) + g);
    float y = z - a2.w;
    if (y > lv[15]){
      lv[15]=y; lj[15]=j;
      #pragma unroll
      for (int s=15; s>0; s--){
        if (lv[s] > lv[s-1]){ float tv=lv[s]; lv[s]=lv[s-1]; lv[s-1]=tv; int tj=lj[s]; lj[s]=lj[s-1]; lj[s-1]=tj; }
      }
    }
  }
  for (int r=0; r<16; r++){
    float bv = lv[0]; int bj = lj[0];
    #pragma unroll
    for (int off=32; off>=1; off>>=1){
      float ov = __shfl_xor(bv, off);
      int   oj = __shfl_xor(bj, off);
      if (ov > bv || (ov == bv && oj < bj)){ bv = ov; bj = oj; }
    }
    if (l == 0){ soft_src[i*16+r] = bj; top_v[i*16+r] = __expf(bv); }
    if (lj[0] == bj){
      #pragma unroll
      for (int s=0; s<15; s++){ lv[s]=lv[s+1]; lj[s]=lj[s+1]; }
      lv[15]=-1e30f; lj[15]=0x7fffffff;
    }
  }
}

// z-cached variant: streaming read, no threefry/transcendentals
__global__ __launch_bounds__(64) void k_rowtopk_z(const float* __restrict__ zc,
    const float* __restrict__ Kf, int* __restrict__ soft_src, float* __restrict__ top_v){
  int i = blockIdx.x; int l = threadIdx.x;
  const float4* zrow = (const float4*)(zc + ((size_t)i<<13));
  const float4* K4 = (const float4*)Kf;
  float lv[16]; int lj[16];
  #pragma unroll
  for (int s=0; s<16; s++){ lv[s]=-1e30f; lj[s]=0x7fffffff; }
  for (int tt=0; tt<32; tt++){
    int jq = l + 64*tt;
    float4 z4 = zrow[jq];
    float4 k4 = K4[jq];
    float yv[4] = {z4.x-k4.x, z4.y-k4.y, z4.z-k4.z, z4.w-k4.w};
    #pragma unroll
    for (int c=0; c<4; c++){
      float y = yv[c];
      if (y > lv[15]){
        lv[15]=y; lj[15]=4*jq+c;
        #pragma unroll
        for (int s=15; s>0; s--){
          if (lv[s] > lv[s-1]){ float tv=lv[s]; lv[s]=lv[s-1]; lv[s-1]=tv; int tj=lj[s]; lj[s]=lj[s-1]; lj[s-1]=tj; }
        }
      }
    }
  }
  for (int r=0; r<16; r++){
    float bv = lv[0]; int bj = lj[0];
    #pragma unroll
    for (int off=32; off>=1; off>>=1){
      float ov = __shfl_xor(bv, off);
      int   oj = __shfl_xor(bj, off);
      if (ov > bv || (ov == bv && oj < bj)){ bv = ov; bj = oj; }
    }
    if (l == 0){ soft_src[i*16+r] = bj; top_v[i*16+r] = __expf(bv); }
    if (lj[0] == bj){
      #pragma unroll
      for (int s=0; s<15; s++){ lv[s]=lv[s+1]; lj[s]=lj[s+1]; }
      lv[15]=-1e30f; lj[15]=0x7fffffff;
    }
  }
}

// A = x@Wsrc, B = x@Wdst, V = x@Wlin  (8 rows per block)
__global__ __launch_bounds__(128) void k_xw(const float* __restrict__ x,
    const float* __restrict__ Wsrc, const float* __restrict__ Wdst, const float* __restrict__ Wlin,
    float* __restrict__ A, float* __restrict__ B, float* __restrict__ V){
  int g0 = blockIdx.x*8; int c = threadIdx.x;
  __shared__ float xs[8][64];
  for (int idx=c; idx<512; idx+=128) xs[idx>>6][idx&63] = x[(g0 + (idx>>6))*64 + (idx&63)];
  __syncthreads();
  float aA[8], aB[8], aV[8];
  #pragma unroll
  for (int g=0; g<8; g++){ aA[g]=0.0f; aB[g]=0.0f; aV[g]=0.0f; }
  for (int k=0; k<64; k++){
    float ws=Wsrc[k*128+c], wd=Wdst[k*128+c], wl=Wlin[k*128+c];
    #pragma unroll
    for (int g=0; g<8; g++){
      float xv = xs[g][k];
      aA[g] += xv*ws; aB[g] += xv*wd; aV[g] += xv*wl;
    }
  }
  #pragma unroll
  for (int g=0; g<8; g++){
    A[(g0+g)*128+c]=aA[g]; B[(g0+g)*128+c]=aB[g]; V[(g0+g)*128+c]=aV[g];
  }
}

// k-split GEMM, packed-f32 accumulators: lane (kh=l>>5, q=l&31) does 8 edges x
// 4 cols (two v2f) over its 64-k half -> v_pk_fma_f32 halves VALU inst count.
#define GEMMW2(WPTR)                                                        \
  {                                                                         \
    const float4* __restrict__ Wp = ((const float4*)(WPTR)) + khbase*32 + q; \
    _Pragma("unroll")                                                       \
    for (int e=0; e<8; e++){ accA[e] = (v2f){0.f,0.f}; accB[e] = (v2f){0.f,0.f}; } \
    for (int kk=0; kk<16; kk++){                                            \
      float4 w0 = Wp[0], w1 = Wp[32], w2 = Wp[64], w3 = Wp[96];             \
      Wp += 128;                                                            \
      v2f w0a = {w0.x,w0.y}, w0b = {w0.z,w0.w};                             \
      v2f w1a = {w1.x,w1.y}, w1b = {w1.z,w1.w};                             \
      v2f w2a = {w2.x,w2.y}, w2b = {w2.z,w2.w};                             \
      v2f w3a = {w3.x,w3.y}, w3b = {w3.z,w3.w};                             \
      _Pragma("unroll")                                                     \
      for (int e=0; e<8; e++){                                              \
        const float4 ev = *(const float4*)(&ein[e0+e][khbase + 4*kk]);      \
        v2f ex = {ev.x,ev.x}, ey = {ev.y,ev.y}, ez = {ev.z,ev.z}, ew = {ev.w,ev.w}; \
        accA[e] += ex*w0a; accB[e] += ex*w0b;                               \
        accA[e] += ey*w1a; accB[e] += ey*w1b;                               \
        accA[e] += ez*w2a; accB[e] += ez*w2b;                               \
        accA[e] += ew*w3a; accB[e] += ew*w3b;                               \
      }                                                                     \
    }                                                                       \
  }

// cross-half reduction (lane ^ 32) + bias
#define KREDUCE(BPTR)                                                       \
  {                                                                         \
    float4 bb = ((const float4*)(BPTR))[q];                                 \
    _Pragma("unroll")                                                       \
    for (int e=0; e<8; e++){                                                \
      accA[e].x += __shfl_xor(accA[e].x, 32); accA[e].x += bb.x;            \
      accA[e].y += __shfl_xor(accA[e].y, 32); accA[e].y += bb.y;            \
      accB[e].x += __shfl_xor(accB[e].x, 32); accB[e].x += bb.z;            \
      accB[e].y += __shfl_xor(accB[e].y, 32); accB[e].y += bb.w;            \
    }                                                                       \
  }

// PointTransformerConv, per-target fused. 256 threads = 4 waves x 8 edges.
// NOTE: no min-waves clause -- (256,4) forced VGPR=64 + catastrophic spill (R2).
__global__ __launch_bounds__(256) void k_edge(const float* __restrict__ pos,
    const int* __restrict__ soft_src, const float* __restrict__ top_v, const int* __restrict__ knn_src,
    const float* __restrict__ A, const float* __restrict__ B, const float* __restrict__ V,
    const float* __restrict__ Wp1, const float* __restrict__ bp1,
    const float* __restrict__ Wp2, const float* __restrict__ bp2,
    const float* __restrict__ Wa1, const float* __restrict__ ba1,
    const float* __restrict__ Wa2, const float* __restrict__ ba2,
    float* __restrict__ h){
  int i = blockIdx.x; int t = threadIdx.x;
  int l = t & 63; int w = t >> 6; int e0 = w*8;
  int kh = l >> 5; int q = l & 31;
  const int khbase = kh*64;
  __shared__ float ein[32][128];
  __shared__ int   ssrc[32];
  __shared__ float sw[32];
  __shared__ float sdp[32][3];
  if (t < 32){
    int s; float wt;
    if (t < 16){ s = soft_src[i*16+t]; wt = top_v[i*16+t]; }
    else       { s = knn_src[i*16+(t-16)]; wt = 1.0f; }
    ssrc[t]=s; sw[t]=wt;
    sdp[t][0]=pos[i*3]-pos[s*3]; sdp[t][1]=pos[i*3+1]-pos[s*3+1]; sdp[t][2]=pos[i*3+2]-pos[s*3+2];
  }
  __syncthreads();
  v2f accA[8], accB[8], dlA[8], dlB[8];
  // stage 1: ph = relu(dpos @ Wp1 + bp1), lane writes cols 2l,2l+1 of its wave's rows
  {
    const float2* W1v = (const float2*)Wp1;
    float2 r0 = W1v[l], r1 = W1v[64+l], r2 = W1v[128+l];
    float2 bb = ((const float2*)bp1)[l];
    #pragma unroll
    for (int e=0; e<8; e++){
      float d0=sdp[e0+e][0], d1=sdp[e0+e][1], d2=sdp[e0+e][2];
      float2 v;
      v.x = fmaxf(d0*r0.x + d1*r1.x + d2*r2.x + bb.x, 0.0f);
      v.y = fmaxf(d0*r0.y + d1*r1.y + d2*r2.y + bb.y, 0.0f);
      *(float2*)(&ein[e0+e][2*l]) = v;
    }
  }
  // delta = ph @ Wp2 + bp2
  GEMMW2(Wp2); KREDUCE(bp2);
  #pragma unroll
  for (int e=0; e<8; e++){ dlA[e] = accA[e]; dlB[e] = accB[e]; }
  // q = B[i] - A[src] + delta   (kh==0 lanes write float4)
  if (kh == 0){
    float4 bi = ((const float4*)(&B[(size_t)i*128]))[q];
    #pragma unroll
    for (int e=0; e<8; e++){
      float4 av = ((const float4*)(&A[(size_t)ssrc[e0+e]*128]))[q];
      float4 v; v.x = bi.x - av.x + dlA[e].x; v.y = bi.y - av.y + dlA[e].y;
      v.z = bi.z - av.z + dlB[e].x; v.w = bi.w - av.w + dlB[e].y;
      *(float4*)(&ein[e0+e][4*q]) = v;
    }
  }
  // ah = relu(q @ Wa1 + ba1)
  GEMMW2(Wa1); KREDUCE(ba1);
  if (kh == 0){
    #pragma unroll
    for (int e=0; e<8; e++){
      float4 v; v.x=fmaxf(accA[e].x,0.f); v.y=fmaxf(accA[e].y,0.f);
      v.z=fmaxf(accB[e].x,0.f); v.w=fmaxf(accB[e].y,0.f);
      *(float4*)(&ein[e0+e][4*q]) = v;
    }
  }
  // logits = ah @ Wa2 + ba2
  GEMMW2(Wa2); KREDUCE(ba2);
  // cross-wave softmax over 32 edges; partials reuse dead ein rows:
  // m: floats [0,512), s: [512,1024), h: [1024,1536)
  float* rbuf = &ein[0][0];
  v2f mA = accA[0], mB = accB[0];
  #pragma unroll
  for (int e=1; e<8; e++){
    mA.x=fmaxf(mA.x,accA[e].x); mA.y=fmaxf(mA.y,accA[e].y);
    mB.x=fmaxf(mB.x,accB[e].x); mB.y=fmaxf(mB.y,accB[e].y);
  }
  __syncthreads();                                   // all GEMM3 LDS reads done
  if (kh == 0){
    float4 mv; mv.x=mA.x; mv.y=mA.y; mv.z=mB.x; mv.w=mB.y;
    *(float4*)(&rbuf[w*128 + 4*q]) = mv;
  }
  __syncthreads();
  float4 M; M.x=-1e30f; M.y=-1e30f; M.z=-1e30f; M.w=-1e30f;
  #pragma unroll
  for (int ww=0; ww<4; ww++){
    float4 mm = *(const float4*)(&rbuf[ww*128 + 4*q]);
    M.x=fmaxf(M.x,mm.x); M.y=fmaxf(M.y,mm.y); M.z=fmaxf(M.z,mm.z); M.w=fmaxf(M.w,mm.w);
  }
  if (kh == 0){
    float4 s2; s2.x=0.f; s2.y=0.f; s2.z=0.f; s2.w=0.f;
    float4 h2; h2.x=0.f; h2.y=0.f; h2.z=0.f; h2.w=0.f;
    #pragma unroll
    for (int e=0; e<8; e++){
      int s = ssrc[e0+e]; float wt = sw[e0+e];
      float4 vv = ((const float4*)(&V[(size_t)s*128]))[q];
      float p;
      p = __expf(accA[e].x - M.x); s2.x += p; h2.x += p*(vv.x + dlA[e].x)*wt;
      p = __expf(accA[e].y - M.y); s2.y += p; h2.y += p*(vv.y + dlA[e].y)*wt;
      p = __expf(accB[e].x - M.z); s2.z += p; h2.z += p*(vv.z + dlB[e].x)*wt;
      p = __expf(accB[e].y - M.w); s2.w += p; h2.w += p*(vv.w + dlB[e].y)*wt;
    }
    *(float4*)(&rbuf[512  + w*128 + 4*q]) = s2;
    *(float4*)(&rbuf[1024 + w*128 + 4*q]) = h2;
  }
  __syncthreads();
  if (w == 0 && kh == 0){
    float4 S; S.x=0.f; S.y=0.f; S.z=0.f; S.w=0.f;
    float4 H; H.x=0.f; H.y=0.f; H.z=0.f; H.w=0.f;
    #pragma unroll
    for (int ww=0; ww<4; ww++){
      float4 sv = *(const float4*)(&rbuf[512  + ww*128 + 4*q]);
      float4 hv = *(const float4*)(&rbuf[1024 + ww*128 + 4*q]);
      S.x+=sv.x; S.y+=sv.y; S.z+=sv.z; S.w+=sv.w;
      H.x+=hv.x; H.y+=hv.y; H.z+=hv.z; H.w+=hv.w;
    }
    float4 o; o.x=H.x/(S.x+1e-16f); o.y=H.y/(S.y+1e-16f);
    o.z=H.z/(S.z+1e-16f); o.w=H.w/(S.w+1e-16f);
    *(float4*)(&h[(size_t)i*128 + 4*q]) = o;
  }
}

// hd = relu(h @ Wd + bd)
__global__ __launch_bounds__(128) void k_down(const float* __restrict__ h,
    const float* __restrict__ Wd, const float* __restrict__ bd, float* __restrict__ hd){
  int g0 = blockIdx.x*8; int c = threadIdx.x;
  __shared__ float hs[8][128];
  for (int idx=c; idx<1024; idx+=128) hs[idx>>7][idx&127] = h[(g0 + (idx>>7))*128 + (idx&127)];
  __syncthreads();
  float acc[8]; float b = bd[c];
  #pragma unroll
  for (int g=0; g<8; g++) acc[g] = b;
  for (int k=0; k<128; k+=4){
    float w0=Wd[(k+0)*128+c], w1=Wd[(k+1)*128+c], w2=Wd[(k+2)*128+c], w3=Wd[(k+3)*128+c];
    #pragma unroll
    for (int g=0; g<8; g++){
      const float4 ev = *(const float4*)(&hs[g][k]);
      acc[g] += ev.x*w0 + ev.y*w1 + ev.z*w2 + ev.w*w3;
    }
  }
  #pragma unroll
  for (int g=0; g<8; g++) hd[(g0+g)*128+c] = fmaxf(acc[g], 0.0f);
}

// y = max(hd[i], max over 32 neighbors hd[src])
__global__ __launch_bounds__(128) void k_pool(const float* __restrict__ hd,
    const int* __restrict__ soft_src, const int* __restrict__ knn_src, float* __restrict__ y){
  int i = blockIdx.x; int c = threadIdx.x;
  __shared__ int ss[32];
  if (c < 16) ss[c] = soft_src[i*16+c];
  else if (c < 32) ss[c] = knn_src[i*16+(c-16)];
  __syncthreads();
  float p = hd[i*128+c];
  for (int e=0; e<32; e++) p = fmaxf(p, hd[ss[e]*128+c]);
  y[i*128+c] = p;
}

// ranks = sorted-unique inverse (count of nonzero bins with smaller vid)
__global__ __launch_bounds__(256) void k_scan(const int* __restrict__ hist,
    int* __restrict__ rank, int* __restrict__ ucnt, int* __restrict__ Uo){
  __shared__ int part[256];
  int t = threadIdx.x;
  int base = t*32;
  int cnt = 0;
  for (int b=0; b<32; b++) cnt += (hist[base+b] > 0);
  part[t] = cnt;
  __syncthreads();
  if (t == 0){
    int run = 0;
    for (int q=0; q<256; q++){ int v = part[q]; part[q] = run; run += v; }
    Uo[0] = run;
  }
  __syncthreads();
  int run = part[t];
  for (int b=0; b<32; b++){
    int bin = base + b;
    rank[bin] = run;
    int hv = hist[bin];
    if (hv > 0){ ucnt[run] = hv; run++; }
  }
}

__global__ __launch_bounds__(128) void k_agg(const float* __restrict__ y, const float* __restrict__ pos,
    const int* __restrict__ vid, const int* __restrict__ rank,
    float* __restrict__ accx, float* __restrict__ accp){
  int n = blockIdx.x; int c = threadIdx.x;
  int r = rank[vid[n]];
  atomicAdd(&accx[r*128+c], y[n*128+c]);
  if (c < 3) atomicAdd(&accp[r*3+c], pos[n*3+c]);
}

__global__ __launch_bounds__(128) void k_final(const float* __restrict__ accx, const float* __restrict__ accp,
    const int* __restrict__ ucnt, const int* __restrict__ Uo, float* __restrict__ out){
  int r = blockIdx.x; int c = threadIdx.x;
  int u = Uo[0];
  float cnt = (r < u) ? (float)ucnt[r] : 0.0f;
  float den = fmaxf(cnt, 1.0f);
  out[r*128+c] = (r < u) ? accx[r*128+c]/den : 0.0f;
  if (c < 3) out[(size_t)NN*128 + r*3 + c] = (r < u) ? accp[r*3+c]/den : 0.0f;
  if (c == 0) out[(size_t)NN*128 + (size_t)NN*3 + r] = cnt;
}

// ---------------- launcher ----------------
extern "C" void kernel_launch(void* const* d_in, const int* in_sizes, int n_in,
                              void* d_out, int out_size, void* d_ws, size_t ws_size,
                              hipStream_t stream){
  (void)in_sizes; (void)n_in; (void)out_size;
  const float* x    = (const float*)d_in[0];
  const float* pos  = (const float*)d_in[1];
  const float* Wg1  = (const float*)d_in[2];
  const float* bg1  = (const float*)d_in[3];
  const float* Wg2  = (const float*)d_in[4];
  const float* bg2  = (const float*)d_in[5];
  const float* Wlin = (const float*)d_in[6];
  const float* Wsrc = (const float*)d_in[7];
  const float* Wdst = (const float*)d_in[8];
  const float* Wp1  = (const float*)d_in[9];
  const float* bp1  = (const float*)d_in[10];
  const float* Wp2  = (const float*)d_in[11];
  const float* bp2  = (const float*)d_in[12];
  const float* Wa1  = (const float*)d_in[13];
  const float* ba1  = (const float*)d_in[14];
  const float* Wa2  = (const float*)d_in[15];
  const float* ba2  = (const float*)d_in[16];
  const float* Wd   = (const float*)d_in[17];
  const float* bd   = (const float*)d_in[18];

  char* ws = (char*)d_ws;
  float* embF   = (float*)(ws + OFF_EMBF);
  float* sp     = (float*)(ws + OFF_SP);
  float* psum   = (float*)(ws + OFF_PSUM);
  int*   ssrc   = (int*)  (ws + OFF_SSRC);
  float* topv   = (float*)(ws + OFF_TOPV);
  int*   ksrc   = (int*)  (ws + OFF_KSRC);
  float* A      = (float*)(ws + OFF_A);
  float* B      = (float*)(ws + OFF_B);
  float* V      = (float*)(ws + OFF_V);
  float* h      = (float*)(ws + OFF_H);
  float* hd     = (float*)(ws + OFF_HD);
  float* y      = (float*)(ws + OFF_Y);
  float* accx   = (float*)(ws + OFF_ACCX);
  float* accp   = (float*)(ws + OFF_ACCP);
  int*   hist   = (int*)  (ws + OFF_HIST);
  int*   rank   = (int*)  (ws + OFF_RANK);
  int*   ucnt   = (int*)  (ws + OFF_UCNT);
  int*   vid    = (int*)  (ws + OFF_VID);
  int*   mi     = (int*)  (ws + OFF_META);
  int*   mx     = (int*)  (ws + OFF_META + 16);
  int*   Uo     = (int*)  (ws + OFF_META + 32);
  float* Kf     = (float*)(ws + OFF_KF);
  float* zc     = (float*)(ws + OFF_Z);

  const bool use_z = (ws_size >= OFF_Z + Z_BYTES);   // constant per run -> deterministic

  // rk = jax.random.split(jax.random.key(42), 2)  -- host threefry
  u32 rk0a, rk0b, rk1a, rk1b;
  tf2x32(0u, 42u, 0u, 0u, rk0a, rk0b);   // foldlike split: key_j = threefry(key, (0, j))
  tf2x32(0u, 42u, 0u, 1u, rk1a, rk1b);

  hipMemsetAsync(hist, 0, 8192*4, stream);
  hipMemsetAsync(accx, 0, (size_t)8192*128*4, stream);
  hipMemsetAsync(accp, 0, (size_t)8192*3*4, stream);

  k_init0<<<1, 64, 0, stream>>>(mi, mx);
  k_min<<<32, 256, 0, stream>>>(pos, mi);
  k_ext<<<32, 256, 0, stream>>>(pos, mi, mx);
  k_vid<<<32, 256, 0, stream>>>(pos, mi, mx, vid, hist, sp);
  k_emb<<<8192, 64, 0, stream>>>(x, Wg1, bg1, Wg2, bg2, rk0a, rk0b, embF);
  k_knn<<<8192, 64, 0, stream>>>(pos, sp, ksrc);
  if (use_z){
    k_colstats<true><<<dim3(32,32), 256, 0, stream>>>(embF, rk1a, rk1b, psum, zc);
    k_colfin<<<32, 256, 0, stream>>>(psum, embF, Kf);
    k_rowtopk_z<<<8192, 64, 0, stream>>>(zc, Kf, ssrc, topv);
  } else {
    k_colstats<false><<<dim3(32,32), 256, 0, stream>>>(embF, rk1a, rk1b, psum, nullptr);
    k_colfin<<<32, 256, 0, stream>>>(psum, embF, Kf);
    k_rowtopk<<<8192, 64, 0, stream>>>(embF, rk1a, rk1b, ssrc, topv);
  }
  k_xw<<<1024, 128, 0, stream>>>(x, Wsrc, Wdst, Wlin, A, B, V);
  k_edge<<<8192, 256, 0, stream>>>(pos, ssrc, topv, ksrc, A, B, V,
                                   Wp1, bp1, Wp2, bp2, Wa1, ba1, Wa2, ba2, h);
  k_down<<<1024, 128, 0, stream>>>(h, Wd, bd, hd);
  k_pool<<<8192, 128, 0, stream>>>(hd, ssrc, ksrc, y);
  k_scan<<<1, 256, 0, stream>>>(hist, rank, ucnt, Uo);
  k_agg<<<8192, 128, 0, stream>>>(y, pos, vid, rank, accx, accp);
  k_final<<<8192, 128, 0, stream>>>(accx, accp, ucnt, Uo, (float*)d_out);
}

// Round 7
// 1180.248 us; speedup vs baseline: 1.2994x; 1.0753x over previous
//
#include <hip/hip_runtime.h>
#include <stdint.h>

// ---------------------------------------------------------------------------
// Enc_block: KNN graph + gumbel-softmax soft edges + PointTransformerConv +
// down + neighbor max-pool + GridSampling.  N=8192, Cin=64, Cout=128, K=16.
// ---------------------------------------------------------------------------

typedef unsigned int u32;
typedef float v2f __attribute__((ext_vector_type(2)));

#define NN 8192
#define EPS20 1e-20f
#define QSCALE 489.0671f   // 65535/134; z in [-99.8, 33.3] -> q = (z+100)*QSCALE

// ---------------- threefry2x32 (JAX key schedule) ----------------
__host__ __device__ static inline u32 rotl32(u32 v, int r){ return (v<<r)|(v>>(32-r)); }

__host__ __device__ static inline void tf2x32(u32 k0, u32 k1, u32 c0, u32 c1, u32& o0, u32& o1){
  u32 ks2 = k0 ^ k1 ^ 0x1BD11BDAu;
  u32 x0 = c0 + k0;
  u32 x1 = c1 + k1;
#define TFR(r) x0 += x1; x1 = rotl32(x1,(r)); x1 ^= x0;
  TFR(13) TFR(15) TFR(26) TFR(6)
  x0 += k1;  x1 += ks2 + 1u;
  TFR(17) TFR(29) TFR(16) TFR(24)
  x0 += ks2; x1 += k0 + 2u;
  TFR(13) TFR(15) TFR(26) TFR(6)
  x0 += k0;  x1 += k1 + 3u;
  TFR(17) TFR(29) TFR(16) TFR(24)
  x0 += k1;  x1 += ks2 + 4u;
  TFR(13) TFR(15) TFR(26) TFR(6)
  x0 += ks2; x1 += k0 + 5u;
#undef TFR
  o0 = x0; o1 = x1;
}

__device__ static inline u32 rbits(u32 k0, u32 k1, u32 idx){
  u32 o0,o1; tf2x32(k0,k1, 0u, idx, o0,o1);   // partitionable: counter (0, idx)
  return o0 ^ o1;                              // 32-bit fold
}

__device__ static inline float u01(u32 b){
  return __uint_as_float((b>>9) | 0x3f800000u) - 1.0f;   // [0,1), JAX formula
}

// ---------------- workspace layout ----------------
// Prefix: live across the whole pipeline.
static constexpr size_t OFF_EMBF = 0;                              // [8192][12] f32: e[10], se, K
static constexpr size_t OFF_SP   = OFF_EMBF + (size_t)8192*12*4;
static constexpr size_t OFF_PSUM = OFF_SP   + (size_t)8192*4;      // [32][8192]
static constexpr size_t OFF_SSRC = OFF_PSUM + (size_t)32*8192*4;   // int [8192][16]
static constexpr size_t OFF_TOPV = OFF_SSRC + (size_t)8192*16*4;
static constexpr size_t OFF_KSRC = OFF_TOPV + (size_t)8192*16*4;   // int [8192][16]
static constexpr size_t OFF_HIST = OFF_KSRC + (size_t)8192*16*4;   // int [8192]
static constexpr size_t OFF_RANK = OFF_HIST + (size_t)8192*4;
static constexpr size_t OFF_UCNT = OFF_RANK + (size_t)8192*4;
static constexpr size_t OFF_VID  = OFF_UCNT + (size_t)8192*4;
static constexpr size_t OFF_META = OFF_VID  + (size_t)8192*4;      // mi i[3] @0, mx i[3] @16B, U i @32B
static constexpr size_t OFF_QKI  = OFF_META + 64;                  // int [8192] quantized K
static constexpr size_t OFF_CAND = OFF_QKI  + (size_t)8192*4;      // int [8192][32]
static constexpr size_t OFF_BIG  = (OFF_CAND + (size_t)8192*32*4 + 255) & ~(size_t)255;
// Overlap region: u16 z-cache [8192][8192] lives here during colstats..rescore;
// A/B/V/H/HD/Y/ACCX/ACCP live here afterwards (k_xw launched after rescore).
static constexpr size_t OFF_A    = OFF_BIG;
static constexpr size_t OFF_B    = OFF_A    + (size_t)8192*128*4;
static constexpr size_t OFF_V    = OFF_B    + (size_t)8192*128*4;
static constexpr size_t OFF_H    = OFF_V    + (size_t)8192*128*4;
static constexpr size_t OFF_HD   = OFF_H    + (size_t)8192*128*4;
static constexpr size_t OFF_Y    = OFF_HD   + (size_t)8192*128*4;
static constexpr size_t OFF_ACCX = OFF_Y    + (size_t)8192*128*4;
static constexpr size_t OFF_ACCP = OFF_ACCX + (size_t)8192*128*4;
static constexpr size_t OFF_ZQ   = OFF_BIG;
static constexpr size_t ZQ_BYTES = (size_t)NN*NN*2;

// ---------------- kernels ----------------

__global__ void k_init0(int* __restrict__ mi, int* __restrict__ mx){
  int t = threadIdx.x;
  if (t < 3){ mi[t] = 0x7f7fffff; mx[t] = 0; }
}

// per-dim min of pos (positive floats: int-bit compare is order-preserving)
__global__ __launch_bounds__(256) void k_min(const float* __restrict__ pos, int* __restrict__ mi){
  __shared__ int red[768];
  int t = threadIdx.x;
  int n = blockIdx.x*256 + t;
  red[t]     = __float_as_int(pos[n*3+0]);
  red[256+t] = __float_as_int(pos[n*3+1]);
  red[512+t] = __float_as_int(pos[n*3+2]);
  __syncthreads();
  for (int s=128; s>0; s>>=1){
    if (t < s){
      red[t]     = min(red[t],     red[t+s]);
      red[256+t] = min(red[256+t], red[256+t+s]);
      red[512+t] = min(red[512+t], red[512+t+s]);
    }
    __syncthreads();
  }
  if (t == 0){ atomicMin(&mi[0], red[0]); atomicMin(&mi[1], red[256]); atomicMin(&mi[2], red[512]); }
}

// per-dim max voxel index
__global__ __launch_bounds__(256) void k_ext(const float* __restrict__ pos, const int* __restrict__ mi,
                                             int* __restrict__ mx){
  __shared__ int red[768];
  int t = threadIdx.x;
  int n = blockIdx.x*256 + t;
  float p0 = __int_as_float(mi[0]), p1 = __int_as_float(mi[1]), p2 = __int_as_float(mi[2]);
  red[t]     = (int)floorf((pos[n*3+0]-p0)*2.0f);   // /0.5 == *2 exactly
  red[256+t] = (int)floorf((pos[n*3+1]-p1)*2.0f);
  red[512+t] = (int)floorf((pos[n*3+2]-p2)*2.0f);
  __syncthreads();
  for (int s=128; s>0; s>>=1){
    if (t < s){
      red[t]     = max(red[t],     red[t+s]);
      red[256+t] = max(red[256+t], red[256+t+s]);
      red[512+t] = max(red[512+t], red[512+t+s]);
    }
    __syncthreads();
  }
  if (t == 0){ atomicMax(&mx[0], red[0]); atomicMax(&mx[1], red[256]); atomicMax(&mx[2], red[512]); }
}

// voxel id + histogram + pos squared norms
__global__ __launch_bounds__(256) void k_vid(const float* __restrict__ pos,
                                             const int* __restrict__ mi, const int* __restrict__ mx,
                                             int* __restrict__ vid, int* __restrict__ hist,
                                             float* __restrict__ sp){
  int n = blockIdx.x*256 + threadIdx.x;
  float p0=pos[n*3], p1=pos[n*3+1], p2=pos[n*3+2];
  sp[n] = p0*p0 + p1*p1 + p2*p2;
  float q0 = __int_as_float(mi[0]), q1 = __int_as_float(mi[1]), q2 = __int_as_float(mi[2]);
  int v0 = (int)floorf((p0-q0)*2.0f);
  int v1 = (int)floorf((p1-q1)*2.0f);
  int v2 = (int)floorf((p2-q2)*2.0f);
  int nv1 = mx[1]+1, nv2 = mx[2]+1;
  int id = (v0*nv1 + v1)*nv2 + v2;
  vid[n] = id;
  atomicAdd(&hist[id], 1);
}

// embF[i] = { relu(x@Wg1+bg1)@Wg2+bg2 + u*0.001  (10), |emb|^2, 0 }
__global__ __launch_bounds__(64) void k_emb(const float* __restrict__ x,
    const float* __restrict__ Wg1, const float* __restrict__ bg1,
    const float* __restrict__ Wg2, const float* __restrict__ bg2,
    u32 ka, u32 kb, float* __restrict__ embF){
  int i = blockIdx.x; int t = threadIdx.x;
  __shared__ float xs[64], hs[64], esq[10];
  xs[t] = x[i*64+t];
  __syncthreads();
  float a = bg1[t];
  for (int k=0; k<64; k++) a += xs[k]*Wg1[k*64+t];
  hs[t] = fmaxf(a, 0.0f);
  __syncthreads();
  if (t < 10){
    float e = bg2[t];
    for (int k=0; k<64; k++) e += hs[k]*Wg2[k*10+t];
    e += u01(rbits(ka, kb, (u32)(i*10+t))) * 0.001f;
    embF[i*12+t] = e;
    esq[t] = e*e;
  }
  __syncthreads();
  if (t == 0){
    float ssum = 0.0f;
    #pragma unroll
    for (int d=0; d<10; d++) ssum += esq[d];
    embF[i*12+10] = ssum;
    embF[i*12+11] = 0.0f;
  }
}

// KNN: top-16 smallest d2 per row (diag excluded), ties -> lower index
__global__ __launch_bounds__(64) void k_knn(const float* __restrict__ pos, const float* __restrict__ sp,
                                            int* __restrict__ knn_src){
  int i = blockIdx.x; int l = threadIdx.x;
  float pi0=pos[i*3], pi1=pos[i*3+1], pi2=pos[i*3+2];
  float spi = sp[i];
  float lv[16]; int lj[16];
  #pragma unroll
  for (int s=0; s<16; s++){ lv[s]=1e30f; lj[s]=0x7fffffff; }
  for (int tt=0; tt<128; tt++){
    int j = l + 64*tt;
    if (j == i) continue;
    float d = spi + sp[j] - 2.0f*(pi0*pos[j*3] + pi1*pos[j*3+1] + pi2*pos[j*3+2]);
    d = fmaxf(d, 0.0f);
    if (d < lv[15]){
      lv[15]=d; lj[15]=j;
      #pragma unroll
      for (int s=15; s>0; s--){
        if (lv[s] < lv[s-1]){ float tv=lv[s]; lv[s]=lv[s-1]; lv[s-1]=tv; int tj=lj[s]; lj[s]=lj[s-1]; lj[s-1]=tj; }
      }
    }
  }
  for (int r=0; r<16; r++){
    float bv = lv[0]; int bj = lj[0];
    #pragma unroll
    for (int off=32; off>=1; off>>=1){
      float ov = __shfl_xor(bv, off);
      int   oj = __shfl_xor(bj, off);
      if (ov < bv || (ov == bv && oj < bj)){ bv = ov; bj = oj; }
    }
    if (l == 0) knn_src[i*16+r] = bj;
    if (lj[0] == bj){
      #pragma unroll
      for (int s=0; s<15; s++){ lv[s]=lv[s+1]; lj[s]=lj[s+1]; }
      lv[15]=1e30f; lj[15]=0x7fffffff;
    }
  }
}

// z = 2*(log(exp(-d2)+eps) + gumbel).  Hard bound: z <= 2*g_max <= 33.3,
// so sum(exp(z-40)) never overflows -> no max pass needed at all.
// Optionally stores quantized z (u16, step ~0.002) into the overlap cache.
template<bool STZ>
__global__ __launch_bounds__(256) void k_colstats(const float* __restrict__ embF,
                                                  u32 ka, u32 kb, float* __restrict__ psum,
                                                  unsigned short* __restrict__ zq){
  __shared__ float4 sE4[768];                 // 256 rows x 12 floats
  int t = threadIdx.x;
  int j = blockIdx.x*256 + t;
  int i0 = blockIdx.y*256;
  const float4* gF = (const float4*)embF;
  #pragma unroll
  for (int q=0; q<3; q++) sE4[t + 256*q] = gF[(size_t)i0*3 + t + 256*q];
  __syncthreads();
  float4 b0 = gF[j*3+0], b1 = gF[j*3+1], b2 = gF[j*3+2];
  float sej = b2.z;
  float s = 0.0f;
  unsigned short* zp = STZ ? (zq + ((size_t)i0<<13) + j) : nullptr;
  for (int r=0; r<256; r++){
    float4 a0 = sE4[r*3+0], a1 = sE4[r*3+1], a2 = sE4[r*3+2];
    float dot = a0.x*b0.x + a0.y*b0.y + a0.z*b0.z + a0.w*b0.w
              + a1.x*b1.x + a1.y*b1.y + a1.z*b1.z + a1.w*b1.w
              + a2.x*b2.x + a2.y*b2.y;
    float d2 = fmaxf(a2.z + sej - 2.0f*dot, 0.0f);
    float u = u01(rbits(ka, kb, (u32)(i0+r)*8192u + (u32)j));
    float g = -__logf(-__logf(u + EPS20) + EPS20);
    float z = 2.0f*(__logf(__expf(-d2) + EPS20) + g);
    s += __expf(z - 40.0f);
    if (STZ){
      float qf = (z + 100.0f)*QSCALE + 0.5f;
      qf = fminf(fmaxf(qf, 0.0f), 65535.0f);
      *zp = (unsigned short)qf;
      zp += NN;
    }
  }
  psum[blockIdx.y*NN + j] = s;
}

// K_j = 40 + log(sum_chunks psum); write f32 K into embF[j][11] and quantized K
__global__ __launch_bounds__(256) void k_colfin(const float* __restrict__ psum, float* __restrict__ embF,
                                                int* __restrict__ qKi){
  int j = blockIdx.x*256 + threadIdx.x;
  float S = 0.0f;
  for (int c=0; c<32; c++) S += psum[c*NN + j];
  float K = 40.0f + __logf(S);
  embF[j*12+11] = K;
  qKi[j] = (int)((K + 100.0f)*QSCALE + 0.5f);   // same transform as z (no clamp; int range)
}

// FALLBACK: per-row top-16 of y = z - K_j by full recompute
__global__ __launch_bounds__(64) void k_rowtopk(const float* __restrict__ embF,
    u32 ka, u32 kb, int* __restrict__ soft_src, float* __restrict__ top_v){
  int i = blockIdx.x; int l = threadIdx.x;
  const float4* gF = (const float4*)embF;
  float4 b0 = gF[i*3+0], b1 = gF[i*3+1], b2 = gF[i*3+2];
  float sei = b2.z;
  float lv[16]; int lj[16];
  #pragma unroll
  for (int s=0; s<16; s++){ lv[s]=-1e30f; lj[s]=0x7fffffff; }
  for (int tt=0; tt<128; tt++){
    int j = l + 64*tt;
    float4 a0 = gF[j*3+0], a1 = gF[j*3+1], a2 = gF[j*3+2];
    float dot = a0.x*b0.x + a0.y*b0.y + a0.z*b0.z + a0.w*b0.w
              + a1.x*b1.x + a1.y*b1.y + a1.z*b1.z + a1.w*b1.w
              + a2.x*b2.x + a2.y*b2.y;
    float d2 = fmaxf(a2.z + sei - 2.0f*dot, 0.0f);
    float u = u01(rbits(ka, kb, (u32)i*8192u + (u32)j));
    float g = -__logf(-__logf(u + EPS20) + EPS20);
    float z = 2.0f*(__logf(__expf(-d2) + EPS20) + g);
    float y = z - a2.w;
    if (y > lv[15]){
      lv[15]=y; lj[15]=j;
      #pragma unroll
      for (int s=15; s>0; s--){
        if (lv[s] > lv[s-1]){ float tv=lv[s]; lv[s]=lv[s-1]; lv[s-1]=tv; int tj=lj[s]; lj[s]=lj[s-1]; lj[s-1]=tj; }
      }
    }
  }
  for (int r=0; r<16; r++){
    float bv = lv[0]; int bj = lj[0];
    #pragma unroll
    for (int off=32; off>=1; off>>=1){
      float ov = __shfl_xor(bv, off);
      int   oj = __shfl_xor(bj, off);
      if (ov > bv || (ov == bv && oj < bj)){ bv = ov; bj = oj; }
    }
    if (l == 0){ soft_src[i*16+r] = bj; top_v[i*16+r] = __expf(bv); }
    if (lj[0] == bj){
      #pragma unroll
      for (int s=0; s<15; s++){ lv[s]=lv[s+1]; lj[s]=lj[s+1]; }
      lv[15]=-1e30f; lj[15]=0x7fffffff;
    }
  }
}

// cached path A: per-row top-32 candidates by integer qy = q_z - q_K
// (no threefry, no transcendentals; margin covers +-1-step quantization error)
__global__ __launch_bounds__(64) void k_qtopk(const unsigned short* __restrict__ zq,
    const int* __restrict__ qKi, int* __restrict__ cand){
  int i = blockIdx.x; int l = threadIdx.x;
  const uint4* zrow = (const uint4*)(zq + ((size_t)i<<13));   // 8 u16 per uint4
  int lv[16]; int lj[16];
  #pragma unroll
  for (int s=0; s<16; s++){ lv[s]=-0x40000000; lj[s]=0x7fffffff; }
  for (int tt=0; tt<16; tt++){
    int blk = l + 64*tt;
    uint4 zv = zrow[blk];
    int jb = blk*8;
    const int4* qk4 = (const int4*)(qKi + jb);
    int4 ka4 = qk4[0], kb4 = qk4[1];
    u32 wv[4] = {zv.x, zv.y, zv.z, zv.w};
    int qk[8] = {ka4.x,ka4.y,ka4.z,ka4.w, kb4.x,kb4.y,kb4.z,kb4.w};
    #pragma unroll
    for (int c=0; c<8; c++){
      int qz = (int)((wv[c>>1] >> ((c&1)*16)) & 0xffffu);
      int qy = qz - qk[c];
      if (qy > lv[15]){
        lv[15]=qy; lj[15]=jb+c;
        #pragma unroll
        for (int s=15; s>0; s--){
          if (lv[s] > lv[s-1]){ int tv=lv[s]; lv[s]=lv[s-1]; lv[s-1]=tv; int tj=lj[s]; lj[s]=lj[s-1]; lj[s-1]=tj; }
        }
      }
    }
  }
  for (int r=0; r<32; r++){
    int bv = lv[0]; int bj = lj[0];
    #pragma unroll
    for (int off=32; off>=1; off>>=1){
      int ov = __shfl_xor(bv, off);
      int oj = __shfl_xor(bj, off);
      if (ov > bv || (ov == bv && oj < bj)){ bv = ov; bj = oj; }
    }
    if (l == 0) cand[i*32+r] = bj;
    if (lj[0] == bj){
      #pragma unroll
      for (int s=0; s<15; s++){ lv[s]=lv[s+1]; lj[s]=lj[s+1]; }
      lv[15]=-0x40000000; lj[15]=0x7fffffff;
    }
  }
}

// cached path B: exact rescore of the 32 candidates -> exact top-16
// (y computed with the identical expression as k_rowtopk -> bit-equal values)
__global__ __launch_bounds__(64) void k_rescore(const float* __restrict__ embF,
    const int* __restrict__ cand, u32 ka, u32 kb,
    int* __restrict__ soft_src, float* __restrict__ top_v){
  int i = blockIdx.x; int l = threadIdx.x;
  const float4* gF = (const float4*)embF;
  float4 b0 = gF[i*3+0], b1 = gF[i*3+1], b2 = gF[i*3+2];
  float sei = b2.z;
  float y = -1e30f; int jc = 0x7fffffff;
  if (l < 32){
    jc = cand[i*32+l];
    float4 a0 = gF[jc*3+0], a1 = gF[jc*3+1], a2 = gF[jc*3+2];
    float dot = a0.x*b0.x + a0.y*b0.y + a0.z*b0.z + a0.w*b0.w
              + a1.x*b1.x + a1.y*b1.y + a1.z*b1.z + a1.w*b1.w
              + a2.x*b2.x + a2.y*b2.y;
    float d2 = fmaxf(a2.z + sei - 2.0f*dot, 0.0f);
    float u = u01(rbits(ka, kb, (u32)i*8192u + (u32)jc));
    float g = -__logf(-__logf(u + EPS20) + EPS20);
    float z = 2.0f*(__logf(__expf(-d2) + EPS20) + g);
    y = z - a2.w;
  }
  for (int r=0; r<16; r++){
    float bv = y; int bj = jc;
    #pragma unroll
    for (int off=32; off>=1; off>>=1){
      float ov = __shfl_xor(bv, off);
      int   oj = __shfl_xor(bj, off);
      if (ov > bv || (ov == bv && oj < bj)){ bv = ov; bj = oj; }
    }
    if (l == 0){ soft_src[i*16+r] = bj; top_v[i*16+r] = __expf(bv); }
    if (jc == bj){ y = -1e30f; jc = 0x7fffffff; }
  }
}

// A = x@Wsrc, B = x@Wdst, V = x@Wlin  (8 rows per block)
__global__ __launch_bounds__(128) void k_xw(const float* __restrict__ x,
    const float* __restrict__ Wsrc, const float* __restrict__ Wdst, const float* __restrict__ Wlin,
    float* __restrict__ A, float* __restrict__ B, float* __restrict__ V){
  int g0 = blockIdx.x*8; int c = threadIdx.x;
  __shared__ float xs[8][64];
  for (int idx=c; idx<512; idx+=128) xs[idx>>6][idx&63] = x[(g0 + (idx>>6))*64 + (idx&63)];
  __syncthreads();
  float aA[8], aB[8], aV[8];
  #pragma unroll
  for (int g=0; g<8; g++){ aA[g]=0.0f; aB[g]=0.0f; aV[g]=0.0f; }
  for (int k=0; k<64; k++){
    float ws=Wsrc[k*128+c], wd=Wdst[k*128+c], wl=Wlin[k*128+c];
    #pragma unroll
    for (int g=0; g<8; g++){
      float xv = xs[g][k];
      aA[g] += xv*ws; aB[g] += xv*wd; aV[g] += xv*wl;
    }
  }
  #pragma unroll
  for (int g=0; g<8; g++){
    A[(g0+g)*128+c]=aA[g]; B[(g0+g)*128+c]=aB[g]; V[(g0+g)*128+c]=aV[g];
  }
}

// k-split GEMM, packed-f32 accumulators: lane (kh=l>>5, q=l&31) does 8 edges x
// 4 cols (two v2f) over its 64-k half -> v_pk_fma_f32 halves VALU inst count.
#define GEMMW2(WPTR)                                                        \
  {                                                                         \
    const float4* __restrict__ Wp = ((const float4*)(WPTR)) + khbase*32 + q; \
    _Pragma("unroll")                                                       \
    for (int e=0; e<8; e++){ accA[e] = (v2f){0.f,0.f}; accB[e] = (v2f){0.f,0.f}; } \
    for (int kk=0; kk<16; kk++){                                            \
      float4 w0 = Wp[0], w1 = Wp[32], w2 = Wp[64], w3 = Wp[96];             \
      Wp += 128;                                                            \
      v2f w0a = {w0.x,w0.y}, w0b = {w0.z,w0.w};                             \
      v2f w1a = {w1.x,w1.y}, w1b = {w1.z,w1.w};                             \
      v2f w2a = {w2.x,w2.y}, w2b = {w2.z,w2.w};                             \
      v2f w3a = {w3.x,w3.y}, w3b = {w3.z,w3.w};                             \
      _Pragma("unroll")                                                     \
      for (int e=0; e<8; e++){                                              \
        const float4 ev = *(const float4*)(&ein[e0+e][khbase + 4*kk]);      \
        v2f ex = {ev.x,ev.x}, ey = {ev.y,ev.y}, ez = {ev.z,ev.z}, ew = {ev.w,ev.w}; \
        accA[e] += ex*w0a; accB[e] += ex*w0b;                               \
        accA[e] += ey*w1a; accB[e] += ey*w1b;                               \
        accA[e] += ez*w2a; accB[e] += ez*w2b;                               \
        accA[e] += ew*w3a; accB[e] += ew*w3b;                               \
      }                                                                     \
    }                                                                       \
  }

// cross-half reduction (lane ^ 32) + bias
#define KREDUCE(BPTR)                                                       \
  {                                                                         \
    float4 bb = ((const float4*)(BPTR))[q];                                 \
    _Pragma("unroll")                                                       \
    for (int e=0; e<8; e++){                                                \
      accA[e].x += __shfl_xor(accA[e].x, 32); accA[e].x += bb.x;            \
      accA[e].y += __shfl_xor(accA[e].y, 32); accA[e].y += bb.y;            \
      accB[e].x += __shfl_xor(accB[e].x, 32); accB[e].x += bb.z;            \
      accB[e].y += __shfl_xor(accB[e].y, 32); accB[e].y += bb.w;            \
    }                                                                       \
  }

// PointTransformerConv, per-target fused. 256 threads = 4 waves x 8 edges.
// NOTE: no min-waves clause -- (256,4) forced VGPR=64 + catastrophic spill (R2).
__global__ __launch_bounds__(256) void k_edge(const float* __restrict__ pos,
    const int* __restrict__ soft_src, const float* __restrict__ top_v, const int* __restrict__ knn_src,
    const float* __restrict__ A, const float* __restrict__ B, const float* __restrict__ V,
    const float* __restrict__ Wp1, const float* __restrict__ bp1,
    const float* __restrict__ Wp2, const float* __restrict__ bp2,
    const float* __restrict__ Wa1, const float* __restrict__ ba1,
    const float* __restrict__ Wa2, const float* __restrict__ ba2,
    float* __restrict__ h){
  int i = blockIdx.x; int t = threadIdx.x;
  int l = t & 63; int w = t >> 6; int e0 = w*8;
  int kh = l >> 5; int q = l & 31;
  const int khbase = kh*64;
  __shared__ float ein[32][128];
  __shared__ int   ssrc[32];
  __shared__ float sw[32];
  __shared__ float sdp[32][3];
  if (t < 32){
    int s; float wt;
    if (t < 16){ s = soft_src[i*16+t]; wt = top_v[i*16+t]; }
    else       { s = knn_src[i*16+(t-16)]; wt = 1.0f; }
    ssrc[t]=s; sw[t]=wt;
    sdp[t][0]=pos[i*3]-pos[s*3]; sdp[t][1]=pos[i*3+1]-pos[s*3+1]; sdp[t][2]=pos[i*3+2]-pos[s*3+2];
  }
  __syncthreads();
  v2f accA[8], accB[8], dlA[8], dlB[8];
  // stage 1: ph = relu(dpos @ Wp1 + bp1)
  {
    const float2* W1v = (const float2*)Wp1;
    float2 r0 = W1v[l], r1 = W1v[64+l], r2 = W1v[128+l];
    float2 bb = ((const float2*)bp1)[l];
    #pragma unroll
    for (int e=0; e<8; e++){
      float d0=sdp[e0+e][0], d1=sdp[e0+e][1], d2=sdp[e0+e][2];
      float2 v;
      v.x = fmaxf(d0*r0.x + d1*r1.x + d2*r2.x + bb.x, 0.0f);
      v.y = fmaxf(d0*r0.y + d1*r1.y + d2*r2.y + bb.y, 0.0f);
      *(float2*)(&ein[e0+e][2*l]) = v;
    }
  }
  // delta = ph @ Wp2 + bp2
  GEMMW2(Wp2); KREDUCE(bp2);
  #pragma unroll
  for (int e=0; e<8; e++){ dlA[e] = accA[e]; dlB[e] = accB[e]; }
  // q = B[i] - A[src] + delta   (kh==0 lanes write float4)
  if (kh == 0){
    float4 bi = ((const float4*)(&B[(size_t)i*128]))[q];
    #pragma unroll
    for (int e=0; e<8; e++){
      float4 av = ((const float4*)(&A[(size_t)ssrc[e0+e]*128]))[q];
      float4 v; v.x = bi.x - av.x + dlA[e].x; v.y = bi.y - av.y + dlA[e].y;
      v.z = bi.z - av.z + dlB[e].x; v.w = bi.w - av.w + dlB[e].y;
      *(float4*)(&ein[e0+e][4*q]) = v;
    }
  }
  // ah = relu(q @ Wa1 + ba1)
  GEMMW2(Wa1); KREDUCE(ba1);
  if (kh == 0){
    #pragma unroll
    for (int e=0; e<8; e++){
      float4 v; v.x=fmaxf(accA[e].x,0.f); v.y=fmaxf(accA[e].y,0.f);
      v.z=fmaxf(accB[e].x,0.f); v.w=fmaxf(accB[e].y,0.f);
      *(float4*)(&ein[e0+e][4*q]) = v;
    }
  }
  // logits = ah @ Wa2 + ba2
  GEMMW2(Wa2); KREDUCE(ba2);
  // cross-wave softmax over 32 edges; partials reuse dead ein rows:
  float* rbuf = &ein[0][0];
  v2f mA = accA[0], mB = accB[0];
  #pragma unroll
  for (int e=1; e<8; e++){
    mA.x=fmaxf(mA.x,accA[e].x); mA.y=fmaxf(mA.y,accA[e].y);
    mB.x=fmaxf(mB.x,accB[e].x); mB.y=fmaxf(mB.y,accB[e].y);
  }
  __syncthreads();                                   // all GEMM3 LDS reads done
  if (kh == 0){
    float4 mv; mv.x=mA.x; mv.y=mA.y; mv.z=mB.x; mv.w=mB.y;
    *(float4*)(&rbuf[w*128 + 4*q]) = mv;
  }
  __syncthreads();
  float4 M; M.x=-1e30f; M.y=-1e30f; M.z=-1e30f; M.w=-1e30f;
  #pragma unroll
  for (int ww=0; ww<4; ww++){
    float4 mm = *(const float4*)(&rbuf[ww*128 + 4*q]);
    M.x=fmaxf(M.x,mm.x); M.y=fmaxf(M.y,mm.y); M.z=fmaxf(M.z,mm.z); M.w=fmaxf(M.w,mm.w);
  }
  if (kh == 0){
    float4 s2; s2.x=0.f; s2.y=0.f; s2.z=0.f; s2.w=0.f;
    float4 h2; h2.x=0.f; h2.y=0.f; h2.z=0.f; h2.w=0.f;
    #pragma unroll
    for (int e=0; e<8; e++){
      int s = ssrc[e0+e]; float wt = sw[e0+e];
      float4 vv = ((const float4*)(&V[(size_t)s*128]))[q];
      float p;
      p = __expf(accA[e].x - M.x); s2.x += p; h2.x += p*(vv.x + dlA[e].x)*wt;
      p = __expf(accA[e].y - M.y); s2.y += p; h2.y += p*(vv.y + dlA[e].y)*wt;
      p = __expf(accB[e].x - M.z); s2.z += p; h2.z += p*(vv.z + dlB[e].x)*wt;
      p = __expf(accB[e].y - M.w); s2.w += p; h2.w += p*(vv.w + dlB[e].y)*wt;
    }
    *(float4*)(&rbuf[512  + w*128 + 4*q]) = s2;
    *(float4*)(&rbuf[1024 + w*128 + 4*q]) = h2;
  }
  __syncthreads();
  if (w == 0 && kh == 0){
    float4 S; S.x=0.f; S.y=0.f; S.z=0.f; S.w=0.f;
    float4 H; H.x=0.f; H.y=0.f; H.z=0.f; H.w=0.f;
    #pragma unroll
    for (int ww=0; ww<4; ww++){
      float4 sv = *(const float4*)(&rbuf[512  + ww*128 + 4*q]);
      float4 hv = *(const float4*)(&rbuf[1024 + ww*128 + 4*q]);
      S.x+=sv.x; S.y+=sv.y; S.z+=sv.z; S.w+=sv.w;
      H.x+=hv.x; H.y+=hv.y; H.z+=hv.z; H.w+=hv.w;
    }
    float4 o; o.x=H.x/(S.x+1e-16f); o.y=H.y/(S.y+1e-16f);
    o.z=H.z/(S.z+1e-16f); o.w=H.w/(S.w+1e-16f);
    *(float4*)(&h[(size_t)i*128 + 4*q]) = o;
  }
}

// hd = relu(h @ Wd + bd)
__global__ __launch_bounds__(128) void k_down(const float* __restrict__ h,
    const float* __restrict__ Wd, const float* __restrict__ bd, float* __restrict__ hd){
  int g0 = blockIdx.x*8; int c = threadIdx.x;
  __shared__ float hs[8][128];
  for (int idx=c; idx<1024; idx+=128) hs[idx>>7][idx&127] = h[(g0 + (idx>>7))*128 + (idx&127)];
  __syncthreads();
  float acc[8]; float b = bd[c];
  #pragma unroll
  for (int g=0; g<8; g++) acc[g] = b;
  for (int k=0; k<128; k+=4){
    float w0=Wd[(k+0)*128+c], w1=Wd[(k+1)*128+c], w2=Wd[(k+2)*128+c], w3=Wd[(k+3)*128+c];
    #pragma unroll
    for (int g=0; g<8; g++){
      const float4 ev = *(const float4*)(&hs[g][k]);
      acc[g] += ev.x*w0 + ev.y*w1 + ev.z*w2 + ev.w*w3;
    }
  }
  #pragma unroll
  for (int g=0; g<8; g++) hd[(g0+g)*128+c] = fmaxf(acc[g], 0.0f);
}

// y = max(hd[i], max over 32 neighbors hd[src])
__global__ __launch_bounds__(128) void k_pool(const float* __restrict__ hd,
    const int* __restrict__ soft_src, const int* __restrict__ knn_src, float* __restrict__ y){
  int i = blockIdx.x; int c = threadIdx.x;
  __shared__ int ss[32];
  if (c < 16) ss[c] = soft_src[i*16+c];
  else if (c < 32) ss[c] = knn_src[i*16+(c-16)];
  __syncthreads();
  float p = hd[i*128+c];
  for (int e=0; e<32; e++) p = fmaxf(p, hd[ss[e]*128+c]);
  y[i*128+c] = p;
}

// ranks = sorted-unique inverse (count of nonzero bins with smaller vid)
__global__ __launch_bounds__(256) void k_scan(const int* __restrict__ hist,
    int* __restrict__ rank, int* __restrict__ ucnt, int* __restrict__ Uo){
  __shared__ int part[256];
  int t = threadIdx.x;
  int base = t*32;
  int cnt = 0;
  for (int b=0; b<32; b++) cnt += (hist[base+b] > 0);
  part[t] = cnt;
  __syncthreads();
  if (t == 0){
    int run = 0;
    for (int q=0; q<256; q++){ int v = part[q]; part[q] = run; run += v; }
    Uo[0] = run;
  }
  __syncthreads();
  int run = part[t];
  for (int b=0; b<32; b++){
    int bin = base + b;
    rank[bin] = run;
    int hv = hist[bin];
    if (hv > 0){ ucnt[run] = hv; run++; }
  }
}

__global__ __launch_bounds__(128) void k_agg(const float* __restrict__ y, const float* __restrict__ pos,
    const int* __restrict__ vid, const int* __restrict__ rank,
    float* __restrict__ accx, float* __restrict__ accp){
  int n = blockIdx.x; int c = threadIdx.x;
  int r = rank[vid[n]];
  atomicAdd(&accx[r*128+c], y[n*128+c]);
  if (c < 3) atomicAdd(&accp[r*3+c], pos[n*3+c]);
}

__global__ __launch_bounds__(128) void k_final(const float* __restrict__ accx, const float* __restrict__ accp,
    const int* __restrict__ ucnt, const int* __restrict__ Uo, float* __restrict__ out){
  int r = blockIdx.x; int c = threadIdx.x;
  int u = Uo[0];
  float cnt = (r < u) ? (float)ucnt[r] : 0.0f;
  float den = fmaxf(cnt, 1.0f);
  out[r*128+c] = (r < u) ? accx[r*128+c]/den : 0.0f;
  if (c < 3) out[(size_t)NN*128 + r*3 + c] = (r < u) ? accp[r*3+c]/den : 0.0f;
  if (c == 0) out[(size_t)NN*128 + (size_t)NN*3 + r] = cnt;
}

// ---------------- launcher ----------------
extern "C" void kernel_launch(void* const* d_in, const int* in_sizes, int n_in,
                              void* d_out, int out_size, void* d_ws, size_t ws_size,
                              hipStream_t stream){
  (void)in_sizes; (void)n_in; (void)out_size;
  const float* x    = (const float*)d_in[0];
  const float* pos  = (const float*)d_in[1];
  const float* Wg1  = (const float*)d_in[2];
  const float* bg1  = (const float*)d_in[3];
  const float* Wg2  = (const float*)d_in[4];
  const float* bg2  = (const float*)d_in[5];
  const float* Wlin = (const float*)d_in[6];
  const float* Wsrc = (const float*)d_in[7];
  const float* Wdst = (const float*)d_in[8];
  const float* Wp1  = (const float*)d_in[9];
  const float* bp1  = (const float*)d_in[10];
  const float* Wp2  = (const float*)d_in[11];
  const float* bp2  = (const float*)d_in[12];
  const float* Wa1  = (const float*)d_in[13];
  const float* ba1  = (const float*)d_in[14];
  const float* Wa2  = (const float*)d_in[15];
  const float* ba2  = (const float*)d_in[16];
  const float* Wd   = (const float*)d_in[17];
  const float* bd   = (const float*)d_in[18];

  char* ws = (char*)d_ws;
  float* embF   = (float*)(ws + OFF_EMBF);
  float* sp     = (float*)(ws + OFF_SP);
  float* psum   = (float*)(ws + OFF_PSUM);
  int*   ssrc   = (int*)  (ws + OFF_SSRC);
  float* topv   = (float*)(ws + OFF_TOPV);
  int*   ksrc   = (int*)  (ws + OFF_KSRC);
  int*   hist   = (int*)  (ws + OFF_HIST);
  int*   rank   = (int*)  (ws + OFF_RANK);
  int*   ucnt   = (int*)  (ws + OFF_UCNT);
  int*   vid    = (int*)  (ws + OFF_VID);
  int*   mi     = (int*)  (ws + OFF_META);
  int*   mx     = (int*)  (ws + OFF_META + 16);
  int*   Uo     = (int*)  (ws + OFF_META + 32);
  int*   qKi    = (int*)  (ws + OFF_QKI);
  int*   cand   = (int*)  (ws + OFF_CAND);
  float* A      = (float*)(ws + OFF_A);
  float* B      = (float*)(ws + OFF_B);
  float* V      = (float*)(ws + OFF_V);
  float* h      = (float*)(ws + OFF_H);
  float* hd     = (float*)(ws + OFF_HD);
  float* y      = (float*)(ws + OFF_Y);
  float* accx   = (float*)(ws + OFF_ACCX);
  float* accp   = (float*)(ws + OFF_ACCP);
  unsigned short* zq = (unsigned short*)(ws + OFF_ZQ);

  const bool use_q = (ws_size >= OFF_ZQ + ZQ_BYTES);   // constant per run -> deterministic

  // rk = jax.random.split(jax.random.key(42), 2)  -- host threefry (foldlike)
  u32 rk0a, rk0b, rk1a, rk1b;
  tf2x32(0u, 42u, 0u, 0u, rk0a, rk0b);
  tf2x32(0u, 42u, 0u, 1u, rk1a, rk1b);

  hipMemsetAsync(hist, 0, 8192*4, stream);
  k_init0<<<1, 64, 0, stream>>>(mi, mx);
  k_min<<<32, 256, 0, stream>>>(pos, mi);
  k_ext<<<32, 256, 0, stream>>>(pos, mi, mx);
  k_vid<<<32, 256, 0, stream>>>(pos, mi, mx, vid, hist, sp);
  k_emb<<<8192, 64, 0, stream>>>(x, Wg1, bg1, Wg2, bg2, rk0a, rk0b, embF);
  k_knn<<<8192, 64, 0, stream>>>(pos, sp, ksrc);
  if (use_q){
    k_colstats<true><<<dim3(32,32), 256, 0, stream>>>(embF, rk1a, rk1b, psum, zq);
    k_colfin<<<32, 256, 0, stream>>>(psum, embF, qKi);
    k_qtopk<<<8192, 64, 0, stream>>>(zq, qKi, cand);
    k_rescore<<<8192, 64, 0, stream>>>(embF, cand, rk1a, rk1b, ssrc, topv);
  } else {
    k_colstats<false><<<dim3(32,32), 256, 0, stream>>>(embF, rk1a, rk1b, psum, nullptr);
    k_colfin<<<32, 256, 0, stream>>>(psum, embF, qKi);
    k_rowtopk<<<8192, 64, 0, stream>>>(embF, rk1a, rk1b, ssrc, topv);
  }
  // Overlap region is free of z-cache readers from here on.
  k_xw<<<1024, 128, 0, stream>>>(x, Wsrc, Wdst, Wlin, A, B, V);
  k_edge<<<8192, 256, 0, stream>>>(pos, ssrc, topv, ksrc, A, B, V,
                                   Wp1, bp1, Wp2, bp2, Wa1, ba1, Wa2, ba2, h);
  k_down<<<1024, 128, 0, stream>>>(h, Wd, bd, hd);
  k_pool<<<8192, 128, 0, stream>>>(hd, ssrc, ksrc, y);
  hipMemsetAsync(accx, 0, (size_t)8192*128*4, stream);
  hipMemsetAsync(accp, 0, (size_t)8192*3*4, stream);
  k_scan<<<1, 256, 0, stream>>>(hist, rank, ucnt, Uo);
  k_agg<<<8192, 128, 0, stream>>>(y, pos, vid, rank, accx, accp);
  k_final<<<8192, 128, 0, stream>>>(accx, accp, ucnt, Uo, (float*)d_out);
}

// Round 8
// 1144.971 us; speedup vs baseline: 1.3394x; 1.0308x over previous
//
#include <hip/hip_runtime.h>
#include <stdint.h>

// ---------------------------------------------------------------------------
// Enc_block: KNN graph + gumbel-softmax soft edges + PointTransformerConv +
// down + neighbor max-pool + GridSampling.  N=8192, Cin=64, Cout=128, K=16.
// ---------------------------------------------------------------------------

typedef unsigned int u32;
typedef float v2f __attribute__((ext_vector_type(2)));
typedef float v4f __attribute__((ext_vector_type(4)));

#define NN 8192
#define EPS20 1e-20f
#define QSCALE 489.0671f   // 65535/134; z in [-99.8, 33.3] -> q = (z+100)*QSCALE

// packed fp32 FMA with op_sel broadcast of src1 (no splat movs):
// lo-variant: both result halves use s1.lo ; hi-variant: both use s1.hi
__device__ static inline void pk_fma_lo(v2f& acc, v2f w, v2f e){
  asm("v_pk_fma_f32 %0, %1, %2, %0 op_sel:[0,0,0] op_sel_hi:[1,0,1]"
      : "+v"(acc) : "v"(w), "v"(e));
}
__device__ static inline void pk_fma_hi(v2f& acc, v2f w, v2f e){
  asm("v_pk_fma_f32 %0, %1, %2, %0 op_sel:[0,1,0] op_sel_hi:[1,1,1]"
      : "+v"(acc) : "v"(w), "v"(e));
}

// ---------------- threefry2x32 (JAX key schedule) ----------------
__host__ __device__ static inline u32 rotl32(u32 v, int r){ return (v<<r)|(v>>(32-r)); }

__host__ __device__ static inline void tf2x32(u32 k0, u32 k1, u32 c0, u32 c1, u32& o0, u32& o1){
  u32 ks2 = k0 ^ k1 ^ 0x1BD11BDAu;
  u32 x0 = c0 + k0;
  u32 x1 = c1 + k1;
#define TFR(r) x0 += x1; x1 = rotl32(x1,(r)); x1 ^= x0;
  TFR(13) TFR(15) TFR(26) TFR(6)
  x0 += k1;  x1 += ks2 + 1u;
  TFR(17) TFR(29) TFR(16) TFR(24)
  x0 += ks2; x1 += k0 + 2u;
  TFR(13) TFR(15) TFR(26) TFR(6)
  x0 += k0;  x1 += k1 + 3u;
  TFR(17) TFR(29) TFR(16) TFR(24)
  x0 += k1;  x1 += ks2 + 4u;
  TFR(13) TFR(15) TFR(26) TFR(6)
  x0 += ks2; x1 += k0 + 5u;
#undef TFR
  o0 = x0; o1 = x1;
}

__device__ static inline u32 rbits(u32 k0, u32 k1, u32 idx){
  u32 o0,o1; tf2x32(k0,k1, 0u, idx, o0,o1);   // partitionable: counter (0, idx)
  return o0 ^ o1;                              // 32-bit fold
}

__device__ static inline float u01(u32 b){
  return __uint_as_float((b>>9) | 0x3f800000u) - 1.0f;   // [0,1), JAX formula
}

// z = 2*(log(exp(-d2)+eps) + g)  ==  2*(g - d2) for all entries that can reach
// top-16 or contribute to the colsum (need d2 within ~16.6 of row min; there the
// eps correction is <=1e-4 and the identity matches the reference's exp/log
// roundtrip to ~1e-6 -- same order as __expf deltas).  Saves 2 TRANS/element.
__device__ static inline float gumbel_g(u32 ub){
  float u = u01(ub);
  float w = -__logf(u + EPS20);
  return -__logf(w + EPS20);
}

// ---------------- workspace layout ----------------
static constexpr size_t OFF_EMBF = 0;                              // [8192][12] f32: e[10], se, K
static constexpr size_t OFF_SP   = OFF_EMBF + (size_t)8192*12*4;
static constexpr size_t OFF_PSUM = OFF_SP   + (size_t)8192*4;      // [32][8192]
static constexpr size_t OFF_SSRC = OFF_PSUM + (size_t)32*8192*4;   // int [8192][16]
static constexpr size_t OFF_TOPV = OFF_SSRC + (size_t)8192*16*4;
static constexpr size_t OFF_KSRC = OFF_TOPV + (size_t)8192*16*4;   // int [8192][16]
static constexpr size_t OFF_HIST = OFF_KSRC + (size_t)8192*16*4;   // int [8192]
static constexpr size_t OFF_RANK = OFF_HIST + (size_t)8192*4;
static constexpr size_t OFF_UCNT = OFF_RANK + (size_t)8192*4;
static constexpr size_t OFF_VID  = OFF_UCNT + (size_t)8192*4;
static constexpr size_t OFF_META = OFF_VID  + (size_t)8192*4;      // mi i[3] @0, mx i[3] @16B, U i @32B
static constexpr size_t OFF_QKI  = OFF_META + 64;                  // int [8192] quantized K
static constexpr size_t OFF_CAND = OFF_QKI  + (size_t)8192*4;      // int [8192][32]
static constexpr size_t OFF_BIG  = (OFF_CAND + (size_t)8192*32*4 + 255) & ~(size_t)255;
// Overlap region: u16 z-cache [8192][8192] lives here during colstats..rescore;
// A/B/V/H/HD/Y/ACCX/ACCP live here afterwards (k_xw launched after rescore).
static constexpr size_t OFF_A    = OFF_BIG;
static constexpr size_t OFF_B    = OFF_A    + (size_t)8192*128*4;
static constexpr size_t OFF_V    = OFF_B    + (size_t)8192*128*4;
static constexpr size_t OFF_H    = OFF_V    + (size_t)8192*128*4;
static constexpr size_t OFF_HD   = OFF_H    + (size_t)8192*128*4;
static constexpr size_t OFF_Y    = OFF_HD   + (size_t)8192*128*4;
static constexpr size_t OFF_ACCX = OFF_Y    + (size_t)8192*128*4;
static constexpr size_t OFF_ACCP = OFF_ACCX + (size_t)8192*128*4;
static constexpr size_t OFF_ZQ   = OFF_BIG;
static constexpr size_t ZQ_BYTES = (size_t)NN*NN*2;

// ---------------- kernels ----------------

__global__ void k_init0(int* __restrict__ mi, int* __restrict__ mx){
  int t = threadIdx.x;
  if (t < 3){ mi[t] = 0x7f7fffff; mx[t] = 0; }
}

// per-dim min of pos (positive floats: int-bit compare is order-preserving)
__global__ __launch_bounds__(256) void k_min(const float* __restrict__ pos, int* __restrict__ mi){
  __shared__ int red[768];
  int t = threadIdx.x;
  int n = blockIdx.x*256 + t;
  red[t]     = __float_as_int(pos[n*3+0]);
  red[256+t] = __float_as_int(pos[n*3+1]);
  red[512+t] = __float_as_int(pos[n*3+2]);
  __syncthreads();
  for (int s=128; s>0; s>>=1){
    if (t < s){
      red[t]     = min(red[t],     red[t+s]);
      red[256+t] = min(red[256+t], red[256+t+s]);
      red[512+t] = min(red[512+t], red[512+t+s]);
    }
    __syncthreads();
  }
  if (t == 0){ atomicMin(&mi[0], red[0]); atomicMin(&mi[1], red[256]); atomicMin(&mi[2], red[512]); }
}

// per-dim max voxel index
__global__ __launch_bounds__(256) void k_ext(const float* __restrict__ pos, const int* __restrict__ mi,
                                             int* __restrict__ mx){
  __shared__ int red[768];
  int t = threadIdx.x;
  int n = blockIdx.x*256 + t;
  float p0 = __int_as_float(mi[0]), p1 = __int_as_float(mi[1]), p2 = __int_as_float(mi[2]);
  red[t]     = (int)floorf((pos[n*3+0]-p0)*2.0f);   // /0.5 == *2 exactly
  red[256+t] = (int)floorf((pos[n*3+1]-p1)*2.0f);
  red[512+t] = (int)floorf((pos[n*3+2]-p2)*2.0f);
  __syncthreads();
  for (int s=128; s>0; s>>=1){
    if (t < s){
      red[t]     = max(red[t],     red[t+s]);
      red[256+t] = max(red[256+t], red[256+t+s]);
      red[512+t] = max(red[512+t], red[512+t+s]);
    }
    __syncthreads();
  }
  if (t == 0){ atomicMax(&mx[0], red[0]); atomicMax(&mx[1], red[256]); atomicMax(&mx[2], red[512]); }
}

// voxel id + histogram + pos squared norms
__global__ __launch_bounds__(256) void k_vid(const float* __restrict__ pos,
                                             const int* __restrict__ mi, const int* __restrict__ mx,
                                             int* __restrict__ vid, int* __restrict__ hist,
                                             float* __restrict__ sp){
  int n = blockIdx.x*256 + threadIdx.x;
  float p0=pos[n*3], p1=pos[n*3+1], p2=pos[n*3+2];
  sp[n] = p0*p0 + p1*p1 + p2*p2;
  float q0 = __int_as_float(mi[0]), q1 = __int_as_float(mi[1]), q2 = __int_as_float(mi[2]);
  int v0 = (int)floorf((p0-q0)*2.0f);
  int v1 = (int)floorf((p1-q1)*2.0f);
  int v2 = (int)floorf((p2-q2)*2.0f);
  int nv1 = mx[1]+1, nv2 = mx[2]+1;
  int id = (v0*nv1 + v1)*nv2 + v2;
  vid[n] = id;
  atomicAdd(&hist[id], 1);
}

// embF[i] = { relu(x@Wg1+bg1)@Wg2+bg2 + u*0.001  (10), |emb|^2, 0 }
__global__ __launch_bounds__(64) void k_emb(const float* __restrict__ x,
    const float* __restrict__ Wg1, const float* __restrict__ bg1,
    const float* __restrict__ Wg2, const float* __restrict__ bg2,
    u32 ka, u32 kb, float* __restrict__ embF){
  int i = blockIdx.x; int t = threadIdx.x;
  __shared__ float xs[64], hs[64], esq[10];
  xs[t] = x[i*64+t];
  __syncthreads();
  float a = bg1[t];
  for (int k=0; k<64; k++) a += xs[k]*Wg1[k*64+t];
  hs[t] = fmaxf(a, 0.0f);
  __syncthreads();
  if (t < 10){
    float e = bg2[t];
    for (int k=0; k<64; k++) e += hs[k]*Wg2[k*10+t];
    e += u01(rbits(ka, kb, (u32)(i*10+t))) * 0.001f;
    embF[i*12+t] = e;
    esq[t] = e*e;
  }
  __syncthreads();
  if (t == 0){
    float ssum = 0.0f;
    #pragma unroll
    for (int d=0; d<10; d++) ssum += esq[d];
    embF[i*12+10] = ssum;
    embF[i*12+11] = 0.0f;
  }
}

// KNN: top-16 smallest d2 per row (diag excluded), ties -> lower index
__global__ __launch_bounds__(64) void k_knn(const float* __restrict__ pos, const float* __restrict__ sp,
                                            int* __restrict__ knn_src){
  int i = blockIdx.x; int l = threadIdx.x;
  float pi0=pos[i*3], pi1=pos[i*3+1], pi2=pos[i*3+2];
  float spi = sp[i];
  float lv[16]; int lj[16];
  #pragma unroll
  for (int s=0; s<16; s++){ lv[s]=1e30f; lj[s]=0x7fffffff; }
  for (int tt=0; tt<128; tt++){
    int j = l + 64*tt;
    if (j == i) continue;
    float d = spi + sp[j] - 2.0f*(pi0*pos[j*3] + pi1*pos[j*3+1] + pi2*pos[j*3+2]);
    d = fmaxf(d, 0.0f);
    if (d < lv[15]){
      lv[15]=d; lj[15]=j;
      #pragma unroll
      for (int s=15; s>0; s--){
        if (lv[s] < lv[s-1]){ float tv=lv[s]; lv[s]=lv[s-1]; lv[s-1]=tv; int tj=lj[s]; lj[s]=lj[s-1]; lj[s-1]=tj; }
      }
    }
  }
  for (int r=0; r<16; r++){
    float bv = lv[0]; int bj = lj[0];
    #pragma unroll
    for (int off=32; off>=1; off>>=1){
      float ov = __shfl_xor(bv, off);
      int   oj = __shfl_xor(bj, off);
      if (ov < bv || (ov == bv && oj < bj)){ bv = ov; bj = oj; }
    }
    if (l == 0) knn_src[i*16+r] = bj;
    if (lj[0] == bj){
      #pragma unroll
      for (int s=0; s<15; s++){ lv[s]=lv[s+1]; lj[s]=lj[s+1]; }
      lv[15]=1e30f; lj[15]=0x7fffffff;
    }
  }
}

// z = 2*(g - d2).  Hard bound: z <= 2*g_max <= 33.3, so sum(exp(z-40)) never
// overflows -> no max pass needed.  Stores quantized z (u16) into the cache.
template<bool STZ>
__global__ __launch_bounds__(256) void k_colstats(const float* __restrict__ embF,
                                                  u32 ka, u32 kb, float* __restrict__ psum,
                                                  unsigned short* __restrict__ zq){
  __shared__ float4 sE4[768];                 // 256 rows x 12 floats
  int t = threadIdx.x;
  int j = blockIdx.x*256 + t;
  int i0 = blockIdx.y*256;
  const float4* gF = (const float4*)embF;
  #pragma unroll
  for (int q=0; q<3; q++) sE4[t + 256*q] = gF[(size_t)i0*3 + t + 256*q];
  __syncthreads();
  float4 b0 = gF[j*3+0], b1 = gF[j*3+1], b2 = gF[j*3+2];
  float sej = b2.z;
  float s = 0.0f;
  unsigned short* zp = STZ ? (zq + ((size_t)i0<<13) + j) : nullptr;
  for (int r=0; r<256; r++){
    float4 a0 = sE4[r*3+0], a1 = sE4[r*3+1], a2 = sE4[r*3+2];
    float dot = a0.x*b0.x + a0.y*b0.y + a0.z*b0.z + a0.w*b0.w
              + a1.x*b1.x + a1.y*b1.y + a1.z*b1.z + a1.w*b1.w
              + a2.x*b2.x + a2.y*b2.y;
    float d2 = fmaxf(a2.z + sej - 2.0f*dot, 0.0f);
    float g = gumbel_g(rbits(ka, kb, (u32)(i0+r)*8192u + (u32)j));
    float z = 2.0f*(g - d2);
    s += __expf(z - 40.0f);
    if (STZ){
      float qf = (z + 100.0f)*QSCALE + 0.5f;
      qf = fminf(fmaxf(qf, 0.0f), 65535.0f);
      *zp = (unsigned short)qf;
      zp += NN;
    }
  }
  psum[blockIdx.y*NN + j] = s;
}

// K_j = 40 + log(sum_chunks psum); write f32 K into embF[j][11] and quantized K
__global__ __launch_bounds__(256) void k_colfin(const float* __restrict__ psum, float* __restrict__ embF,
                                                int* __restrict__ qKi){
  int j = blockIdx.x*256 + threadIdx.x;
  float S = 0.0f;
  for (int c=0; c<32; c++) S += psum[c*NN + j];
  float K = 40.0f + __logf(S);
  embF[j*12+11] = K;
  qKi[j] = (int)((K + 100.0f)*QSCALE + 0.5f);   // same transform as z
}

// FALLBACK: per-row top-16 of y = z - K_j by full recompute
__global__ __launch_bounds__(64) void k_rowtopk(const float* __restrict__ embF,
    u32 ka, u32 kb, int* __restrict__ soft_src, float* __restrict__ top_v){
  int i = blockIdx.x; int l = threadIdx.x;
  const float4* gF = (const float4*)embF;
  float4 b0 = gF[i*3+0], b1 = gF[i*3+1], b2 = gF[i*3+2];
  float sei = b2.z;
  float lv[16]; int lj[16];
  #pragma unroll
  for (int s=0; s<16; s++){ lv[s]=-1e30f; lj[s]=0x7fffffff; }
  for (int tt=0; tt<128; tt++){
    int j = l + 64*tt;
    float4 a0 = gF[j*3+0], a1 = gF[j*3+1], a2 = gF[j*3+2];
    float dot = a0.x*b0.x + a0.y*b0.y + a0.z*b0.z + a0.w*b0.w
              + a1.x*b1.x + a1.y*b1.y + a1.z*b1.z + a1.w*b1.w
              + a2.x*b2.x + a2.y*b2.y;
    float d2 = fmaxf(a2.z + sei - 2.0f*dot, 0.0f);
    float g = gumbel_g(rbits(ka, kb, (u32)i*8192u + (u32)j));
    float z = 2.0f*(g - d2);
    float y = z - a2.w;
    if (y > lv[15]){
      lv[15]=y; lj[15]=j;
      #pragma unroll
      for (int s=15; s>0; s--){
        if (lv[s] > lv[s-1]){ float tv=lv[s]; lv[s]=lv[s-1]; lv[s-1]=tv; int tj=lj[s]; lj[s]=lj[s-1]; lj[s-1]=tj; }
      }
    }
  }
  for (int r=0; r<16; r++){
    float bv = lv[0]; int bj = lj[0];
    #pragma unroll
    for (int off=32; off>=1; off>>=1){
      float ov = __shfl_xor(bv, off);
      int   oj = __shfl_xor(bj, off);
      if (ov > bv || (ov == bv && oj < bj)){ bv = ov; bj = oj; }
    }
    if (l == 0){ soft_src[i*16+r] = bj; top_v[i*16+r] = __expf(bv); }
    if (lj[0] == bj){
      #pragma unroll
      for (int s=0; s<15; s++){ lv[s]=lv[s+1]; lj[s]=lj[s+1]; }
      lv[15]=-1e30f; lj[15]=0x7fffffff;
    }
  }
}

// cached path A: per-row top-32 candidates by integer qy = q_z - q_K
__global__ __launch_bounds__(64) void k_qtopk(const unsigned short* __restrict__ zq,
    const int* __restrict__ qKi, int* __restrict__ cand){
  int i = blockIdx.x; int l = threadIdx.x;
  const uint4* zrow = (const uint4*)(zq + ((size_t)i<<13));   // 8 u16 per uint4
  int lv[16]; int lj[16];
  #pragma unroll
  for (int s=0; s<16; s++){ lv[s]=-0x40000000; lj[s]=0x7fffffff; }
  for (int tt=0; tt<16; tt++){
    int blk = l + 64*tt;
    uint4 zv = zrow[blk];
    int jb = blk*8;
    const int4* qk4 = (const int4*)(qKi + jb);
    int4 ka4 = qk4[0], kb4 = qk4[1];
    u32 wv[4] = {zv.x, zv.y, zv.z, zv.w};
    int qk[8] = {ka4.x,ka4.y,ka4.z,ka4.w, kb4.x,kb4.y,kb4.z,kb4.w};
    #pragma unroll
    for (int c=0; c<8; c++){
      int qz = (int)((wv[c>>1] >> ((c&1)*16)) & 0xffffu);
      int qy = qz - qk[c];
      if (qy > lv[15]){
        lv[15]=qy; lj[15]=jb+c;
        #pragma unroll
        for (int s=15; s>0; s--){
          if (lv[s] > lv[s-1]){ int tv=lv[s]; lv[s]=lv[s-1]; lv[s-1]=tv; int tj=lj[s]; lj[s]=lj[s-1]; lj[s-1]=tj; }
        }
      }
    }
  }
  for (int r=0; r<32; r++){
    int bv = lv[0]; int bj = lj[0];
    #pragma unroll
    for (int off=32; off>=1; off>>=1){
      int ov = __shfl_xor(bv, off);
      int oj = __shfl_xor(bj, off);
      if (ov > bv || (ov == bv && oj < bj)){ bv = ov; bj = oj; }
    }
    if (l == 0) cand[i*32+r] = bj;
    if (lj[0] == bj){
      #pragma unroll
      for (int s=0; s<15; s++){ lv[s]=lv[s+1]; lj[s]=lj[s+1]; }
      lv[15]=-0x40000000; lj[15]=0x7fffffff;
    }
  }
}

// cached path B: exact rescore of the 32 candidates -> exact top-16
__global__ __launch_bounds__(64) void k_rescore(const float* __restrict__ embF,
    const int* __restrict__ cand, u32 ka, u32 kb,
    int* __restrict__ soft_src, float* __restrict__ top_v){
  int i = blockIdx.x; int l = threadIdx.x;
  const float4* gF = (const float4*)embF;
  float4 b0 = gF[i*3+0], b1 = gF[i*3+1], b2 = gF[i*3+2];
  float sei = b2.z;
  float y = -1e30f; int jc = 0x7fffffff;
  if (l < 32){
    jc = cand[i*32+l];
    float4 a0 = gF[jc*3+0], a1 = gF[jc*3+1], a2 = gF[jc*3+2];
    float dot = a0.x*b0.x + a0.y*b0.y + a0.z*b0.z + a0.w*b0.w
              + a1.x*b1.x + a1.y*b1.y + a1.z*b1.z + a1.w*b1.w
              + a2.x*b2.x + a2.y*b2.y;
    float d2 = fmaxf(a2.z + sei - 2.0f*dot, 0.0f);
    float g = gumbel_g(rbits(ka, kb, (u32)i*8192u + (u32)jc));
    float z = 2.0f*(g - d2);
    y = z - a2.w;
  }
  for (int r=0; r<16; r++){
    float bv = y; int bj = jc;
    #pragma unroll
    for (int off=32; off>=1; off>>=1){
      float ov = __shfl_xor(bv, off);
      int   oj = __shfl_xor(bj, off);
      if (ov > bv || (ov == bv && oj < bj)){ bv = ov; bj = oj; }
    }
    if (l == 0){ soft_src[i*16+r] = bj; top_v[i*16+r] = __expf(bv); }
    if (jc == bj){ y = -1e30f; jc = 0x7fffffff; }
  }
}

// A = x@Wsrc, B = x@Wdst, V = x@Wlin  (8 rows per block)
__global__ __launch_bounds__(128) void k_xw(const float* __restrict__ x,
    const float* __restrict__ Wsrc, const float* __restrict__ Wdst, const float* __restrict__ Wlin,
    float* __restrict__ A, float* __restrict__ B, float* __restrict__ V){
  int g0 = blockIdx.x*8; int c = threadIdx.x;
  __shared__ float xs[8][64];
  for (int idx=c; idx<512; idx+=128) xs[idx>>6][idx&63] = x[(g0 + (idx>>6))*64 + (idx&63)];
  __syncthreads();
  float aA[8], aB[8], aV[8];
  #pragma unroll
  for (int g=0; g<8; g++){ aA[g]=0.0f; aB[g]=0.0f; aV[g]=0.0f; }
  for (int k=0; k<64; k++){
    float ws=Wsrc[k*128+c], wd=Wdst[k*128+c], wl=Wlin[k*128+c];
    #pragma unroll
    for (int g=0; g<8; g++){
      float xv = xs[g][k];
      aA[g] += xv*ws; aB[g] += xv*wd; aV[g] += xv*wl;
    }
  }
  #pragma unroll
  for (int g=0; g<8; g++){
    A[(g0+g)*128+c]=aA[g]; B[(g0+g)*128+c]=aB[g]; V[(g0+g)*128+c]=aV[g];
  }
}

// k-split GEMM, op_sel packed FMA: lane (kh=l>>5, q=l&31) does 8 edges x 4 cols
// over its 64-k half; activation quad consumed via op_sel broadcast (0 movs).
#define GEMMW2(WPTR)                                                        \
  {                                                                         \
    const v4f* __restrict__ Wp = ((const v4f*)(WPTR)) + khbase*32 + q;      \
    _Pragma("unroll")                                                       \
    for (int e=0; e<8; e++){ accA[e] = (v2f){0.f,0.f}; accB[e] = (v2f){0.f,0.f}; } \
    for (int kk=0; kk<16; kk++){                                            \
      v4f w0 = Wp[0], w1 = Wp[32], w2 = Wp[64], w3 = Wp[96];                \
      Wp += 128;                                                            \
      v2f w0a = __builtin_shufflevector(w0,w0,0,1), w0b = __builtin_shufflevector(w0,w0,2,3); \
      v2f w1a = __builtin_shufflevector(w1,w1,0,1), w1b = __builtin_shufflevector(w1,w1,2,3); \
      v2f w2a = __builtin_shufflevector(w2,w2,0,1), w2b = __builtin_shufflevector(w2,w2,2,3); \
      v2f w3a = __builtin_shufflevector(w3,w3,0,1), w3b = __builtin_shufflevector(w3,w3,2,3); \
      _Pragma("unroll")                                                     \
      for (int e=0; e<8; e++){                                              \
        v4f ev = *(const v4f*)(&ein[e0+e][khbase + 4*kk]);                  \
        v2f exy = __builtin_shufflevector(ev,ev,0,1);                       \
        v2f ezw = __builtin_shufflevector(ev,ev,2,3);                       \
        pk_fma_lo(accA[e], w0a, exy); pk_fma_lo(accB[e], w0b, exy);         \
        pk_fma_hi(accA[e], w1a, exy); pk_fma_hi(accB[e], w1b, exy);         \
        pk_fma_lo(accA[e], w2a, ezw); pk_fma_lo(accB[e], w2b, ezw);         \
        pk_fma_hi(accA[e], w3a, ezw); pk_fma_hi(accB[e], w3b, ezw);         \
      }                                                                     \
    }                                                                       \
  }

// cross-half reduction (lane ^ 32) + bias
#define KREDUCE(BPTR)                                                       \
  {                                                                         \
    float4 bb = ((const float4*)(BPTR))[q];                                 \
    _Pragma("unroll")                                                       \
    for (int e=0; e<8; e++){                                                \
      accA[e].x += __shfl_xor(accA[e].x, 32); accA[e].x += bb.x;            \
      accA[e].y += __shfl_xor(accA[e].y, 32); accA[e].y += bb.y;            \
      accB[e].x += __shfl_xor(accB[e].x, 32); accB[e].x += bb.z;            \
      accB[e].y += __shfl_xor(accB[e].y, 32); accB[e].y += bb.w;            \
    }                                                                       \
  }

// PointTransformerConv, per-target fused. 256 threads = 4 waves x 8 edges.
// NOTE: no min-waves clause -- (256,4) forced VGPR=64 + catastrophic spill (R2).
__global__ __launch_bounds__(256) void k_edge(const float* __restrict__ pos,
    const int* __restrict__ soft_src, const float* __restrict__ top_v, const int* __restrict__ knn_src,
    const float* __restrict__ A, const float* __restrict__ B, const float* __restrict__ V,
    const float* __restrict__ Wp1, const float* __restrict__ bp1,
    const float* __restrict__ Wp2, const float* __restrict__ bp2,
    const float* __restrict__ Wa1, const float* __restrict__ ba1,
    const float* __restrict__ Wa2, const float* __restrict__ ba2,
    float* __restrict__ h){
  int i = blockIdx.x; int t = threadIdx.x;
  int l = t & 63; int w = t >> 6; int e0 = w*8;
  int kh = l >> 5; int q = l & 31;
  const int khbase = kh*64;
  __shared__ float ein[32][128];
  __shared__ int   ssrc[32];
  __shared__ float sw[32];
  __shared__ float sdp[32][3];
  if (t < 32){
    int s; float wt;
    if (t < 16){ s = soft_src[i*16+t]; wt = top_v[i*16+t]; }
    else       { s = knn_src[i*16+(t-16)]; wt = 1.0f; }
    ssrc[t]=s; sw[t]=wt;
    sdp[t][0]=pos[i*3]-pos[s*3]; sdp[t][1]=pos[i*3+1]-pos[s*3+1]; sdp[t][2]=pos[i*3+2]-pos[s*3+2];
  }
  __syncthreads();
  v2f accA[8], accB[8], dlA[8], dlB[8];
  // stage 1: ph = relu(dpos @ Wp1 + bp1)
  {
    const float2* W1v = (const float2*)Wp1;
    float2 r0 = W1v[l], r1 = W1v[64+l], r2 = W1v[128+l];
    float2 bb = ((const float2*)bp1)[l];
    #pragma unroll
    for (int e=0; e<8; e++){
      float d0=sdp[e0+e][0], d1=sdp[e0+e][1], d2=sdp[e0+e][2];
      float2 v;
      v.x = fmaxf(d0*r0.x + d1*r1.x + d2*r2.x + bb.x, 0.0f);
      v.y = fmaxf(d0*r0.y + d1*r1.y + d2*r2.y + bb.y, 0.0f);
      *(float2*)(&ein[e0+e][2*l]) = v;
    }
  }
  // delta = ph @ Wp2 + bp2
  GEMMW2(Wp2); KREDUCE(bp2);
  #pragma unroll
  for (int e=0; e<8; e++){ dlA[e] = accA[e]; dlB[e] = accB[e]; }
  // q = B[i] - A[src] + delta   (kh==0 lanes write float4)
  if (kh == 0){
    float4 bi = ((const float4*)(&B[(size_t)i*128]))[q];
    #pragma unroll
    for (int e=0; e<8; e++){
      float4 av = ((const float4*)(&A[(size_t)ssrc[e0+e]*128]))[q];
      float4 v; v.x = bi.x - av.x + dlA[e].x; v.y = bi.y - av.y + dlA[e].y;
      v.z = bi.z - av.z + dlB[e].x; v.w = bi.w - av.w + dlB[e].y;
      *(float4*)(&ein[e0+e][4*q]) = v;
    }
  }
  // ah = relu(q @ Wa1 + ba1)
  GEMMW2(Wa1); KREDUCE(ba1);
  if (kh == 0){
    #pragma unroll
    for (int e=0; e<8; e++){
      float4 v; v.x=fmaxf(accA[e].x,0.f); v.y=fmaxf(accA[e].y,0.f);
      v.z=fmaxf(accB[e].x,0.f); v.w=fmaxf(accB[e].y,0.f);
      *(float4*)(&ein[e0+e][4*q]) = v;
    }
  }
  // logits = ah @ Wa2 + ba2
  GEMMW2(Wa2); KREDUCE(ba2);
  // cross-wave softmax over 32 edges; partials reuse dead ein rows:
  float* rbuf = &ein[0][0];
  v2f mA = accA[0], mB = accB[0];
  #pragma unroll
  for (int e=1; e<8; e++){
    mA.x=fmaxf(mA.x,accA[e].x); mA.y=fmaxf(mA.y,accA[e].y);
    mB.x=fmaxf(mB.x,accB[e].x); mB.y=fmaxf(mB.y,accB[e].y);
  }
  __syncthreads();                                   // all GEMM3 LDS reads done
  if (kh == 0){
    float4 mv; mv.x=mA.x; mv.y=mA.y; mv.z=mB.x; mv.w=mB.y;
    *(float4*)(&rbuf[w*128 + 4*q]) = mv;
  }
  __syncthreads();
  float4 M; M.x=-1e30f; M.y=-1e30f; M.z=-1e30f; M.w=-1e30f;
  #pragma unroll
  for (int ww=0; ww<4; ww++){
    float4 mm = *(const float4*)(&rbuf[ww*128 + 4*q]);
    M.x=fmaxf(M.x,mm.x); M.y=fmaxf(M.y,mm.y); M.z=fmaxf(M.z,mm.z); M.w=fmaxf(M.w,mm.w);
  }
  if (kh == 0){
    float4 s2; s2.x=0.f; s2.y=0.f; s2.z=0.f; s2.w=0.f;
    float4 h2; h2.x=0.f; h2.y=0.f; h2.z=0.f; h2.w=0.f;
    #pragma unroll
    for (int e=0; e<8; e++){
      int s = ssrc[e0+e]; float wt = sw[e0+e];
      float4 vv = ((const float4*)(&V[(size_t)s*128]))[q];
      float p;
      p = __expf(accA[e].x - M.x); s2.x += p; h2.x += p*(vv.x + dlA[e].x)*wt;
      p = __expf(accA[e].y - M.y); s2.y += p; h2.y += p*(vv.y + dlA[e].y)*wt;
      p = __expf(accB[e].x - M.z); s2.z += p; h2.z += p*(vv.z + dlB[e].x)*wt;
      p = __expf(accB[e].y - M.w); s2.w += p; h2.w += p*(vv.w + dlB[e].y)*wt;
    }
    *(float4*)(&rbuf[512  + w*128 + 4*q]) = s2;
    *(float4*)(&rbuf[1024 + w*128 + 4*q]) = h2;
  }
  __syncthreads();
  if (w == 0 && kh == 0){
    float4 S; S.x=0.f; S.y=0.f; S.z=0.f; S.w=0.f;
    float4 H; H.x=0.f; H.y=0.f; H.z=0.f; H.w=0.f;
    #pragma unroll
    for (int ww=0; ww<4; ww++){
      float4 sv = *(const float4*)(&rbuf[512  + ww*128 + 4*q]);
      float4 hv = *(const float4*)(&rbuf[1024 + ww*128 + 4*q]);
      S.x+=sv.x; S.y+=sv.y; S.z+=sv.z; S.w+=sv.w;
      H.x+=hv.x; H.y+=hv.y; H.z+=hv.z; H.w+=hv.w;
    }
    float4 o; o.x=H.x/(S.x+1e-16f); o.y=H.y/(S.y+1e-16f);
    o.z=H.z/(S.z+1e-16f); o.w=H.w/(S.w+1e-16f);
    *(float4*)(&h[(size_t)i*128 + 4*q]) = o;
  }
}

// hd = relu(h @ Wd + bd)
__global__ __launch_bounds__(128) void k_down(const float* __restrict__ h,
    const float* __restrict__ Wd, const float* __restrict__ bd, float* __restrict__ hd){
  int g0 = blockIdx.x*8; int c = threadIdx.x;
  __shared__ float hs[8][128];
  for (int idx=c; idx<1024; idx+=128) hs[idx>>7][idx&127] = h[(g0 + (idx>>7))*128 + (idx&127)];
  __syncthreads();
  float acc[8]; float b = bd[c];
  #pragma unroll
  for (int g=0; g<8; g++) acc[g] = b;
  for (int k=0; k<128; k+=4){
    float w0=Wd[(k+0)*128+c], w1=Wd[(k+1)*128+c], w2=Wd[(k+2)*128+c], w3=Wd[(k+3)*128+c];
    #pragma unroll
    for (int g=0; g<8; g++){
      const float4 ev = *(const float4*)(&hs[g][k]);
      acc[g] += ev.x*w0 + ev.y*w1 + ev.z*w2 + ev.w*w3;
    }
  }
  #pragma unroll
  for (int g=0; g<8; g++) hd[(g0+g)*128+c] = fmaxf(acc[g], 0.0f);
}

// y = max(hd[i], max over 32 neighbors hd[src])
__global__ __launch_bounds__(128) void k_pool(const float* __restrict__ hd,
    const int* __restrict__ soft_src, const int* __restrict__ knn_src, float* __restrict__ y){
  int i = blockIdx.x; int c = threadIdx.x;
  __shared__ int ss[32];
  if (c < 16) ss[c] = soft_src[i*16+c];
  else if (c < 32) ss[c] = knn_src[i*16+(c-16)];
  __syncthreads();
  float p = hd[i*128+c];
  for (int e=0; e<32; e++) p = fmaxf(p, hd[ss[e]*128+c]);
  y[i*128+c] = p;
}

// ranks = sorted-unique inverse (count of nonzero bins with smaller vid)
__global__ __launch_bounds__(256) void k_scan(const int* __restrict__ hist,
    int* __restrict__ rank, int* __restrict__ ucnt, int* __restrict__ Uo){
  __shared__ int part[256];
  int t = threadIdx.x;
  int base = t*32;
  int cnt = 0;
  for (int b=0; b<32; b++) cnt += (hist[base+b] > 0);
  part[t] = cnt;
  __syncthreads();
  if (t == 0){
    int run = 0;
    for (int q=0; q<256; q++){ int v = part[q]; part[q] = run; run += v; }
    Uo[0] = run;
  }
  __syncthreads();
  int run = part[t];
  for (int b=0; b<32; b++){
    int bin = base + b;
    rank[bin] = run;
    int hv = hist[bin];
    if (hv > 0){ ucnt[run] = hv; run++; }
  }
}

__global__ __launch_bounds__(128) void k_agg(const float* __restrict__ y, const float* __restrict__ pos,
    const int* __restrict__ vid, const int* __restrict__ rank,
    float* __restrict__ accx, float* __restrict__ accp){
  int n = blockIdx.x; int c = threadIdx.x;
  int r = rank[vid[n]];
  atomicAdd(&accx[r*128+c], y[n*128+c]);
  if (c < 3) atomicAdd(&accp[r*3+c], pos[n*3+c]);
}

__global__ __launch_bounds__(128) void k_final(const float* __restrict__ accx, const float* __restrict__ accp,
    const int* __restrict__ ucnt, const int* __restrict__ Uo, float* __restrict__ out){
  int r = blockIdx.x; int c = threadIdx.x;
  int u = Uo[0];
  float cnt = (r < u) ? (float)ucnt[r] : 0.0f;
  float den = fmaxf(cnt, 1.0f);
  out[r*128+c] = (r < u) ? accx[r*128+c]/den : 0.0f;
  if (c < 3) out[(size_t)NN*128 + r*3 + c] = (r < u) ? accp[r*3+c]/den : 0.0f;
  if (c == 0) out[(size_t)NN*128 + (size_t)NN*3 + r] = cnt;
}

// ---------------- launcher ----------------
extern "C" void kernel_launch(void* const* d_in, const int* in_sizes, int n_in,
                              void* d_out, int out_size, void* d_ws, size_t ws_size,
                              hipStream_t stream){
  (void)in_sizes; (void)n_in; (void)out_size;
  const float* x    = (const float*)d_in[0];
  const float* pos  = (const float*)d_in[1];
  const float* Wg1  = (const float*)d_in[2];
  const float* bg1  = (const float*)d_in[3];
  const float* Wg2  = (const float*)d_in[4];
  const float* bg2  = (const float*)d_in[5];
  const float* Wlin = (const float*)d_in[6];
  const float* Wsrc = (const float*)d_in[7];
  const float* Wdst = (const float*)d_in[8];
  const float* Wp1  = (const float*)d_in[9];
  const float* bp1  = (const float*)d_in[10];
  const float* Wp2  = (const float*)d_in[11];
  const float* bp2  = (const float*)d_in[12];
  const float* Wa1  = (const float*)d_in[13];
  const float* ba1  = (const float*)d_in[14];
  const float* Wa2  = (const float*)d_in[15];
  const float* ba2  = (const float*)d_in[16];
  const float* Wd   = (const float*)d_in[17];
  const float* bd   = (const float*)d_in[18];

  char* ws = (char*)d_ws;
  float* embF   = (float*)(ws + OFF_EMBF);
  float* sp     = (float*)(ws + OFF_SP);
  float* psum   = (float*)(ws + OFF_PSUM);
  int*   ssrc   = (int*)  (ws + OFF_SSRC);
  float* topv   = (float*)(ws + OFF_TOPV);
  int*   ksrc   = (int*)  (ws + OFF_KSRC);
  int*   hist   = (int*)  (ws + OFF_HIST);
  int*   rank   = (int*)  (ws + OFF_RANK);
  int*   ucnt   = (int*)  (ws + OFF_UCNT);
  int*   vid    = (int*)  (ws + OFF_VID);
  int*   mi     = (int*)  (ws + OFF_META);
  int*   mx     = (int*)  (ws + OFF_META + 16);
  int*   Uo     = (int*)  (ws + OFF_META + 32);
  int*   qKi    = (int*)  (ws + OFF_QKI);
  int*   cand   = (int*)  (ws + OFF_CAND);
  float* A      = (float*)(ws + OFF_A);
  float* B      = (float*)(ws + OFF_B);
  float* V      = (float*)(ws + OFF_V);
  float* h      = (float*)(ws + OFF_H);
  float* hd     = (float*)(ws + OFF_HD);
  float* y      = (float*)(ws + OFF_Y);
  float* accx   = (float*)(ws + OFF_ACCX);
  float* accp   = (float*)(ws + OFF_ACCP);
  unsigned short* zq = (unsigned short*)(ws + OFF_ZQ);

  const bool use_q = (ws_size >= OFF_ZQ + ZQ_BYTES);   // constant per run -> deterministic

  // rk = jax.random.split(jax.random.key(42), 2)  -- host threefry (foldlike)
  u32 rk0a, rk0b, rk1a, rk1b;
  tf2x32(0u, 42u, 0u, 0u, rk0a, rk0b);
  tf2x32(0u, 42u, 0u, 1u, rk1a, rk1b);

  hipMemsetAsync(hist, 0, 8192*4, stream);
  k_init0<<<1, 64, 0, stream>>>(mi, mx);
  k_min<<<32, 256, 0, stream>>>(pos, mi);
  k_ext<<<32, 256, 0, stream>>>(pos, mi, mx);
  k_vid<<<32, 256, 0, stream>>>(pos, mi, mx, vid, hist, sp);
  k_emb<<<8192, 64, 0, stream>>>(x, Wg1, bg1, Wg2, bg2, rk0a, rk0b, embF);
  k_knn<<<8192, 64, 0, stream>>>(pos, sp, ksrc);
  if (use_q){
    k_colstats<true><<<dim3(32,32), 256, 0, stream>>>(embF, rk1a, rk1b, psum, zq);
    k_colfin<<<32, 256, 0, stream>>>(psum, embF, qKi);
    k_qtopk<<<8192, 64, 0, stream>>>(zq, qKi, cand);
    k_rescore<<<8192, 64, 0, stream>>>(embF, cand, rk1a, rk1b, ssrc, topv);
  } else {
    k_colstats<false><<<dim3(32,32), 256, 0, stream>>>(embF, rk1a, rk1b, psum, nullptr);
    k_colfin<<<32, 256, 0, stream>>>(psum, embF, qKi);
    k_rowtopk<<<8192, 64, 0, stream>>>(embF, rk1a, rk1b, ssrc, topv);
  }
  // Overlap region is free of z-cache readers from here on.
  k_xw<<<1024, 128, 0, stream>>>(x, Wsrc, Wdst, Wlin, A, B, V);
  k_edge<<<8192, 256, 0, stream>>>(pos, ssrc, topv, ksrc, A, B, V,
                                   Wp1, bp1, Wp2, bp2, Wa1, ba1, Wa2, ba2, h);
  k_down<<<1024, 128, 0, stream>>>(h, Wd, bd, hd);
  k_pool<<<8192, 128, 0, stream>>>(hd, ssrc, ksrc, y);
  hipMemsetAsync(accx, 0, (size_t)8192*128*4, stream);
  hipMemsetAsync(accp, 0, (size_t)8192*3*4, stream);
  k_scan<<<1, 256, 0, stream>>>(hist, rank, ucnt, Uo);
  k_agg<<<8192, 128, 0, stream>>>(y, pos, vid, rank, accx, accp);
  k_final<<<8192, 128, 0, stream>>>(accx, accp, ucnt, Uo, (float*)d_out);
}

// Round 10
// 925.530 us; speedup vs baseline: 1.6570x; 1.2371x over previous
//
#include <hip/hip_runtime.h>
#include <stdint.h>

// ---------------------------------------------------------------------------
// Enc_block: KNN graph + gumbel-softmax soft edges + PointTransformerConv +
// down + neighbor max-pool + GridSampling.  N=8192, Cin=64, Cout=128, K=16.
// ---------------------------------------------------------------------------

typedef unsigned int u32;
typedef float v2f __attribute__((ext_vector_type(2)));
typedef float v4f __attribute__((ext_vector_type(4)));

#define NN 8192
#define EPS20 1e-20f
#define QSCALE 489.0671f   // 65535/134; z in [-99.8, 33.3] -> q = (z+100)*QSCALE

// packed fp32 FMA with op_sel broadcast of src1 (no splat movs)
__device__ static inline void pk_fma_lo(v2f& acc, v2f w, v2f e){
  asm("v_pk_fma_f32 %0, %1, %2, %0 op_sel:[0,0,0] op_sel_hi:[1,0,1]"
      : "+v"(acc) : "v"(w), "v"(e));
}
__device__ static inline void pk_fma_hi(v2f& acc, v2f w, v2f e){
  asm("v_pk_fma_f32 %0, %1, %2, %0 op_sel:[0,1,0] op_sel_hi:[1,1,1]"
      : "+v"(acc) : "v"(w), "v"(e));
}

// ---------------- threefry2x32 (JAX key schedule) ----------------
__host__ __device__ static inline u32 rotl32(u32 v, int r){ return (v<<r)|(v>>(32-r)); }

__host__ __device__ static inline void tf2x32(u32 k0, u32 k1, u32 c0, u32 c1, u32& o0, u32& o1){
  u32 ks2 = k0 ^ k1 ^ 0x1BD11BDAu;
  u32 x0 = c0 + k0;
  u32 x1 = c1 + k1;
#define TFR(r) x0 += x1; x1 = rotl32(x1,(r)); x1 ^= x0;
  TFR(13) TFR(15) TFR(26) TFR(6)
  x0 += k1;  x1 += ks2 + 1u;
  TFR(17) TFR(29) TFR(16) TFR(24)
  x0 += ks2; x1 += k0 + 2u;
  TFR(13) TFR(15) TFR(26) TFR(6)
  x0 += k0;  x1 += k1 + 3u;
  TFR(17) TFR(29) TFR(16) TFR(24)
  x0 += k1;  x1 += ks2 + 4u;
  TFR(13) TFR(15) TFR(26) TFR(6)
  x0 += ks2; x1 += k0 + 5u;
#undef TFR
  o0 = x0; o1 = x1;
}

__device__ static inline u32 rbits(u32 k0, u32 k1, u32 idx){
  u32 o0,o1; tf2x32(k0,k1, 0u, idx, o0,o1);   // partitionable: counter (0, idx)
  return o0 ^ o1;                              // 32-bit fold
}

__device__ static inline float u01(u32 b){
  return __uint_as_float((b>>9) | 0x3f800000u) - 1.0f;   // [0,1), JAX formula
}

// z = 2*(log(exp(-d2)+eps) + g)  ==  2*(g - d2) for all entries that can reach
// top-16 or contribute to the colsum (eps correction <=1e-4 there).
__device__ static inline float gumbel_g(u32 ub){
  float u = u01(ub);
  float w = -__logf(u + EPS20);
  return -__logf(w + EPS20);
}

// ---------------- workspace layout ----------------
static constexpr size_t OFF_EMBF = 0;                              // [8192][12] f32: e[10], se, K
static constexpr size_t OFF_SP   = OFF_EMBF + (size_t)8192*12*4;   // (unused, kept for layout)
static constexpr size_t OFF_PSUM = OFF_SP   + (size_t)8192*4;      // [32][8192]
static constexpr size_t OFF_SSRC = OFF_PSUM + (size_t)32*8192*4;   // int [8192][16]
static constexpr size_t OFF_TOPV = OFF_SSRC + (size_t)8192*16*4;
static constexpr size_t OFF_KSRC = OFF_TOPV + (size_t)8192*16*4;   // int [8192][16]
static constexpr size_t OFF_HIST = OFF_KSRC + (size_t)8192*16*4;   // int [8192]
static constexpr size_t OFF_RANK = OFF_HIST + (size_t)8192*4;
static constexpr size_t OFF_UCNT = OFF_RANK + (size_t)8192*4;
static constexpr size_t OFF_VID  = OFF_UCNT + (size_t)8192*4;
static constexpr size_t OFF_META = OFF_VID  + (size_t)8192*4;      // mi i[3] @0, mx i[3] @16B, U i @32B
static constexpr size_t OFF_QKI  = OFF_META + 64;                  // int [8192] quantized K
static constexpr size_t OFF_CAND = OFF_QKI  + (size_t)8192*4;      // int [8192][32]
static constexpr size_t OFF_POS4 = OFF_CAND + (size_t)8192*32*4;   // float4 [8192] {x,y,z,|p|^2}
static constexpr size_t OFF_BIG  = (OFF_POS4 + (size_t)8192*16 + 255) & ~(size_t)255;
// Overlap region: u16 z-cache [8192][8192] lives here during colstats..rescore;
// A/B/V/H/HD/Y/ACCX/ACCP live here afterwards (k_xw launched after rescore).
static constexpr size_t OFF_A    = OFF_BIG;
static constexpr size_t OFF_B    = OFF_A    + (size_t)8192*128*4;
static constexpr size_t OFF_V    = OFF_B    + (size_t)8192*128*4;
static constexpr size_t OFF_H    = OFF_V    + (size_t)8192*128*4;
static constexpr size_t OFF_HD   = OFF_H    + (size_t)8192*128*4;
static constexpr size_t OFF_Y    = OFF_HD   + (size_t)8192*128*4;
static constexpr size_t OFF_ACCX = OFF_Y    + (size_t)8192*128*4;
static constexpr size_t OFF_ACCP = OFF_ACCX + (size_t)8192*128*4;
static constexpr size_t OFF_ZQ   = OFF_BIG;
static constexpr size_t ZQ_BYTES = (size_t)NN*NN*2;

// ---------------- kernels ----------------

__global__ void k_init0(int* __restrict__ mi, int* __restrict__ mx){
  int t = threadIdx.x;
  if (t < 3){ mi[t] = 0x7f7fffff; mx[t] = 0; }
}

// per-dim min of pos (positive floats: int-bit compare is order-preserving)
__global__ __launch_bounds__(256) void k_min(const float* __restrict__ pos, int* __restrict__ mi){
  __shared__ int red[768];
  int t = threadIdx.x;
  int n = blockIdx.x*256 + t;
  red[t]     = __float_as_int(pos[n*3+0]);
  red[256+t] = __float_as_int(pos[n*3+1]);
  red[512+t] = __float_as_int(pos[n*3+2]);
  __syncthreads();
  for (int s=128; s>0; s>>=1){
    if (t < s){
      red[t]     = min(red[t],     red[t+s]);
      red[256+t] = min(red[256+t], red[256+t+s]);
      red[512+t] = min(red[512+t], red[512+t+s]);
    }
    __syncthreads();
  }
  if (t == 0){ atomicMin(&mi[0], red[0]); atomicMin(&mi[1], red[256]); atomicMin(&mi[2], red[512]); }
}

// per-dim max voxel index
__global__ __launch_bounds__(256) void k_ext(const float* __restrict__ pos, const int* __restrict__ mi,
                                             int* __restrict__ mx){
  __shared__ int red[768];
  int t = threadIdx.x;
  int n = blockIdx.x*256 + t;
  float p0 = __int_as_float(mi[0]), p1 = __int_as_float(mi[1]), p2 = __int_as_float(mi[2]);
  red[t]     = (int)floorf((pos[n*3+0]-p0)*2.0f);   // /0.5 == *2 exactly
  red[256+t] = (int)floorf((pos[n*3+1]-p1)*2.0f);
  red[512+t] = (int)floorf((pos[n*3+2]-p2)*2.0f);
  __syncthreads();
  for (int s=128; s>0; s>>=1){
    if (t < s){
      red[t]     = max(red[t],     red[t+s]);
      red[256+t] = max(red[256+t], red[256+t+s]);
      red[512+t] = max(red[512+t], red[512+t+s]);
    }
    __syncthreads();
  }
  if (t == 0){ atomicMax(&mx[0], red[0]); atomicMax(&mx[1], red[256]); atomicMax(&mx[2], red[512]); }
}

// voxel id + histogram + SoA pos4 = {x,y,z,|p|^2}
__global__ __launch_bounds__(256) void k_vid(const float* __restrict__ pos,
                                             const int* __restrict__ mi, const int* __restrict__ mx,
                                             int* __restrict__ vid, int* __restrict__ hist,
                                             float4* __restrict__ pos4){
  int n = blockIdx.x*256 + threadIdx.x;
  float p0=pos[n*3], p1=pos[n*3+1], p2=pos[n*3+2];
  float4 p4; p4.x=p0; p4.y=p1; p4.z=p2; p4.w = p0*p0 + p1*p1 + p2*p2;
  pos4[n] = p4;
  float q0 = __int_as_float(mi[0]), q1 = __int_as_float(mi[1]), q2 = __int_as_float(mi[2]);
  int v0 = (int)floorf((p0-q0)*2.0f);
  int v1 = (int)floorf((p1-q1)*2.0f);
  int v2 = (int)floorf((p2-q2)*2.0f);
  int nv1 = mx[1]+1, nv2 = mx[2]+1;
  int id = (v0*nv1 + v1)*nv2 + v2;
  vid[n] = id;
  atomicAdd(&hist[id], 1);
}

// embF[i] = { relu(x@Wg1+bg1)@Wg2+bg2 + u*0.001  (10), |emb|^2, 0 }
__global__ __launch_bounds__(64) void k_emb(const float* __restrict__ x,
    const float* __restrict__ Wg1, const float* __restrict__ bg1,
    const float* __restrict__ Wg2, const float* __restrict__ bg2,
    u32 ka, u32 kb, float* __restrict__ embF){
  int i = blockIdx.x; int t = threadIdx.x;
  __shared__ float xs[64], hs[64], esq[10];
  xs[t] = x[i*64+t];
  __syncthreads();
  float a = bg1[t];
  for (int k=0; k<64; k++) a += xs[k]*Wg1[k*64+t];
  hs[t] = fmaxf(a, 0.0f);
  __syncthreads();
  if (t < 10){
    float e = bg2[t];
    for (int k=0; k<64; k++) e += hs[k]*Wg2[k*10+t];
    e += u01(rbits(ka, kb, (u32)(i*10+t))) * 0.001f;
    embF[i*12+t] = e;
    esq[t] = e*e;
  }
  __syncthreads();
  if (t == 0){
    float ssum = 0.0f;
    #pragma unroll
    for (int d=0; d<10; d++) ssum += esq[d];
    embF[i*12+10] = ssum;
    embF[i*12+11] = 0.0f;
  }
}

// KNN: top-16 smallest d2 per row (diag excluded), ties -> lower index.
// SoA float4 loads; per-lane top-8 (P[lane holds >8 of global top-16] ~ 1e-11/row);
// full 6-round shfl butterfly merge (known-good).
__global__ __launch_bounds__(64) void k_knn(const float4* __restrict__ pos4,
                                            int* __restrict__ knn_src){
  int i = blockIdx.x; int l = threadIdx.x;
  float4 pi = pos4[i];
  float lv[8]; int lj[8];
  #pragma unroll
  for (int s=0; s<8; s++){ lv[s]=1e30f; lj[s]=0x7fffffff; }
  for (int tt=0; tt<128; tt++){
    int j = l + 64*tt;
    float4 pj = pos4[j];
    float d = pi.w + pj.w - 2.0f*(pi.x*pj.x + pi.y*pj.y + pi.z*pj.z);
    d = fmaxf(d, 0.0f);
    if (j != i && d < lv[7]){
      lv[7]=d; lj[7]=j;
      #pragma unroll
      for (int s=7; s>0; s--){
        if (lv[s] < lv[s-1]){ float tv=lv[s]; lv[s]=lv[s-1]; lv[s-1]=tv; int tj=lj[s]; lj[s]=lj[s-1]; lj[s-1]=tj; }
      }
    }
  }
  for (int r=0; r<16; r++){
    float bv = lv[0]; int bj = lj[0];
    #pragma unroll
    for (int off=32; off>=1; off>>=1){
      float ov = __shfl_xor(bv, off);
      int   oj = __shfl_xor(bj, off);
      if (ov < bv || (ov == bv && oj < bj)){ bv = ov; bj = oj; }
    }
    if (l == 0) knn_src[i*16+r] = bj;
    if (lj[0] == bj){
      #pragma unroll
      for (int s=0; s<7; s++){ lv[s]=lv[s+1]; lj[s]=lj[s+1]; }
      lv[7]=1e30f; lj[7]=0x7fffffff;
    }
  }
}

// z = 2*(g - d2).  Hard bound: z <= 2*g_max <= 33.3, so sum(exp(z-40)) never
// overflows -> no max pass needed.  Stores quantized z (u16) into the cache.
template<bool STZ>
__global__ __launch_bounds__(256) void k_colstats(const float* __restrict__ embF,
                                                  u32 ka, u32 kb, float* __restrict__ psum,
                                                  unsigned short* __restrict__ zq){
  __shared__ float4 sE4[768];                 // 256 rows x 12 floats
  int t = threadIdx.x;
  int j = blockIdx.x*256 + t;
  int i0 = blockIdx.y*256;
  const float4* gF = (const float4*)embF;
  #pragma unroll
  for (int q=0; q<3; q++) sE4[t + 256*q] = gF[(size_t)i0*3 + t + 256*q];
  __syncthreads();
  float4 b0 = gF[j*3+0], b1 = gF[j*3+1], b2 = gF[j*3+2];
  float sej = b2.z;
  float s = 0.0f;
  unsigned short* zp = STZ ? (zq + ((size_t)i0<<13) + j) : nullptr;
  for (int r=0; r<256; r++){
    float4 a0 = sE4[r*3+0], a1 = sE4[r*3+1], a2 = sE4[r*3+2];
    float dot = a0.x*b0.x + a0.y*b0.y + a0.z*b0.z + a0.w*b0.w
              + a1.x*b1.x + a1.y*b1.y + a1.z*b1.z + a1.w*b1.w
              + a2.x*b2.x + a2.y*b2.y;
    float d2 = fmaxf(a2.z + sej - 2.0f*dot, 0.0f);
    float g = gumbel_g(rbits(ka, kb, (u32)(i0+r)*8192u + (u32)j));
    float z = 2.0f*(g - d2);
    s += __expf(z - 40.0f);
    if (STZ){
      float qf = (z + 100.0f)*QSCALE + 0.5f;
      qf = fminf(fmaxf(qf, 0.0f), 65535.0f);
      *zp = (unsigned short)qf;
      zp += NN;
    }
  }
  psum[blockIdx.y*NN + j] = s;
}

// K_j = 40 + log(sum_chunks psum); write f32 K into embF[j][11] and quantized K
__global__ __launch_bounds__(256) void k_colfin(const float* __restrict__ psum, float* __restrict__ embF,
                                                int* __restrict__ qKi){
  int j = blockIdx.x*256 + threadIdx.x;
  float S = 0.0f;
  for (int c=0; c<32; c++) S += psum[c*NN + j];
  float K = 40.0f + __logf(S);
  embF[j*12+11] = K;
  qKi[j] = (int)((K + 100.0f)*QSCALE + 0.5f);   // same transform as z
}

// FALLBACK: per-row top-16 of y = z - K_j by full recompute
__global__ __launch_bounds__(64) void k_rowtopk(const float* __restrict__ embF,
    u32 ka, u32 kb, int* __restrict__ soft_src, float* __restrict__ top_v){
  int i = blockIdx.x; int l = threadIdx.x;
  const float4* gF = (const float4*)embF;
  float4 b0 = gF[i*3+0], b1 = gF[i*3+1], b2 = gF[i*3+2];
  float sei = b2.z;
  float lv[16]; int lj[16];
  #pragma unroll
  for (int s=0; s<16; s++){ lv[s]=-1e30f; lj[s]=0x7fffffff; }
  for (int tt=0; tt<128; tt++){
    int j = l + 64*tt;
    float4 a0 = gF[j*3+0], a1 = gF[j*3+1], a2 = gF[j*3+2];
    float dot = a0.x*b0.x + a0.y*b0.y + a0.z*b0.z + a0.w*b0.w
              + a1.x*b1.x + a1.y*b1.y + a1.z*b1.z + a1.w*b1.w
              + a2.x*b2.x + a2.y*b2.y;
    float d2 = fmaxf(a2.z + sei - 2.0f*dot, 0.0f);
    float g = gumbel_g(rbits(ka, kb, (u32)i*8192u + (u32)j));
    float z = 2.0f*(g - d2);
    float y = z - a2.w;
    if (y > lv[15]){
      lv[15]=y; lj[15]=j;
      #pragma unroll
      for (int s=15; s>0; s--){
        if (lv[s] > lv[s-1]){ float tv=lv[s]; lv[s]=lv[s-1]; lv[s-1]=tv; int tj=lj[s]; lj[s]=lj[s-1]; lj[s-1]=tj; }
      }
    }
  }
  for (int r=0; r<16; r++){
    float bv = lv[0]; int bj = lj[0];
    #pragma unroll
    for (int off=32; off>=1; off>>=1){
      float ov = __shfl_xor(bv, off);
      int   oj = __shfl_xor(bj, off);
      if (ov > bv || (ov == bv && oj < bj)){ bv = ov; bj = oj; }
    }
    if (l == 0){ soft_src[i*16+r] = bj; top_v[i*16+r] = __expf(bv); }
    if (lj[0] == bj){
      #pragma unroll
      for (int s=0; s<15; s++){ lv[s]=lv[s+1]; lj[s]=lj[s+1]; }
      lv[15]=-1e30f; lj[15]=0x7fffffff;
    }
  }
}

// cached path A: per-row top-32 candidates by integer qy = q_z - q_K.
// per-lane top-8 + full shfl butterfly merge (known-good).
__global__ __launch_bounds__(64) void k_qtopk(const unsigned short* __restrict__ zq,
    const int* __restrict__ qKi, int* __restrict__ cand){
  int i = blockIdx.x; int l = threadIdx.x;
  const uint4* zrow = (const uint4*)(zq + ((size_t)i<<13));   // 8 u16 per uint4
  int lv[8]; int lj[8];
  #pragma unroll
  for (int s=0; s<8; s++){ lv[s]=-0x40000000; lj[s]=0x7fffffff; }
  for (int tt=0; tt<16; tt++){
    int blk = l + 64*tt;
    uint4 zv = zrow[blk];
    int jb = blk*8;
    const int4* qk4 = (const int4*)(qKi + jb);
    int4 ka4 = qk4[0], kb4 = qk4[1];
    u32 wv[4] = {zv.x, zv.y, zv.z, zv.w};
    int qk[8] = {ka4.x,ka4.y,ka4.z,ka4.w, kb4.x,kb4.y,kb4.z,kb4.w};
    #pragma unroll
    for (int c=0; c<8; c++){
      int qz = (int)((wv[c>>1] >> ((c&1)*16)) & 0xffffu);
      int qy = qz - qk[c];
      if (qy > lv[7]){
        lv[7]=qy; lj[7]=jb+c;
        #pragma unroll
        for (int s=7; s>0; s--){
          if (lv[s] > lv[s-1]){ int tv=lv[s]; lv[s]=lv[s-1]; lv[s-1]=tv; int tj=lj[s]; lj[s]=lj[s-1]; lj[s-1]=tj; }
        }
      }
    }
  }
  for (int r=0; r<32; r++){
    int bv = lv[0]; int bj = lj[0];
    #pragma unroll
    for (int off=32; off>=1; off>>=1){
      int ov = __shfl_xor(bv, off);
      int oj = __shfl_xor(bj, off);
      if (ov > bv || (ov == bv && oj < bj)){ bv = ov; bj = oj; }
    }
    if (l == 0) cand[i*32+r] = bj;
    if (lj[0] == bj){
      #pragma unroll
      for (int s=0; s<7; s++){ lv[s]=lv[s+1]; lj[s]=lj[s+1]; }
      lv[7]=-0x40000000; lj[7]=0x7fffffff;
    }
  }
}

// cached path B: exact rescore of the 32 candidates -> exact top-16
__global__ __launch_bounds__(64) void k_rescore(const float* __restrict__ embF,
    const int* __restrict__ cand, u32 ka, u32 kb,
    int* __restrict__ soft_src, float* __restrict__ top_v){
  int i = blockIdx.x; int l = threadIdx.x;
  const float4* gF = (const float4*)embF;
  float4 b0 = gF[i*3+0], b1 = gF[i*3+1], b2 = gF[i*3+2];
  float sei = b2.z;
  float y = -1e30f; int jc = 0x7fffffff;
  if (l < 32){
    jc = cand[i*32+l];
    float4 a0 = gF[jc*3+0], a1 = gF[jc*3+1], a2 = gF[jc*3+2];
    float dot = a0.x*b0.x + a0.y*b0.y + a0.z*b0.z + a0.w*b0.w
              + a1.x*b1.x + a1.y*b1.y + a1.z*b1.z + a1.w*b1.w
              + a2.x*b2.x + a2.y*b2.y;
    float d2 = fmaxf(a2.z + sei - 2.0f*dot, 0.0f);
    float g = gumbel_g(rbits(ka, kb, (u32)i*8192u + (u32)jc));
    float z = 2.0f*(g - d2);
    y = z - a2.w;
  }
  for (int r=0; r<16; r++){
    float bv = y; int bj = jc;
    #pragma unroll
    for (int off=32; off>=1; off>>=1){
      float ov = __shfl_xor(bv, off);
      int   oj = __shfl_xor(bj, off);
      if (ov > bv || (ov == bv && oj < bj)){ bv = ov; bj = oj; }
    }
    if (l == 0){ soft_src[i*16+r] = bj; top_v[i*16+r] = __expf(bv); }
    if (jc == bj){ y = -1e30f; jc = 0x7fffffff; }
  }
}

// A = x@Wsrc, B = x@Wdst, V = x@Wlin  (8 rows per block)
__global__ __launch_bounds__(128) void k_xw(const float* __restrict__ x,
    const float* __restrict__ Wsrc, const float* __restrict__ Wdst, const float* __restrict__ Wlin,
    float* __restrict__ A, float* __restrict__ B, float* __restrict__ V){
  int g0 = blockIdx.x*8; int c = threadIdx.x;
  __shared__ float xs[8][64];
  for (int idx=c; idx<512; idx+=128) xs[idx>>6][idx&63] = x[(g0 + (idx>>6))*64 + (idx&63)];
  __syncthreads();
  float aA[8], aB[8], aV[8];
  #pragma unroll
  for (int g=0; g<8; g++){ aA[g]=0.0f; aB[g]=0.0f; aV[g]=0.0f; }
  for (int k=0; k<64; k++){
    float ws=Wsrc[k*128+c], wd=Wdst[k*128+c], wl=Wlin[k*128+c];
    #pragma unroll
    for (int g=0; g<8; g++){
      float xv = xs[g][k];
      aA[g] += xv*ws; aB[g] += xv*wd; aV[g] += xv*wl;
    }
  }
  #pragma unroll
  for (int g=0; g<8; g++){
    A[(g0+g)*128+c]=aA[g]; B[(g0+g)*128+c]=aB[g]; V[(g0+g)*128+c]=aV[g];
  }
}

// k-split GEMM, op_sel packed FMA: lane (kh=l>>5, q=l&31) does 8 edges x 4 cols
// over its 64-k half; activation quad consumed via op_sel broadcast (0 movs).
#define GEMMW2(WPTR)                                                        \
  {                                                                         \
    const v4f* __restrict__ Wp = ((const v4f*)(WPTR)) + khbase*32 + q;      \
    _Pragma("unroll")                                                       \
    for (int e=0; e<8; e++){ accA[e] = (v2f){0.f,0.f}; accB[e] = (v2f){0.f,0.f}; } \
    for (int kk=0; kk<16; kk++){                                            \
      v4f w0 = Wp[0], w1 = Wp[32], w2 = Wp[64], w3 = Wp[96];                \
      Wp += 128;                                                            \
      v2f w0a = __builtin_shufflevector(w0,w0,0,1), w0b = __builtin_shufflevector(w0,w0,2,3); \
      v2f w1a = __builtin_shufflevector(w1,w1,0,1), w1b = __builtin_shufflevector(w1,w1,2,3); \
      v2f w2a = __builtin_shufflevector(w2,w2,0,1), w2b = __builtin_shufflevector(w2,w2,2,3); \
      v2f w3a = __builtin_shufflevector(w3,w3,0,1), w3b = __builtin_shufflevector(w3,w3,2,3); \
      _Pragma("unroll")                                                     \
      for (int e=0; e<8; e++){                                              \
        v4f ev = *(const v4f*)(&ein[e0+e][khbase + 4*kk]);                  \
        v2f exy = __builtin_shufflevector(ev,ev,0,1);                       \
        v2f ezw = __builtin_shufflevector(ev,ev,2,3);                       \
        pk_fma_lo(accA[e], w0a, exy); pk_fma_lo(accB[e], w0b, exy);         \
        pk_fma_hi(accA[e], w1a, exy); pk_fma_hi(accB[e], w1b, exy);         \
        pk_fma_lo(accA[e], w2a, ezw); pk_fma_lo(accB[e], w2b, ezw);         \
        pk_fma_hi(accA[e], w3a, ezw); pk_fma_hi(accB[e], w3b, ezw);         \
      }                                                                     \
    }                                                                       \
  }

// cross-half reduction (lane ^ 32) + bias (shfl form -- known good)
#define KREDUCE(BPTR)                                                       \
  {                                                                         \
    float4 bb = ((const float4*)(BPTR))[q];                                 \
    _Pragma("unroll")                                                       \
    for (int e=0; e<8; e++){                                                \
      accA[e].x += __shfl_xor(accA[e].x, 32); accA[e].x += bb.x;            \
      accA[e].y += __shfl_xor(accA[e].y, 32); accA[e].y += bb.y;            \
      accB[e].x += __shfl_xor(accB[e].x, 32); accB[e].x += bb.z;            \
      accB[e].y += __shfl_xor(accB[e].y, 32); accB[e].y += bb.w;            \
    }                                                                       \
  }

// PointTransformerConv, per-target fused. 256 threads = 4 waves x 8 edges.
// NOTE: no min-waves clause -- (256,4) forced VGPR=64 + catastrophic spill (R2).
__global__ __launch_bounds__(256) void k_edge(const float* __restrict__ pos,
    const int* __restrict__ soft_src, const float* __restrict__ top_v, const int* __restrict__ knn_src,
    const float* __restrict__ A, const float* __restrict__ B, const float* __restrict__ V,
    const float* __restrict__ Wp1, const float* __restrict__ bp1,
    const float* __restrict__ Wp2, const float* __restrict__ bp2,
    const float* __restrict__ Wa1, const float* __restrict__ ba1,
    const float* __restrict__ Wa2, const float* __restrict__ ba2,
    float* __restrict__ h){
  int i = blockIdx.x; int t = threadIdx.x;
  int l = t & 63; int w = t >> 6; int e0 = w*8;
  int kh = l >> 5; int q = l & 31;
  const int khbase = kh*64;
  __shared__ float ein[32][128];
  __shared__ int   ssrc[32];
  __shared__ float sw[32];
  __shared__ float sdp[32][3];
  if (t < 32){
    int s; float wt;
    if (t < 16){ s = soft_src[i*16+t]; wt = top_v[i*16+t]; }
    else       { s = knn_src[i*16+(t-16)]; wt = 1.0f; }
    ssrc[t]=s; sw[t]=wt;
    sdp[t][0]=pos[i*3]-pos[s*3]; sdp[t][1]=pos[i*3+1]-pos[s*3+1]; sdp[t][2]=pos[i*3+2]-pos[s*3+2];
  }
  __syncthreads();
  v2f accA[8], accB[8], dlA[8], dlB[8];
  // stage 1: ph = relu(dpos @ Wp1 + bp1)
  {
    const float2* W1v = (const float2*)Wp1;
    float2 r0 = W1v[l], r1 = W1v[64+l], r2 = W1v[128+l];
    float2 bb = ((const float2*)bp1)[l];
    #pragma unroll
    for (int e=0; e<8; e++){
      float d0=sdp[e0+e][0], d1=sdp[e0+e][1], d2=sdp[e0+e][2];
      float2 v;
      v.x = fmaxf(d0*r0.x + d1*r1.x + d2*r2.x + bb.x, 0.0f);
      v.y = fmaxf(d0*r0.y + d1*r1.y + d2*r2.y + bb.y, 0.0f);
      *(float2*)(&ein[e0+e][2*l]) = v;
    }
  }
  // delta = ph @ Wp2 + bp2
  GEMMW2(Wp2); KREDUCE(bp2);
  #pragma unroll
  for (int e=0; e<8; e++){ dlA[e] = accA[e]; dlB[e] = accB[e]; }
  // q = B[i] - A[src] + delta   (kh==0 lanes write float4)
  if (kh == 0){
    float4 bi = ((const float4*)(&B[(size_t)i*128]))[q];
    #pragma unroll
    for (int e=0; e<8; e++){
      float4 av = ((const float4*)(&A[(size_t)ssrc[e0+e]*128]))[q];
      float4 v; v.x = bi.x - av.x + dlA[e].x; v.y = bi.y - av.y + dlA[e].y;
      v.z = bi.z - av.z + dlB[e].x; v.w = bi.w - av.w + dlB[e].y;
      *(float4*)(&ein[e0+e][4*q]) = v;
    }
  }
  // ah = relu(q @ Wa1 + ba1)
  GEMMW2(Wa1); KREDUCE(ba1);
  if (kh == 0){
    #pragma unroll
    for (int e=0; e<8; e++){
      float4 v; v.x=fmaxf(accA[e].x,0.f); v.y=fmaxf(accA[e].y,0.f);
      v.z=fmaxf(accB[e].x,0.f); v.w=fmaxf(accB[e].y,0.f);
      *(float4*)(&ein[e0+e][4*q]) = v;
    }
  }
  // logits = ah @ Wa2 + ba2
  GEMMW2(Wa2); KREDUCE(ba2);
  // cross-wave softmax over 32 edges; partials reuse dead ein rows:
  float* rbuf = &ein[0][0];
  v2f mA = accA[0], mB = accB[0];
  #pragma unroll
  for (int e=1; e<8; e++){
    mA.x=fmaxf(mA.x,accA[e].x); mA.y=fmaxf(mA.y,accA[e].y);
    mB.x=fmaxf(mB.x,accB[e].x); mB.y=fmaxf(mB.y,accB[e].y);
  }
  __syncthreads();                                   // all GEMM3 LDS reads done
  if (kh == 0){
    float4 mv; mv.x=mA.x; mv.y=mA.y; mv.z=mB.x; mv.w=mB.y;
    *(float4*)(&rbuf[w*128 + 4*q]) = mv;
  }
  __syncthreads();
  float4 M; M.x=-1e30f; M.y=-1e30f; M.z=-1e30f; M.w=-1e30f;
  #pragma unroll
  for (int ww=0; ww<4; ww++){
    float4 mm = *(const float4*)(&rbuf[ww*128 + 4*q]);
    M.x=fmaxf(M.x,mm.x); M.y=fmaxf(M.y,mm.y); M.z=fmaxf(M.z,mm.z); M.w=fmaxf(M.w,mm.w);
  }
  if (kh == 0){
    float4 s2; s2.x=0.f; s2.y=0.f; s2.z=0.f; s2.w=0.f;
    float4 h2; h2.x=0.f; h2.y=0.f; h2.z=0.f; h2.w=0.f;
    #pragma unroll
    for (int e=0; e<8; e++){
      int s = ssrc[e0+e]; float wt = sw[e0+e];
      float4 vv = ((const float4*)(&V[(size_t)s*128]))[q];
      float p;
      p = __expf(accA[e].x - M.x); s2.x += p; h2.x += p*(vv.x + dlA[e].x)*wt;
      p = __expf(accA[e].y - M.y); s2.y += p; h2.y += p*(vv.y + dlA[e].y)*wt;
      p = __expf(accB[e].x - M.z); s2.z += p; h2.z += p*(vv.z + dlB[e].x)*wt;
      p = __expf(accB[e].y - M.w); s2.w += p; h2.w += p*(vv.w + dlB[e].y)*wt;
    }
    *(float4*)(&rbuf[512  + w*128 + 4*q]) = s2;
    *(float4*)(&rbuf[1024 + w*128 + 4*q]) = h2;
  }
  __syncthreads();
  if (w == 0 && kh == 0){
    float4 S; S.x=0.f; S.y=0.f; S.z=0.f; S.w=0.f;
    float4 H; H.x=0.f; H.y=0.f; H.z=0.f; H.w=0.f;
    #pragma unroll
    for (int ww=0; ww<4; ww++){
      float4 sv = *(const float4*)(&rbuf[512  + ww*128 + 4*q]);
      float4 hv = *(const float4*)(&rbuf[1024 + ww*128 + 4*q]);
      S.x+=sv.x; S.y+=sv.y; S.z+=sv.z; S.w+=sv.w;
      H.x+=hv.x; H.y+=hv.y; H.z+=hv.z; H.w+=hv.w;
    }
    float4 o; o.x=H.x/(S.x+1e-16f); o.y=H.y/(S.y+1e-16f);
    o.z=H.z/(S.z+1e-16f); o.w=H.w/(S.w+1e-16f);
    *(float4*)(&h[(size_t)i*128 + 4*q]) = o;
  }
}

// hd = relu(h @ Wd + bd)
__global__ __launch_bounds__(128) void k_down(const float* __restrict__ h,
    const float* __restrict__ Wd, const float* __restrict__ bd, float* __restrict__ hd){
  int g0 = blockIdx.x*8; int c = threadIdx.x;
  __shared__ float hs[8][128];
  for (int idx=c; idx<1024; idx+=128) hs[idx>>7][idx&127] = h[(g0 + (idx>>7))*128 + (idx&127)];
  __syncthreads();
  float acc[8]; float b = bd[c];
  #pragma unroll
  for (int g=0; g<8; g++) acc[g] = b;
  for (int k=0; k<128; k+=4){
    float w0=Wd[(k+0)*128+c], w1=Wd[(k+1)*128+c], w2=Wd[(k+2)*128+c], w3=Wd[(k+3)*128+c];
    #pragma unroll
    for (int g=0; g<8; g++){
      const float4 ev = *(const float4*)(&hs[g][k]);
      acc[g] += ev.x*w0 + ev.y*w1 + ev.z*w2 + ev.w*w3;
    }
  }
  #pragma unroll
  for (int g=0; g<8; g++) hd[(g0+g)*128+c] = fmaxf(acc[g], 0.0f);
}

// y = max(hd[i], max over 32 neighbors hd[src])
__global__ __launch_bounds__(128) void k_pool(const float* __restrict__ hd,
    const int* __restrict__ soft_src, const int* __restrict__ knn_src, float* __restrict__ y){
  int i = blockIdx.x; int c = threadIdx.x;
  __shared__ int ss[32];
  if (c < 16) ss[c] = soft_src[i*16+c];
  else if (c < 32) ss[c] = knn_src[i*16+(c-16)];
  __syncthreads();
  float p = hd[i*128+c];
  for (int e=0; e<32; e++) p = fmaxf(p, hd[ss[e]*128+c]);
  y[i*128+c] = p;
}

// ranks = sorted-unique inverse (count of nonzero bins with smaller vid)
__global__ __launch_bounds__(256) void k_scan(const int* __restrict__ hist,
    int* __restrict__ rank, int* __restrict__ ucnt, int* __restrict__ Uo){
  __shared__ int part[256];
  int t = threadIdx.x;
  int base = t*32;
  int cnt = 0;
  for (int b=0; b<32; b++) cnt += (hist[base+b] > 0);
  part[t] = cnt;
  __syncthreads();
  if (t == 0){
    int run = 0;
    for (int q=0; q<256; q++){ int v = part[q]; part[q] = run; run += v; }
    Uo[0] = run;
  }
  __syncthreads();
  int run = part[t];
  for (int b=0; b<32; b++){
    int bin = base + b;
    rank[bin] = run;
    int hv = hist[bin];
    if (hv > 0){ ucnt[run] = hv; run++; }
  }
}

__global__ __launch_bounds__(128) void k_agg(const float* __restrict__ y, const float* __restrict__ pos,
    const int* __restrict__ vid, const int* __restrict__ rank,
    float* __restrict__ accx, float* __restrict__ accp){
  int n = blockIdx.x; int c = threadIdx.x;
  int r = rank[vid[n]];
  atomicAdd(&accx[r*128+c], y[n*128+c]);
  if (c < 3) atomicAdd(&accp[r*3+c], pos[n*3+c]);
}

__global__ __launch_bounds__(128) void k_final(const float* __restrict__ accx, const float* __restrict__ accp,
    const int* __restrict__ ucnt, const int* __restrict__ Uo, float* __restrict__ out){
  int r = blockIdx.x; int c = threadIdx.x;
  int u = Uo[0];
  float cnt = (r < u) ? (float)ucnt[r] : 0.0f;
  float den = fmaxf(cnt, 1.0f);
  out[r*128+c] = (r < u) ? accx[r*128+c]/den : 0.0f;
  if (c < 3) out[(size_t)NN*128 + r*3 + c] = (r < u) ? accp[r*3+c]/den : 0.0f;
  if (c == 0) out[(size_t)NN*128 + (size_t)NN*3 + r] = cnt;
}

// ---------------- launcher ----------------
extern "C" void kernel_launch(void* const* d_in, const int* in_sizes, int n_in,
                              void* d_out, int out_size, void* d_ws, size_t ws_size,
                              hipStream_t stream){
  (void)in_sizes; (void)n_in; (void)out_size;
  const float* x    = (const float*)d_in[0];
  const float* pos  = (const float*)d_in[1];
  const float* Wg1  = (const float*)d_in[2];
  const float* bg1  = (const float*)d_in[3];
  const float* Wg2  = (const float*)d_in[4];
  const float* bg2  = (const float*)d_in[5];
  const float* Wlin = (const float*)d_in[6];
  const float* Wsrc = (const float*)d_in[7];
  const float* Wdst = (const float*)d_in[8];
  const float* Wp1  = (const float*)d_in[9];
  const float* bp1  = (const float*)d_in[10];
  const float* Wp2  = (const float*)d_in[11];
  const float* bp2  = (const float*)d_in[12];
  const float* Wa1  = (const float*)d_in[13];
  const float* ba1  = (const float*)d_in[14];
  const float* Wa2  = (const float*)d_in[15];
  const float* ba2  = (const float*)d_in[16];
  const float* Wd   = (const float*)d_in[17];
  const float* bd   = (const float*)d_in[18];

  char* ws = (char*)d_ws;
  float* embF   = (float*)(ws + OFF_EMBF);
  float* psum   = (float*)(ws + OFF_PSUM);
  int*   ssrc   = (int*)  (ws + OFF_SSRC);
  float* topv   = (float*)(ws + OFF_TOPV);
  int*   ksrc   = (int*)  (ws + OFF_KSRC);
  int*   hist   = (int*)  (ws + OFF_HIST);
  int*   rank   = (int*)  (ws + OFF_RANK);
  int*   ucnt   = (int*)  (ws + OFF_UCNT);
  int*   vid    = (int*)  (ws + OFF_VID);
  int*   mi     = (int*)  (ws + OFF_META);
  int*   mx     = (int*)  (ws + OFF_META + 16);
  int*   Uo     = (int*)  (ws + OFF_META + 32);
  int*   qKi    = (int*)  (ws + OFF_QKI);
  int*   cand   = (int*)  (ws + OFF_CAND);
  float4* pos4  = (float4*)(ws + OFF_POS4);
  float* A      = (float*)(ws + OFF_A);
  float* B      = (float*)(ws + OFF_B);
  float* V      = (float*)(ws + OFF_V);
  float* h      = (float*)(ws + OFF_H);
  float* hd     = (float*)(ws + OFF_HD);
  float* y      = (float*)(ws + OFF_Y);
  float* accx   = (float*)(ws + OFF_ACCX);
  float* accp   = (float*)(ws + OFF_ACCP);
  unsigned short* zq = (unsigned short*)(ws + OFF_ZQ);

  const bool use_q = (ws_size >= OFF_ZQ + ZQ_BYTES);   // constant per run -> deterministic

  // rk = jax.random.split(jax.random.key(42), 2)  -- host threefry (foldlike)
  u32 rk0a, rk0b, rk1a, rk1b;
  tf2x32(0u, 42u, 0u, 0u, rk0a, rk0b);
  tf2x32(0u, 42u, 0u, 1u, rk1a, rk1b);

  hipMemsetAsync(hist, 0, 8192*4, stream);
  k_init0<<<1, 64, 0, stream>>>(mi, mx);
  k_min<<<32, 256, 0, stream>>>(pos, mi);
  k_ext<<<32, 256, 0, stream>>>(pos, mi, mx);
  k_vid<<<32, 256, 0, stream>>>(pos, mi, mx, vid, hist, pos4);
  k_emb<<<8192, 64, 0, stream>>>(x, Wg1, bg1, Wg2, bg2, rk0a, rk0b, embF);
  k_knn<<<8192, 64, 0, stream>>>(pos4, ksrc);
  if (use_q){
    k_colstats<true><<<dim3(32,32), 256, 0, stream>>>(embF, rk1a, rk1b, psum, zq);
    k_colfin<<<32, 256, 0, stream>>>(psum, embF, qKi);
    k_qtopk<<<8192, 64, 0, stream>>>(zq, qKi, cand);
    k_rescore<<<8192, 64, 0, stream>>>(embF, cand, rk1a, rk1b, ssrc, topv);
  } else {
    k_colstats<false><<<dim3(32,32), 256, 0, stream>>>(embF, rk1a, rk1b, psum, nullptr);
    k_colfin<<<32, 256, 0, stream>>>(psum, embF, qKi);
    k_rowtopk<<<8192, 64, 0, stream>>>(embF, rk1a, rk1b, ssrc, topv);
  }
  // Overlap region is free of z-cache readers from here on.
  k_xw<<<1024, 128, 0, stream>>>(x, Wsrc, Wdst, Wlin, A, B, V);
  k_edge<<<8192, 256, 0, stream>>>(pos, ssrc, topv, ksrc, A, B, V,
                                   Wp1, bp1, Wp2, bp2, Wa1, ba1, Wa2, ba2, h);
  k_down<<<1024, 128, 0, stream>>>(h, Wd, bd, hd);
  k_pool<<<8192, 128, 0, stream>>>(hd, ssrc, ksrc, y);
  hipMemsetAsync(accx, 0, (size_t)8192*128*4, stream);
  hipMemsetAsync(accp, 0, (size_t)8192*3*4, stream);
  k_scan<<<1, 256, 0, stream>>>(hist, rank, ucnt, Uo);
  k_agg<<<8192, 128, 0, stream>>>(y, pos, vid, rank, accx, accp);
  k_final<<<8192, 128, 0, stream>>>(accx, accp, ucnt, Uo, (float*)d_out);
}